// Round 1
// 706.844 us; speedup vs baseline: 1.1494x; 1.1494x over previous
//
#include <hip/hip_runtime.h>
#include <cstdint>
#include <cstddef>

// ---------------------------------------------------------------------------
// SSTAFormer round 3: latency attack on k_fused.
//   - 1 wave = 2 graphs (was 1): every weight B-frag load feeds 2 MFMAs ->
//     per-graph global-load count halved, per-wave ILP doubled, 8192 waves.
//   - Shuffle-built MFMA fragments (C-layout col==l15 matches B-frag col==l15,
//     so C->Bfrag is a quad-permutation at fixed l15): kills UT + Abf LDS
//     round trips in all 3 SAGE layers.
//   - K^T computed by MFMA with swapped operands (A = O_WK as-stored = Wk^T,
//     B = T rows); K fragments shuffle straight into regs: Kr buffer gone.
//   - mean(O@wo)@wproj == mean(O)@wo@wproj: WO MFMA pass + Ost buffer gone,
//     replaced by a 3-shuffle column mean + two 64-iter fp32 scalar loops.
//   - __launch_bounds__(256,3): VGPR cap 170 (was 64 effective) so the
//     compiler can keep weight loads in flight. Arena 12800 B/wave ->
//     51200 B/wg -> 3 wg/CU (12 waves/CU).
// ---------------------------------------------------------------------------

typedef __attribute__((ext_vector_type(8))) __bf16 bf16x8;
typedef __attribute__((ext_vector_type(4))) float  f32x4;

#define MFMA16(a,b,c) __builtin_amdgcn_mfma_f32_16x16x32_bf16((a),(b),(c),0,0,0)
#define FENCE() __threadfence_block()

#define NGR    16384
#define EDGES  1048576
#define PRED_ELEMS (16*16384*24)

// workspace layout in ushort units (unchanged; O_WO now unused by k_fused)
#define O_W1L 0               // [128][192]
#define O_W1R 24576
#define O_W2L 49152           // [128][128]
#define O_W2R 65536
#define O_W3L 81920           // [64][128]
#define O_W3R 90112
#define O_T0  98304           // [64 co][64 ci]  (tcn_w[...,0])
#define O_T1  102400
#define O_WQ  106496          // [64][64]
#define O_WK  110592
#define O_WV  114688
#define O_WO  118784
#define O_FC1 122880          // 16 x [64][128]
#define O_FC2 253952          // 16 x [32][64]
#define O_FEAT 286720         // [16384][128] bf16
#define PREP_TOT 286720

static __device__ __forceinline__ unsigned short f2bf(float f){
  unsigned int u = __builtin_bit_cast(unsigned int, f);
  u += 0x7FFFu + ((u >> 16) & 1u);            // RNE
  return (unsigned short)(u >> 16);
}
static __device__ __forceinline__ float bf2f(unsigned short h){
  return __builtin_bit_cast(float, (unsigned int)h << 16);
}
static __device__ __forceinline__ bf16x8 ld8(const unsigned short* p){
  return __builtin_bit_cast(bf16x8, *(const uint4*)p);   // 16B aligned by construction
}
static __device__ __forceinline__ bf16x8 zero8(){
  uint4 u = make_uint4(0u,0u,0u,0u);
  return __builtin_bit_cast(bf16x8, u);
}
static __device__ __forceinline__ ushort4 pack4(f32x4 v){
  ushort4 p; p.x=f2bf(v[0]); p.y=f2bf(v[1]); p.z=f2bf(v[2]); p.w=f2bf(v[3]); return p;
}
static __device__ __forceinline__ void pack2(f32x4 v, unsigned int& p0, unsigned int& p1){
  p0 = (unsigned int)f2bf(v[0]) | ((unsigned int)f2bf(v[1])<<16);
  p1 = (unsigned int)f2bf(v[2]) | ((unsigned int)f2bf(v[3])<<16);
}
// C-layout (row=4*quad+r, col=l15) -> B-frag (k=8*quad+e, col=l15):
// frag dwords come from lanes 32*quad+l15 and 32*quad+l15+16 (garbage for
// quad>=2 -- always multiplied by a zeroed A operand or cndmask'd).
static __device__ __forceinline__ bf16x8 shfrag(unsigned int p0, unsigned int p1,
                                                int laneA, int laneB){
  union { unsigned int d[4]; bf16x8 v; } u;
  u.d[0] = (unsigned int)__shfl((int)p0, laneA, 64);
  u.d[1] = (unsigned int)__shfl((int)p1, laneA, 64);
  u.d[2] = (unsigned int)__shfl((int)p0, laneB, 64);
  u.d[3] = (unsigned int)__shfl((int)p1, laneB, 64);
  return u.v;
}
// A-fragment from global fp32 x row (K padded 168->192, W rows >=168 are zero)
static __device__ __forceinline__ bf16x8 xfrag(const float* __restrict__ xrow, int k0){
  int ks = (k0 < 168) ? k0 : 0;          // clamped lanes multiply zero W rows
  float4 f0 = *(const float4*)(xrow + ks);
  float4 f1 = *(const float4*)(xrow + ks + 4);
  union { unsigned short s[8]; bf16x8 v; } u;
  u.s[0]=f2bf(f0.x); u.s[1]=f2bf(f0.y); u.s[2]=f2bf(f0.z); u.s[3]=f2bf(f0.w);
  u.s[4]=f2bf(f1.x); u.s[5]=f2bf(f1.y); u.s[6]=f2bf(f1.z); u.s[7]=f2bf(f1.w);
  return u.v;
}

// ---------------------------------------------------------------------------
// weight prep (unchanged, verified correct)
// ---------------------------------------------------------------------------
__global__ __launch_bounds__(256) void k_prep(
  const float* __restrict__ w1l, const float* __restrict__ w1r,
  const float* __restrict__ w2l, const float* __restrict__ w2r,
  const float* __restrict__ w3l, const float* __restrict__ w3r,
  const float* __restrict__ tcnw,
  const float* __restrict__ wq, const float* __restrict__ wk,
  const float* __restrict__ wv, const float* __restrict__ wo,
  const float* __restrict__ fc1w, const float* __restrict__ fc2w,
  unsigned short* __restrict__ W)
{
  int idx = blockIdx.x*256 + threadIdx.x;
  if (idx >= PREP_TOT) return;
  float v;
  if      (idx <  24576){ int t=idx;        int n=t/192,k=t%192; v=(k<168)? w1l[k*128+n]:0.f; }
  else if (idx <  49152){ int t=idx- 24576; int n=t/192,k=t%192; v=(k<168)? w1r[k*128+n]:0.f; }
  else if (idx <  65536){ int t=idx- 49152; int n=t/128,k=t%128; v=w2l[k*128+n]; }
  else if (idx <  81920){ int t=idx- 65536; int n=t/128,k=t%128; v=w2r[k*128+n]; }
  else if (idx <  90112){ int t=idx- 81920; int n=t/128,k=t%128; v=w3l[k*64+n]; }
  else if (idx <  98304){ int t=idx- 90112; int n=t/128,k=t%128; v=w3r[k*64+n]; }
  else if (idx < 102400){ int t=idx- 98304; int n=t/64, k=t%64;  v=tcnw[(n*64+k)*2+0]; }
  else if (idx < 106496){ int t=idx-102400; int n=t/64, k=t%64;  v=tcnw[(n*64+k)*2+1]; }
  else if (idx < 110592){ int t=idx-106496; int n=t/64, k=t%64;  v=wq[k*64+n]; }
  else if (idx < 114688){ int t=idx-110592; int n=t/64, k=t%64;  v=wk[k*64+n]; }
  else if (idx < 118784){ int t=idx-114688; int n=t/64, k=t%64;  v=wv[k*64+n]; }
  else if (idx < 122880){ int t=idx-118784; int n=t/64, k=t%64;  v=wo[k*64+n]; }
  else if (idx < 253952){ int t=idx-122880; int kh=t/8192, r=t%8192, n=r/128, k=r%128;
                          v=fc1w[kh*8192 + k*64 + n]; }
  else                  { int t=idx-253952; int kh=t/2048, r=t%2048, n=r/64,  k=r%64;
                          v=(n<24)? fc2w[kh*1536 + k*24 + n] : 0.f; }
  W[idx] = f2bf(v);
}

// ---------------------------------------------------------------------------
// fused GNN + TCN + attention + proj : 1 wg = 8 graphs, 1 wave = 2 graphs
// Per-wave LDS arena 12800 B (ushort offsets), overlays ordered by program
// order + FENCE at phase boundaries (all LDS traffic is wave-private):
//   Hb [2][16][136] 0..4352    (SAGE h, in-place across layers via reg staging)
//   X  [2][16][72]  0..2304    over Hb      (L3 out; dead after TCN)
//   T  [2][16][72]  2304..4608 over Hb tail (TCN out; dead after QKV)
//   VT [2][64][16]  2304..4352 over T head  (written end of V-pass)
//   Qb [2][16][72]  0..2304    over X       (dead after S)
//   Pb [2][4][16][16] 4352..6400            (dead after PV)
//   OM [4][64] f32  0..512     over Qb      (col-means + om@wo staging)
// ---------------------------------------------------------------------------
__global__ __launch_bounds__(256,3) void k_fused(
  const float* __restrict__ x, const int* __restrict__ edst,
  const float* __restrict__ b1, const float* __restrict__ b2,
  const float* __restrict__ b3, const float* __restrict__ tcnb,
  const float* __restrict__ wo, const float* __restrict__ wproj,
  const float* __restrict__ bproj,
  const unsigned short* __restrict__ ws0, unsigned short* __restrict__ feat)
{
  __shared__ alignas(16) unsigned char pool[4*12800];
  const int tid=threadIdx.x, w=tid>>6, lane=tid&63, quad=lane>>4, l15=lane&15;
  unsigned short* AR = (unsigned short*)(pool + w*12800);
  const int gb0 = (blockIdx.x*4 + w)*2;           // first of this wave's 2 graphs

  unsigned short* Hb = AR;              // [2][16][136]
  unsigned short* X  = AR;              // [2][16][72]
  unsigned short* T  = AR + 2304;       // [2][16][72]
  unsigned short* VT = AR + 2304;       // [2][64][16]
  unsigned short* Qb = AR;              // [2][16][72]
  unsigned short* Pb = AR + 4352;       // [2][4][16][16]
  float* OMf = (float*)AR;              // [4][64] f32

  const bf16x8 Z = zero8();
  const f32x4  z = {0.f,0.f,0.f,0.f};
  const int laneA = 32*quad + l15, laneB = laneA + 16;

  // ---- adjacency: A-frags built fully in registers via shuffles ----
  bf16x8 aA[2];
  #pragma unroll
  for (int g=0; g<2; ++g){
    int dl = edst[(gb0+g)*64 + lane] & 15;
    float c4[4]; float csum = 0.f;
    #pragma unroll
    for (int ss=0; ss<4; ++ss){
      int s = quad*4 + ss; int cc = 0;
      #pragma unroll
      for (int k=0;k<4;++k) cc += (__shfl(dl, s*4+k, 64) == l15) ? 1 : 0;
      c4[ss] = (float)cc; csum += (float)cc;
    }
    csum += __shfl_xor(csum, 16, 64);
    csum += __shfl_xor(csum, 32, 64);
    float ainv = 1.f / fmaxf(csum, 1.f);
    unsigned int p0 = (unsigned int)f2bf(c4[0]*ainv) | ((unsigned int)f2bf(c4[1]*ainv)<<16);
    unsigned int p1 = (unsigned int)f2bf(c4[2]*ainv) | ((unsigned int)f2bf(c4[3]*ainv)<<16);
    bf16x8 t = shfrag(p0, p1, laneA, laneB);
    aA[g] = (quad < 2) ? t : Z;           // exact zeros for k>=16
  }

  // ---- SAGE layer 1 (K=192, merged u+v pass, col-split 2x4) ----
  const float* xr0 = x + (size_t)(gb0*16 + l15)*168;
  const float* xr1 = xr0 + 16*168;
  #pragma unroll
  for (int cg=0; cg<2; ++cg){
    f32x4 au[2][4], av_[2][4];
    #pragma unroll
    for (int g=0;g<2;++g)
    #pragma unroll
    for (int c=0;c<4;++c){ au[g][c]=z; av_[g][c]=z; }
    #pragma unroll
    for (int kc=0;kc<6;++kc){
      bf16x8 a0 = xfrag(xr0, kc*32 + quad*8);
      bf16x8 a1 = xfrag(xr1, kc*32 + quad*8);
      #pragma unroll
      for (int c=0;c<4;++c){
        const unsigned short* pb_ = ws0 + (size_t)(cg*64 + c*16 + l15)*192 + kc*32 + quad*8;
        bf16x8 bl = ld8(pb_ + O_W1L);
        bf16x8 br = ld8(pb_ + O_W1R);
        au[0][c]  = MFMA16(a0, bl, au[0][c]);  au[1][c]  = MFMA16(a1, bl, au[1][c]);
        av_[0][c] = MFMA16(a0, br, av_[0][c]); av_[1][c] = MFMA16(a1, br, av_[1][c]);
      }
    }
    #pragma unroll
    for (int g=0;g<2;++g)
    #pragma unroll
    for (int c=0;c<4;++c){
      unsigned int p0,p1; pack2(au[g][c],p0,p1);
      av_[g][c] = MFMA16(aA[g], shfrag(p0,p1,laneA,laneB), av_[g][c]);
    }
    #pragma unroll
    for (int c=0;c<4;++c){
      float bb = b1[cg*64 + c*16 + l15];
      #pragma unroll
      for (int g=0;g<2;++g)
      #pragma unroll
      for (int r=0;r<4;++r)
        Hb[g*2176 + (quad*4+r)*136 + cg*64 + c*16 + l15] = f2bf(fmaxf(av_[g][c][r]+bb, 0.f));
    }
  }
  FENCE();

  // ---- SAGE layer 2 (K=128, two-pass per col-group, reg-staged writeback) ----
  {
    ushort4 os[2][2][4];                        // [cg][g][c]
    #pragma unroll
    for (int cg=0; cg<2; ++cg){
      bf16x8 uf[2][4];
      { // pass u
        f32x4 au[2][4];
        #pragma unroll
        for (int g=0;g<2;++g)
        #pragma unroll
        for (int c=0;c<4;++c) au[g][c]=z;
        #pragma unroll
        for (int kc=0;kc<4;++kc){
          bf16x8 a0 = ld8(Hb +        l15*136 + kc*32 + quad*8);
          bf16x8 a1 = ld8(Hb + 2176 + l15*136 + kc*32 + quad*8);
          #pragma unroll
          for (int c=0;c<4;++c){
            bf16x8 bl = ld8(ws0 + O_W2L + (cg*64 + c*16 + l15)*128 + kc*32 + quad*8);
            au[0][c] = MFMA16(a0, bl, au[0][c]);
            au[1][c] = MFMA16(a1, bl, au[1][c]);
          }
        }
        #pragma unroll
        for (int g=0;g<2;++g)
        #pragma unroll
        for (int c=0;c<4;++c){
          unsigned int p0,p1; pack2(au[g][c],p0,p1);
          uf[g][c] = shfrag(p0,p1,laneA,laneB);
        }
      }
      { // pass v + A@u
        f32x4 av_[2][4];
        #pragma unroll
        for (int g=0;g<2;++g)
        #pragma unroll
        for (int c=0;c<4;++c) av_[g][c]=z;
        #pragma unroll
        for (int kc=0;kc<4;++kc){
          bf16x8 a0 = ld8(Hb +        l15*136 + kc*32 + quad*8);
          bf16x8 a1 = ld8(Hb + 2176 + l15*136 + kc*32 + quad*8);
          #pragma unroll
          for (int c=0;c<4;++c){
            bf16x8 br = ld8(ws0 + O_W2R + (cg*64 + c*16 + l15)*128 + kc*32 + quad*8);
            av_[0][c] = MFMA16(a0, br, av_[0][c]);
            av_[1][c] = MFMA16(a1, br, av_[1][c]);
          }
        }
        #pragma unroll
        for (int g=0;g<2;++g)
        #pragma unroll
        for (int c=0;c<4;++c)
          av_[g][c] = MFMA16(aA[g], uf[g][c], av_[g][c]);
        #pragma unroll
        for (int c=0;c<4;++c){
          float bb = b2[cg*64 + c*16 + l15];
          #pragma unroll
          for (int g=0;g<2;++g){
            ushort4 p;
            p.x = f2bf(fmaxf(av_[g][c][0]+bb, 0.f));
            p.y = f2bf(fmaxf(av_[g][c][1]+bb, 0.f));
            p.z = f2bf(fmaxf(av_[g][c][2]+bb, 0.f));
            p.w = f2bf(fmaxf(av_[g][c][3]+bb, 0.f));
            os[cg][g][c] = p;
          }
        }
      }
    }
    // in-place writeback after ALL reads of both col-groups
    #pragma unroll
    for (int cg=0; cg<2; ++cg)
    #pragma unroll
    for (int g=0; g<2; ++g)
    #pragma unroll
    for (int c=0; c<4; ++c){
      unsigned short* bp = Hb + g*2176 + cg*64 + c*16 + l15;
      ushort4 p = os[cg][g][c];
      bp[(quad*4+0)*136] = p.x;
      bp[(quad*4+1)*136] = p.y;
      bp[(quad*4+2)*136] = p.z;
      bp[(quad*4+3)*136] = p.w;
    }
  }
  FENCE();

  // ---- SAGE layer 3 (64 cols, no relu) -> X; residual kept in regs ----
  float xres[2][4][4];
  {
    bf16x8 uf[2][4];
    { // pass u
      f32x4 au[2][4];
      #pragma unroll
      for (int g=0;g<2;++g)
      #pragma unroll
      for (int c=0;c<4;++c) au[g][c]=z;
      #pragma unroll
      for (int kc=0;kc<4;++kc){
        bf16x8 a0 = ld8(Hb +        l15*136 + kc*32 + quad*8);
        bf16x8 a1 = ld8(Hb + 2176 + l15*136 + kc*32 + quad*8);
        #pragma unroll
        for (int c=0;c<4;++c){
          bf16x8 bl = ld8(ws0 + O_W3L + (c*16 + l15)*128 + kc*32 + quad*8);
          au[0][c] = MFMA16(a0, bl, au[0][c]);
          au[1][c] = MFMA16(a1, bl, au[1][c]);
        }
      }
      #pragma unroll
      for (int g=0;g<2;++g)
      #pragma unroll
      for (int c=0;c<4;++c){
        unsigned int p0,p1; pack2(au[g][c],p0,p1);
        uf[g][c] = shfrag(p0,p1,laneA,laneB);
      }
    }
    { // pass v + A@u -> X
      f32x4 av_[2][4];
      #pragma unroll
      for (int g=0;g<2;++g)
      #pragma unroll
      for (int c=0;c<4;++c) av_[g][c]=z;
      #pragma unroll
      for (int kc=0;kc<4;++kc){
        bf16x8 a0 = ld8(Hb +        l15*136 + kc*32 + quad*8);
        bf16x8 a1 = ld8(Hb + 2176 + l15*136 + kc*32 + quad*8);
        #pragma unroll
        for (int c=0;c<4;++c){
          bf16x8 br = ld8(ws0 + O_W3R + (c*16 + l15)*128 + kc*32 + quad*8);
          av_[0][c] = MFMA16(a0, br, av_[0][c]);
          av_[1][c] = MFMA16(a1, br, av_[1][c]);
        }
      }
      #pragma unroll
      for (int g=0;g<2;++g)
      #pragma unroll
      for (int c=0;c<4;++c)
        av_[g][c] = MFMA16(aA[g], uf[g][c], av_[g][c]);
      #pragma unroll
      for (int c=0;c<4;++c){
        float bb = b3[c*16 + l15];
        #pragma unroll
        for (int g=0;g<2;++g)
        #pragma unroll
        for (int r=0;r<4;++r){
          unsigned short hv = f2bf(av_[g][c][r] + bb);
          xres[g][c][r] = bf2f(hv);
          X[g*1152 + (quad*4+r)*72 + c*16 + l15] = hv;
        }
      }
    }
  }
  FENCE();

  // ---- TCN: t = relu(Xshift@W0 + X@W1 + b) + X ----
  {
    f32x4 acct[2][4];
    #pragma unroll
    for (int g=0;g<2;++g)
    #pragma unroll
    for (int c=0;c<4;++c) acct[g][c]=z;
    #pragma unroll
    for (int kc=0;kc<2;++kc){
      bf16x8 ax0 = ld8(X +        l15*72 + kc*32 + quad*8);
      bf16x8 ax1 = ld8(X + 1152 + l15*72 + kc*32 + quad*8);
      bf16x8 as0 = (l15>0) ? ld8(X +        (l15-1)*72 + kc*32 + quad*8) : Z;
      bf16x8 as1 = (l15>0) ? ld8(X + 1152 + (l15-1)*72 + kc*32 + quad*8) : Z;
      #pragma unroll
      for (int c=0;c<4;++c){
        bf16x8 w0 = ld8(ws0 + O_T0 + (c*16 + l15)*64 + kc*32 + quad*8);
        bf16x8 w1 = ld8(ws0 + O_T1 + (c*16 + l15)*64 + kc*32 + quad*8);
        acct[0][c] = MFMA16(as0, w0, acct[0][c]);
        acct[0][c] = MFMA16(ax0, w1, acct[0][c]);
        acct[1][c] = MFMA16(as1, w0, acct[1][c]);
        acct[1][c] = MFMA16(ax1, w1, acct[1][c]);
      }
    }
    #pragma unroll
    for (int c=0;c<4;++c){
      float tb = tcnb[c*16 + l15];
      #pragma unroll
      for (int g=0;g<2;++g)
      #pragma unroll
      for (int r=0;r<4;++r)
        T[g*1152 + (quad*4+r)*72 + c*16 + l15] =
            f2bf(fmaxf(acct[g][c][r]+tb, 0.f) + xres[g][c][r]);
    }
  }
  FENCE();

  // ---- Q pass: Q row-major -> Qb (over dead X) ----
  {
    f32x4 acc[2][4];
    #pragma unroll
    for (int g=0;g<2;++g)
    #pragma unroll
    for (int c=0;c<4;++c) acc[g][c]=z;
    #pragma unroll
    for (int kc=0;kc<2;++kc){
      bf16x8 t0 = ld8(T +        l15*72 + kc*32 + quad*8);
      bf16x8 t1 = ld8(T + 1152 + l15*72 + kc*32 + quad*8);
      #pragma unroll
      for (int c=0;c<4;++c){
        bf16x8 b = ld8(ws0 + O_WQ + (c*16 + l15)*64 + kc*32 + quad*8);
        acc[0][c] = MFMA16(t0, b, acc[0][c]);
        acc[1][c] = MFMA16(t1, b, acc[1][c]);
      }
    }
    #pragma unroll
    for (int c=0;c<4;++c)
    #pragma unroll
    for (int g=0;g<2;++g)
    #pragma unroll
    for (int r=0;r<4;++r)
      Qb[g*1152 + (quad*4+r)*72 + c*16 + l15] = f2bf(acc[g][c][r]);
  }

  // ---- K^T pass: swapped operands (A = O_WK = Wk^T, B = T rows) ->
  //      C = K^T[d][node], col==l15 -> shuffle straight into B-frags ----
  bf16x8 bK[2][4];
  {
    f32x4 kt[2][4];
    #pragma unroll
    for (int g=0;g<2;++g)
    #pragma unroll
    for (int c=0;c<4;++c) kt[g][c]=z;
    #pragma unroll
    for (int kc=0;kc<2;++kc){
      bf16x8 t0 = ld8(T +        l15*72 + kc*32 + quad*8);
      bf16x8 t1 = ld8(T + 1152 + l15*72 + kc*32 + quad*8);
      #pragma unroll
      for (int c=0;c<4;++c){
        bf16x8 aW = ld8(ws0 + O_WK + (c*16 + l15)*64 + kc*32 + quad*8);
        kt[0][c] = MFMA16(aW, t0, kt[0][c]);
        kt[1][c] = MFMA16(aW, t1, kt[1][c]);
      }
    }
    #pragma unroll
    for (int g=0;g<2;++g)
    #pragma unroll
    for (int c=0;c<4;++c){
      unsigned int p0,p1; pack2(kt[g][c],p0,p1);
      bf16x8 f = shfrag(p0,p1,laneA,laneB);
      bK[g][c] = (quad < 2) ? f : Z;       // K padded 16->32: zero upper half
    }
  }

  // ---- V pass: V transposed -> VT (over T head, after all T reads) ----
  {
    f32x4 acc[2][4];
    #pragma unroll
    for (int g=0;g<2;++g)
    #pragma unroll
    for (int c=0;c<4;++c) acc[g][c]=z;
    #pragma unroll
    for (int kc=0;kc<2;++kc){
      bf16x8 t0 = ld8(T +        l15*72 + kc*32 + quad*8);
      bf16x8 t1 = ld8(T + 1152 + l15*72 + kc*32 + quad*8);
      #pragma unroll
      for (int c=0;c<4;++c){
        bf16x8 b = ld8(ws0 + O_WV + (c*16 + l15)*64 + kc*32 + quad*8);
        acc[0][c] = MFMA16(t0, b, acc[0][c]);
        acc[1][c] = MFMA16(t1, b, acc[1][c]);
      }
    }
    #pragma unroll
    for (int g=0;g<2;++g)
    #pragma unroll
    for (int c=0;c<4;++c)
      *(ushort4*)(VT + g*1024 + (c*16 + l15)*16 + quad*4) = pack4(acc[g][c]);
  }
  FENCE();

  // ---- S = (Q K^T)/4 per head; softmax across l15 lanes -> Pb ----
  {
    #pragma unroll
    for (int g=0;g<2;++g)
    #pragma unroll
    for (int h=0;h<4;++h){
      bf16x8 aQ = (quad < 2) ? ld8(Qb + g*1152 + l15*72 + h*16 + quad*8) : Z;
      f32x4 s4 = MFMA16(aQ, bK[g][h], z);
      #pragma unroll
      for (int r=0;r<4;++r){
        float s = s4[r]*0.25f;
        float m = s;
        m = fmaxf(m, __shfl_xor(m,1,64));
        m = fmaxf(m, __shfl_xor(m,2,64));
        m = fmaxf(m, __shfl_xor(m,4,64));
        m = fmaxf(m, __shfl_xor(m,8,64));
        float p = __expf(s-m);
        float su = p;
        su += __shfl_xor(su,1,64);
        su += __shfl_xor(su,2,64);
        su += __shfl_xor(su,4,64);
        su += __shfl_xor(su,8,64);
        Pb[g*1024 + (h*16 + quad*4 + r)*16 + l15] = f2bf(p/su);
      }
    }
  }
  FENCE();

  // ---- O = P@V per head; column mean over 16 nodes in-register -> OM ----
  {
    #pragma unroll
    for (int g=0;g<2;++g)
    #pragma unroll
    for (int h=0;h<4;++h){
      bf16x8 aP = (quad < 2) ? ld8(Pb + g*1024 + (h*16 + l15)*16 + quad*8) : Z;
      bf16x8 bV = (quad < 2) ? ld8(VT + g*1024 + (h*16 + l15)*16 + quad*8) : Z;
      f32x4 o = MFMA16(aP, bV, z);
      float cs = o[0]+o[1]+o[2]+o[3];
      cs += __shfl_xor(cs, 16, 64);
      cs += __shfl_xor(cs, 32, 64);
      if (quad == 0) OMf[g*64 + h*16 + l15] = cs * (1.f/16.f);
    }
  }
  FENCE();

  // ---- feat = ((mean O) @ wo) @ wproj + bproj  (all fp32 scalar) ----
  {
    float t0 = 0.f, t1 = 0.f;
    #pragma unroll 8
    for (int d=0; d<64; ++d){
      float wv = wo[d*64 + lane];
      t0 += OMf[d]    * wv;
      t1 += OMf[64+d] * wv;
    }
    OMf[128+lane] = t0;
    OMf[192+lane] = t1;
    FENCE();
    float a00 = bproj[lane], a01 = bproj[lane+64];
    float a10 = a00, a11 = a01;
    #pragma unroll 8
    for (int m=0; m<64; ++m){
      float f0 = OMf[128+m], f1 = OMf[192+m];
      float w0 = wproj[m*128 + lane], w1 = wproj[m*128 + lane + 64];
      a00 += f0*w0; a01 += f0*w1;
      a10 += f1*w0; a11 += f1*w1;
    }
    feat[(size_t)gb0*128 + lane]        = f2bf(a00);
    feat[(size_t)gb0*128 + lane + 64]   = f2bf(a01);
    feat[(size_t)(gb0+1)*128 + lane]      = f2bf(a10);
    feat[(size_t)(gb0+1)*128 + lane + 64] = f2bf(a11);
  }
}

// ---------------------------------------------------------------------------
// per-variable fc heads: 1 wave = one (kh, 16-row tile); 16384 waves total
// ---------------------------------------------------------------------------
__global__ __launch_bounds__(256,6) void k_heads(
  const unsigned short* __restrict__ ws0,
  const float* __restrict__ fc1b, const float* __restrict__ fc2b,
  float* __restrict__ pred)
{
  __shared__ alignas(16) unsigned short hh[4*1152];   // per-wave [16][72]
  const int tid=threadIdx.x, w=tid>>6, lane=tid&63, quad=lane>>4, l15=lane&15;
  const int Wv = blockIdx.x*4 + w;          // 0..16383
  const int kh = Wv & 15, tile = Wv >> 4;
  const int rb = tile*16;
  unsigned short* hw = hh + w*1152;
  const unsigned short* featg = ws0 + O_FEAT;
  const unsigned short* W1 = ws0 + O_FC1 + kh*8192;
  const unsigned short* W2 = ws0 + O_FC2 + kh*2048;
  f32x4 z = {0.f,0.f,0.f,0.f};
  f32x4 acc[4] = {z,z,z,z};
  #pragma unroll
  for (int kc=0;kc<4;++kc){
    bf16x8 a = ld8(featg + (size_t)(rb+l15)*128 + kc*32+quad*8);
    #pragma unroll
    for (int c=0;c<4;++c)
      acc[c] = MFMA16(a, ld8(W1 + (c*16+l15)*128 + kc*32+quad*8), acc[c]);
  }
  #pragma unroll
  for (int c=0;c<4;++c){
    float bb = fc1b[kh*64 + c*16+l15];
    #pragma unroll
    for (int r=0;r<4;++r)
      hw[(quad*4+r)*72 + c*16+l15] = f2bf(fmaxf(acc[c][r]+bb, 0.f));
  }
  __threadfence_block();
  f32x4 acc2[2] = {z,z};
  #pragma unroll
  for (int kc=0;kc<2;++kc){
    bf16x8 a = ld8(hw + l15*72 + kc*32+quad*8);
    #pragma unroll
    for (int c=0;c<2;++c)
      acc2[c] = MFMA16(a, ld8(W2 + (c*16+l15)*64 + kc*32+quad*8), acc2[c]);
  }
  #pragma unroll
  for (int c=0;c<2;++c){
    int col = c*16+l15;
    if (col < 24){
      float bb = fc2b[kh*24+col];
      #pragma unroll
      for (int r=0;r<4;++r)
        pred[(size_t)kh*393216 + (size_t)(rb+quad*4+r)*24 + col] = acc2[c][r] + bb;
    }
  }
}

// yb output = y.reshape -> exact copy
__global__ __launch_bounds__(256) void k_copy(const float4* __restrict__ y,
                                              float4* __restrict__ o)
{
  int i = blockIdx.x*256 + threadIdx.x;   // exactly 1572864 float4s
  o[i] = y[i];
}

// ---------------------------------------------------------------------------
extern "C" void kernel_launch(void* const* d_in, const int* in_sizes, int n_in,
                              void* d_out, int out_size, void* d_ws, size_t ws_size,
                              hipStream_t stream) {
  const float* x    = (const float*)d_in[0];
  const float* y    = (const float*)d_in[1];
  const int*   ei   = (const int*)d_in[2];
  const float* w1l  = (const float*)d_in[4];
  const float* w1r  = (const float*)d_in[5];
  const float* b1   = (const float*)d_in[6];
  const float* w2l  = (const float*)d_in[7];
  const float* w2r  = (const float*)d_in[8];
  const float* b2   = (const float*)d_in[9];
  const float* w3l  = (const float*)d_in[10];
  const float* w3r  = (const float*)d_in[11];
  const float* b3   = (const float*)d_in[12];
  const float* tcnw = (const float*)d_in[13];
  const float* tcnb = (const float*)d_in[14];
  const float* wq   = (const float*)d_in[15];
  const float* wk   = (const float*)d_in[16];
  const float* wv   = (const float*)d_in[17];
  const float* wo   = (const float*)d_in[18];
  const float* wpr  = (const float*)d_in[19];
  const float* bpr  = (const float*)d_in[20];
  const float* fc1w = (const float*)d_in[21];
  const float* fc1b = (const float*)d_in[22];
  const float* fc2w = (const float*)d_in[23];
  const float* fc2b = (const float*)d_in[24];

  unsigned short* W = (unsigned short*)d_ws;
  float* out = (float*)d_out;

  k_prep<<<1120, 256, 0, stream>>>(w1l,w1r,w2l,w2r,w3l,w3r,tcnw,wq,wk,wv,wo,fc1w,fc2w,W);
  k_fused<<<NGR/8, 256, 0, stream>>>(x, ei + EDGES, b1,b2,b3,tcnb, wo, wpr, bpr, W, W + O_FEAT);
  k_heads<<<4096, 256, 0, stream>>>(W, fc1b, fc2b, out);
  k_copy<<<6144, 256, 0, stream>>>((const float4*)y, (float4*)(out + PRED_ELEMS));
}

// Round 2
// 650.256 us; speedup vs baseline: 1.2494x; 1.0870x over previous
//
#include <hip/hip_runtime.h>
#include <cstdint>
#include <cstddef>

// ---------------------------------------------------------------------------
// SSTAFormer round 4: scratch elimination + occupancy.
//   - All fragment builders are make_uint4 + bit_cast (no memory-typed unions):
//     round-3 showed 198 MB of WRITE_SIZE = scratch round-trips from the
//     union element-store pattern failing SROA.
//   - VT LDS buffer eliminated: V C-layout (col=d=l15) shuffles straight into
//     PV B-frags via shfrag (bV[2][4] in regs). Pb moved into dead T region.
//     Arena 12800 -> 9216 B/wave -> 36864 B/wg -> 4 wg/CU at (256,4).
//   - k_heads: 2 row-tiles per wave (per-kh weight loads amortized 2x),
//     8192 waves, (256,4).
// ---------------------------------------------------------------------------

typedef __attribute__((ext_vector_type(8))) __bf16 bf16x8;
typedef __attribute__((ext_vector_type(4))) float  f32x4;

#define MFMA16(a,b,c) __builtin_amdgcn_mfma_f32_16x16x32_bf16((a),(b),(c),0,0,0)
#define FENCE() __threadfence_block()

#define NGR    16384
#define EDGES  1048576
#define PRED_ELEMS (16*16384*24)

// workspace layout in ushort units
#define O_W1L 0               // [128][192]
#define O_W1R 24576
#define O_W2L 49152           // [128][128]
#define O_W2R 65536
#define O_W3L 81920           // [64][128]
#define O_W3R 90112
#define O_T0  98304           // [64 co][64 ci]  (tcn_w[...,0])
#define O_T1  102400
#define O_WQ  106496          // [64][64]
#define O_WK  110592
#define O_WV  114688
#define O_WO  118784
#define O_FC1 122880          // 16 x [64][128]
#define O_FC2 253952          // 16 x [32][64]
#define O_FEAT 286720         // [16384][128] bf16
#define PREP_TOT 286720

static __device__ __forceinline__ unsigned short f2bf(float f){
  unsigned int u = __builtin_bit_cast(unsigned int, f);
  u += 0x7FFFu + ((u >> 16) & 1u);            // RNE
  return (unsigned short)(u >> 16);
}
static __device__ __forceinline__ float bf2f(unsigned short h){
  return __builtin_bit_cast(float, (unsigned int)h << 16);
}
static __device__ __forceinline__ bf16x8 ld8(const unsigned short* p){
  return __builtin_bit_cast(bf16x8, *(const uint4*)p);   // 16B aligned by construction
}
static __device__ __forceinline__ bf16x8 zero8(){
  uint4 u = make_uint4(0u,0u,0u,0u);
  return __builtin_bit_cast(bf16x8, u);
}
// pack two f32 -> one dword of 2 bf16 (register-only)
static __device__ __forceinline__ unsigned int pkbf2(float a, float b){
  return (unsigned int)f2bf(a) | ((unsigned int)f2bf(b)<<16);
}
// build bf16x8 from 4 dwords (register-only, no union)
static __device__ __forceinline__ bf16x8 u4bf(unsigned int a, unsigned int b,
                                              unsigned int c, unsigned int d){
  uint4 u = make_uint4(a,b,c,d);
  return __builtin_bit_cast(bf16x8, u);
}
// C-layout (row=4*quad'+r, col=l15) -> B-frag (k=8*quad+e, col=l15):
// frag dwords pulled from lanes 32*quad+l15 and 32*quad+l15+16 (garbage for
// quad>=2 -- always multiplied by a zeroed A operand or cndmask'd).
static __device__ __forceinline__ bf16x8 shfrag(unsigned int p0, unsigned int p1,
                                                int laneA, int laneB){
  return u4bf((unsigned int)__shfl((int)p0, laneA, 64),
              (unsigned int)__shfl((int)p1, laneA, 64),
              (unsigned int)__shfl((int)p0, laneB, 64),
              (unsigned int)__shfl((int)p1, laneB, 64));
}
// A-fragment from global fp32 x row (K padded 168->192, W rows >=168 are zero)
static __device__ __forceinline__ bf16x8 xfrag(const float* __restrict__ xrow, int k0){
  int ks = (k0 < 168) ? k0 : 0;          // clamped lanes multiply zero W rows
  float4 f0 = *(const float4*)(xrow + ks);
  float4 f1 = *(const float4*)(xrow + ks + 4);
  return u4bf(pkbf2(f0.x,f0.y), pkbf2(f0.z,f0.w),
              pkbf2(f1.x,f1.y), pkbf2(f1.z,f1.w));
}

// ---------------------------------------------------------------------------
// weight prep (unchanged, verified correct)
// ---------------------------------------------------------------------------
__global__ __launch_bounds__(256) void k_prep(
  const float* __restrict__ w1l, const float* __restrict__ w1r,
  const float* __restrict__ w2l, const float* __restrict__ w2r,
  const float* __restrict__ w3l, const float* __restrict__ w3r,
  const float* __restrict__ tcnw,
  const float* __restrict__ wq, const float* __restrict__ wk,
  const float* __restrict__ wv, const float* __restrict__ wo,
  const float* __restrict__ fc1w, const float* __restrict__ fc2w,
  unsigned short* __restrict__ W)
{
  int idx = blockIdx.x*256 + threadIdx.x;
  if (idx >= PREP_TOT) return;
  float v;
  if      (idx <  24576){ int t=idx;        int n=t/192,k=t%192; v=(k<168)? w1l[k*128+n]:0.f; }
  else if (idx <  49152){ int t=idx- 24576; int n=t/192,k=t%192; v=(k<168)? w1r[k*128+n]:0.f; }
  else if (idx <  65536){ int t=idx- 49152; int n=t/128,k=t%128; v=w2l[k*128+n]; }
  else if (idx <  81920){ int t=idx- 65536; int n=t/128,k=t%128; v=w2r[k*128+n]; }
  else if (idx <  90112){ int t=idx- 81920; int n=t/128,k=t%128; v=w3l[k*64+n]; }
  else if (idx <  98304){ int t=idx- 90112; int n=t/128,k=t%128; v=w3r[k*64+n]; }
  else if (idx < 102400){ int t=idx- 98304; int n=t/64, k=t%64;  v=tcnw[(n*64+k)*2+0]; }
  else if (idx < 106496){ int t=idx-102400; int n=t/64, k=t%64;  v=tcnw[(n*64+k)*2+1]; }
  else if (idx < 110592){ int t=idx-106496; int n=t/64, k=t%64;  v=wq[k*64+n]; }
  else if (idx < 114688){ int t=idx-110592; int n=t/64, k=t%64;  v=wk[k*64+n]; }
  else if (idx < 118784){ int t=idx-114688; int n=t/64, k=t%64;  v=wv[k*64+n]; }
  else if (idx < 122880){ int t=idx-118784; int n=t/64, k=t%64;  v=wo[k*64+n]; }
  else if (idx < 253952){ int t=idx-122880; int kh=t/8192, r=t%8192, n=r/128, k=r%128;
                          v=fc1w[kh*8192 + k*64 + n]; }
  else                  { int t=idx-253952; int kh=t/2048, r=t%2048, n=r/64,  k=r%64;
                          v=(n<24)? fc2w[kh*1536 + k*24 + n] : 0.f; }
  W[idx] = f2bf(v);
}

// ---------------------------------------------------------------------------
// fused GNN + TCN + attention + proj : 1 wg = 8 graphs, 1 wave = 2 graphs
// Per-wave LDS arena 9216 B (ushort offsets), overlays ordered by program
// order + FENCE at phase boundaries (all LDS traffic is wave-private):
//   Hb [2][16][136] 0..4352    (SAGE h; layer-3 writes X only after all reads)
//   X  [2][16][72]  0..2304    over Hb head (dead after TCN)
//   T  [2][16][72]  2304..4608 over Hb tail (dead after QKV passes)
//   Qb [2][16][72]  0..2304    over X       (dead after S)
//   Pb [2][4][16][16] 2304..4352 over T     (dead after PV)
//   OM [4][64] f32  0..512u    over Qb      (col-means + om@wo staging)
// ---------------------------------------------------------------------------
__global__ __launch_bounds__(256,4) void k_fused(
  const float* __restrict__ x, const int* __restrict__ edst,
  const float* __restrict__ b1, const float* __restrict__ b2,
  const float* __restrict__ b3, const float* __restrict__ tcnb,
  const float* __restrict__ wo, const float* __restrict__ wproj,
  const float* __restrict__ bproj,
  const unsigned short* __restrict__ ws0, unsigned short* __restrict__ feat)
{
  __shared__ alignas(16) unsigned char pool[4*9216];
  const int tid=threadIdx.x, w=tid>>6, lane=tid&63, quad=lane>>4, l15=lane&15;
  unsigned short* AR = (unsigned short*)(pool + w*9216);
  const int gb0 = (blockIdx.x*4 + w)*2;           // first of this wave's 2 graphs

  unsigned short* Hb = AR;              // [2][16][136]
  unsigned short* X  = AR;              // [2][16][72]
  unsigned short* T  = AR + 2304;       // [2][16][72]
  unsigned short* Qb = AR;              // [2][16][72]
  unsigned short* Pb = AR + 2304;       // [2][4][16][16]
  float* OMf = (float*)AR;              // [4][64] f32

  const bf16x8 Z = zero8();
  const f32x4  z = {0.f,0.f,0.f,0.f};
  const int laneA = 32*quad + l15, laneB = laneA + 16;

  // ---- adjacency: A-frags built fully in registers via shuffles ----
  bf16x8 aA[2];
  #pragma unroll
  for (int g=0; g<2; ++g){
    int dl = edst[(gb0+g)*64 + lane] & 15;
    float c4[4]; float csum = 0.f;
    #pragma unroll
    for (int ss=0; ss<4; ++ss){
      int s = quad*4 + ss; int cc = 0;
      #pragma unroll
      for (int k=0;k<4;++k) cc += (__shfl(dl, s*4+k, 64) == l15) ? 1 : 0;
      c4[ss] = (float)cc; csum += (float)cc;
    }
    csum += __shfl_xor(csum, 16, 64);
    csum += __shfl_xor(csum, 32, 64);
    float ainv = 1.f / fmaxf(csum, 1.f);
    unsigned int p0 = pkbf2(c4[0]*ainv, c4[1]*ainv);
    unsigned int p1 = pkbf2(c4[2]*ainv, c4[3]*ainv);
    bf16x8 t = shfrag(p0, p1, laneA, laneB);
    aA[g] = (quad < 2) ? t : Z;           // exact zeros for k>=16
  }

  // ---- SAGE layer 1 (K=192, merged u+v pass, col-split 2x4) ----
  const float* xr0 = x + (size_t)(gb0*16 + l15)*168;
  const float* xr1 = xr0 + 16*168;
  #pragma unroll
  for (int cg=0; cg<2; ++cg){
    f32x4 au[2][4], av_[2][4];
    #pragma unroll
    for (int g=0;g<2;++g)
    #pragma unroll
    for (int c=0;c<4;++c){ au[g][c]=z; av_[g][c]=z; }
    #pragma unroll
    for (int kc=0;kc<6;++kc){
      bf16x8 a0 = xfrag(xr0, kc*32 + quad*8);
      bf16x8 a1 = xfrag(xr1, kc*32 + quad*8);
      #pragma unroll
      for (int c=0;c<4;++c){
        const unsigned short* pb_ = ws0 + (size_t)(cg*64 + c*16 + l15)*192 + kc*32 + quad*8;
        bf16x8 bl = ld8(pb_ + O_W1L);
        bf16x8 br = ld8(pb_ + O_W1R);
        au[0][c]  = MFMA16(a0, bl, au[0][c]);  au[1][c]  = MFMA16(a1, bl, au[1][c]);
        av_[0][c] = MFMA16(a0, br, av_[0][c]); av_[1][c] = MFMA16(a1, br, av_[1][c]);
      }
    }
    #pragma unroll
    for (int g=0;g<2;++g)
    #pragma unroll
    for (int c=0;c<4;++c){
      unsigned int p0 = pkbf2(au[g][c][0], au[g][c][1]);
      unsigned int p1 = pkbf2(au[g][c][2], au[g][c][3]);
      av_[g][c] = MFMA16(aA[g], shfrag(p0,p1,laneA,laneB), av_[g][c]);
    }
    #pragma unroll
    for (int c=0;c<4;++c){
      float bb = b1[cg*64 + c*16 + l15];
      #pragma unroll
      for (int g=0;g<2;++g)
      #pragma unroll
      for (int r=0;r<4;++r)
        Hb[g*2176 + (quad*4+r)*136 + cg*64 + c*16 + l15] = f2bf(fmaxf(av_[g][c][r]+bb, 0.f));
    }
  }
  FENCE();

  // ---- SAGE layer 2 (K=128, two-pass per col-group, reg-staged writeback) ----
  {
    ushort4 os[2][2][4];                        // [cg][g][c]
    #pragma unroll
    for (int cg=0; cg<2; ++cg){
      bf16x8 uf[2][4];
      { // pass u
        f32x4 au[2][4];
        #pragma unroll
        for (int g=0;g<2;++g)
        #pragma unroll
        for (int c=0;c<4;++c) au[g][c]=z;
        #pragma unroll
        for (int kc=0;kc<4;++kc){
          bf16x8 a0 = ld8(Hb +        l15*136 + kc*32 + quad*8);
          bf16x8 a1 = ld8(Hb + 2176 + l15*136 + kc*32 + quad*8);
          #pragma unroll
          for (int c=0;c<4;++c){
            bf16x8 bl = ld8(ws0 + O_W2L + (cg*64 + c*16 + l15)*128 + kc*32 + quad*8);
            au[0][c] = MFMA16(a0, bl, au[0][c]);
            au[1][c] = MFMA16(a1, bl, au[1][c]);
          }
        }
        #pragma unroll
        for (int g=0;g<2;++g)
        #pragma unroll
        for (int c=0;c<4;++c){
          unsigned int p0 = pkbf2(au[g][c][0], au[g][c][1]);
          unsigned int p1 = pkbf2(au[g][c][2], au[g][c][3]);
          uf[g][c] = shfrag(p0,p1,laneA,laneB);
        }
      }
      { // pass v + A@u
        f32x4 av_[2][4];
        #pragma unroll
        for (int g=0;g<2;++g)
        #pragma unroll
        for (int c=0;c<4;++c) av_[g][c]=z;
        #pragma unroll
        for (int kc=0;kc<4;++kc){
          bf16x8 a0 = ld8(Hb +        l15*136 + kc*32 + quad*8);
          bf16x8 a1 = ld8(Hb + 2176 + l15*136 + kc*32 + quad*8);
          #pragma unroll
          for (int c=0;c<4;++c){
            bf16x8 br = ld8(ws0 + O_W2R + (cg*64 + c*16 + l15)*128 + kc*32 + quad*8);
            av_[0][c] = MFMA16(a0, br, av_[0][c]);
            av_[1][c] = MFMA16(a1, br, av_[1][c]);
          }
        }
        #pragma unroll
        for (int g=0;g<2;++g)
        #pragma unroll
        for (int c=0;c<4;++c)
          av_[g][c] = MFMA16(aA[g], uf[g][c], av_[g][c]);
        #pragma unroll
        for (int c=0;c<4;++c){
          float bb = b2[cg*64 + c*16 + l15];
          #pragma unroll
          for (int g=0;g<2;++g){
            ushort4 p;
            p.x = f2bf(fmaxf(av_[g][c][0]+bb, 0.f));
            p.y = f2bf(fmaxf(av_[g][c][1]+bb, 0.f));
            p.z = f2bf(fmaxf(av_[g][c][2]+bb, 0.f));
            p.w = f2bf(fmaxf(av_[g][c][3]+bb, 0.f));
            os[cg][g][c] = p;
          }
        }
      }
    }
    // in-place writeback after ALL reads of both col-groups
    #pragma unroll
    for (int cg=0; cg<2; ++cg)
    #pragma unroll
    for (int g=0; g<2; ++g)
    #pragma unroll
    for (int c=0; c<4; ++c){
      unsigned short* bp = Hb + g*2176 + cg*64 + c*16 + l15;
      ushort4 p = os[cg][g][c];
      bp[(quad*4+0)*136] = p.x;
      bp[(quad*4+1)*136] = p.y;
      bp[(quad*4+2)*136] = p.z;
      bp[(quad*4+3)*136] = p.w;
    }
  }
  FENCE();

  // ---- SAGE layer 3 (64 cols, no relu) -> X; residual kept in regs ----
  float xres[2][4][4];
  {
    bf16x8 uf[2][4];
    { // pass u
      f32x4 au[2][4];
      #pragma unroll
      for (int g=0;g<2;++g)
      #pragma unroll
      for (int c=0;c<4;++c) au[g][c]=z;
      #pragma unroll
      for (int kc=0;kc<4;++kc){
        bf16x8 a0 = ld8(Hb +        l15*136 + kc*32 + quad*8);
        bf16x8 a1 = ld8(Hb + 2176 + l15*136 + kc*32 + quad*8);
        #pragma unroll
        for (int c=0;c<4;++c){
          bf16x8 bl = ld8(ws0 + O_W3L + (c*16 + l15)*128 + kc*32 + quad*8);
          au[0][c] = MFMA16(a0, bl, au[0][c]);
          au[1][c] = MFMA16(a1, bl, au[1][c]);
        }
      }
      #pragma unroll
      for (int g=0;g<2;++g)
      #pragma unroll
      for (int c=0;c<4;++c){
        unsigned int p0 = pkbf2(au[g][c][0], au[g][c][1]);
        unsigned int p1 = pkbf2(au[g][c][2], au[g][c][3]);
        uf[g][c] = shfrag(p0,p1,laneA,laneB);
      }
    }
    { // pass v + A@u -> X (writes only after all Hb reads)
      f32x4 av_[2][4];
      #pragma unroll
      for (int g=0;g<2;++g)
      #pragma unroll
      for (int c=0;c<4;++c) av_[g][c]=z;
      #pragma unroll
      for (int kc=0;kc<4;++kc){
        bf16x8 a0 = ld8(Hb +        l15*136 + kc*32 + quad*8);
        bf16x8 a1 = ld8(Hb + 2176 + l15*136 + kc*32 + quad*8);
        #pragma unroll
        for (int c=0;c<4;++c){
          bf16x8 br = ld8(ws0 + O_W3R + (c*16 + l15)*128 + kc*32 + quad*8);
          av_[0][c] = MFMA16(a0, br, av_[0][c]);
          av_[1][c] = MFMA16(a1, br, av_[1][c]);
        }
      }
      #pragma unroll
      for (int g=0;g<2;++g)
      #pragma unroll
      for (int c=0;c<4;++c)
        av_[g][c] = MFMA16(aA[g], uf[g][c], av_[g][c]);
      #pragma unroll
      for (int c=0;c<4;++c){
        float bb = b3[c*16 + l15];
        #pragma unroll
        for (int g=0;g<2;++g)
        #pragma unroll
        for (int r=0;r<4;++r){
          unsigned short hv = f2bf(av_[g][c][r] + bb);
          xres[g][c][r] = bf2f(hv);
          X[g*1152 + (quad*4+r)*72 + c*16 + l15] = hv;
        }
      }
    }
  }
  FENCE();

  // ---- TCN: t = relu(Xshift@W0 + X@W1 + b) + X ----
  {
    f32x4 acct[2][4];
    #pragma unroll
    for (int g=0;g<2;++g)
    #pragma unroll
    for (int c=0;c<4;++c) acct[g][c]=z;
    #pragma unroll
    for (int kc=0;kc<2;++kc){
      bf16x8 ax0 = ld8(X +        l15*72 + kc*32 + quad*8);
      bf16x8 ax1 = ld8(X + 1152 + l15*72 + kc*32 + quad*8);
      bf16x8 as0 = (l15>0) ? ld8(X +        (l15-1)*72 + kc*32 + quad*8) : Z;
      bf16x8 as1 = (l15>0) ? ld8(X + 1152 + (l15-1)*72 + kc*32 + quad*8) : Z;
      #pragma unroll
      for (int c=0;c<4;++c){
        bf16x8 w0 = ld8(ws0 + O_T0 + (c*16 + l15)*64 + kc*32 + quad*8);
        bf16x8 w1 = ld8(ws0 + O_T1 + (c*16 + l15)*64 + kc*32 + quad*8);
        acct[0][c] = MFMA16(as0, w0, acct[0][c]);
        acct[0][c] = MFMA16(ax0, w1, acct[0][c]);
        acct[1][c] = MFMA16(as1, w0, acct[1][c]);
        acct[1][c] = MFMA16(ax1, w1, acct[1][c]);
      }
    }
    #pragma unroll
    for (int c=0;c<4;++c){
      float tb = tcnb[c*16 + l15];
      #pragma unroll
      for (int g=0;g<2;++g)
      #pragma unroll
      for (int r=0;r<4;++r)
        T[g*1152 + (quad*4+r)*72 + c*16 + l15] =
            f2bf(fmaxf(acct[g][c][r]+tb, 0.f) + xres[g][c][r]);
    }
  }
  FENCE();

  // ---- Q pass: Q row-major -> Qb (over dead X) ----
  {
    f32x4 acc[2][4];
    #pragma unroll
    for (int g=0;g<2;++g)
    #pragma unroll
    for (int c=0;c<4;++c) acc[g][c]=z;
    #pragma unroll
    for (int kc=0;kc<2;++kc){
      bf16x8 t0 = ld8(T +        l15*72 + kc*32 + quad*8);
      bf16x8 t1 = ld8(T + 1152 + l15*72 + kc*32 + quad*8);
      #pragma unroll
      for (int c=0;c<4;++c){
        bf16x8 b = ld8(ws0 + O_WQ + (c*16 + l15)*64 + kc*32 + quad*8);
        acc[0][c] = MFMA16(t0, b, acc[0][c]);
        acc[1][c] = MFMA16(t1, b, acc[1][c]);
      }
    }
    #pragma unroll
    for (int c=0;c<4;++c)
    #pragma unroll
    for (int g=0;g<2;++g)
    #pragma unroll
    for (int r=0;r<4;++r)
      Qb[g*1152 + (quad*4+r)*72 + c*16 + l15] = f2bf(acc[g][c][r]);
  }

  // ---- K^T pass: swapped operands (A = O_WK = Wk^T, B = T rows) ->
  //      C = K^T[d][node], col==l15 -> shuffle straight into B-frags ----
  bf16x8 bK[2][4];
  {
    f32x4 kt[2][4];
    #pragma unroll
    for (int g=0;g<2;++g)
    #pragma unroll
    for (int c=0;c<4;++c) kt[g][c]=z;
    #pragma unroll
    for (int kc=0;kc<2;++kc){
      bf16x8 t0 = ld8(T +        l15*72 + kc*32 + quad*8);
      bf16x8 t1 = ld8(T + 1152 + l15*72 + kc*32 + quad*8);
      #pragma unroll
      for (int c=0;c<4;++c){
        bf16x8 aW = ld8(ws0 + O_WK + (c*16 + l15)*64 + kc*32 + quad*8);
        kt[0][c] = MFMA16(aW, t0, kt[0][c]);
        kt[1][c] = MFMA16(aW, t1, kt[1][c]);
      }
    }
    #pragma unroll
    for (int g=0;g<2;++g)
    #pragma unroll
    for (int c=0;c<4;++c){
      unsigned int p0 = pkbf2(kt[g][c][0], kt[g][c][1]);
      unsigned int p1 = pkbf2(kt[g][c][2], kt[g][c][3]);
      bf16x8 f = shfrag(p0,p1,laneA,laneB);
      bK[g][c] = (quad < 2) ? f : Z;       // K padded 16->32: zero upper half
    }
  }

  // ---- V pass: V C-layout (col=d) -> PV B-frags via shfrag (no LDS) ----
  bf16x8 bV[2][4];
  {
    f32x4 acc[2][4];
    #pragma unroll
    for (int g=0;g<2;++g)
    #pragma unroll
    for (int c=0;c<4;++c) acc[g][c]=z;
    #pragma unroll
    for (int kc=0;kc<2;++kc){
      bf16x8 t0 = ld8(T +        l15*72 + kc*32 + quad*8);
      bf16x8 t1 = ld8(T + 1152 + l15*72 + kc*32 + quad*8);
      #pragma unroll
      for (int c=0;c<4;++c){
        bf16x8 b = ld8(ws0 + O_WV + (c*16 + l15)*64 + kc*32 + quad*8);
        acc[0][c] = MFMA16(t0, b, acc[0][c]);
        acc[1][c] = MFMA16(t1, b, acc[1][c]);
      }
    }
    #pragma unroll
    for (int g=0;g<2;++g)
    #pragma unroll
    for (int c=0;c<4;++c){
      unsigned int p0 = pkbf2(acc[g][c][0], acc[g][c][1]);
      unsigned int p1 = pkbf2(acc[g][c][2], acc[g][c][3]);
      bV[g][c] = shfrag(p0,p1,laneA,laneB);  // garbage k>=16 killed by zero aP
    }
  }
  FENCE();

  // ---- S = (Q K^T)/4 per head; softmax across l15 lanes -> Pb (over T) ----
  {
    #pragma unroll
    for (int g=0;g<2;++g)
    #pragma unroll
    for (int h=0;h<4;++h){
      bf16x8 aQ = (quad < 2) ? ld8(Qb + g*1152 + l15*72 + h*16 + quad*8) : Z;
      f32x4 s4 = MFMA16(aQ, bK[g][h], z);
      #pragma unroll
      for (int r=0;r<4;++r){
        float s = s4[r]*0.25f;
        float m = s;
        m = fmaxf(m, __shfl_xor(m,1,64));
        m = fmaxf(m, __shfl_xor(m,2,64));
        m = fmaxf(m, __shfl_xor(m,4,64));
        m = fmaxf(m, __shfl_xor(m,8,64));
        float p = __expf(s-m);
        float su = p;
        su += __shfl_xor(su,1,64);
        su += __shfl_xor(su,2,64);
        su += __shfl_xor(su,4,64);
        su += __shfl_xor(su,8,64);
        Pb[g*1024 + (h*16 + quad*4 + r)*16 + l15] = f2bf(p/su);
      }
    }
  }
  FENCE();

  // ---- O = P@V per head; column mean over 16 nodes in-register -> OM ----
  {
    #pragma unroll
    for (int g=0;g<2;++g)
    #pragma unroll
    for (int h=0;h<4;++h){
      bf16x8 aP = (quad < 2) ? ld8(Pb + g*1024 + (h*16 + l15)*16 + quad*8) : Z;
      f32x4 o = MFMA16(aP, bV[g][h], z);
      float cs = o[0]+o[1]+o[2]+o[3];
      cs += __shfl_xor(cs, 16, 64);
      cs += __shfl_xor(cs, 32, 64);
      if (quad == 0) OMf[g*64 + h*16 + l15] = cs * (1.f/16.f);
    }
  }
  FENCE();

  // ---- feat = ((mean O) @ wo) @ wproj + bproj  (all fp32 scalar) ----
  {
    float t0 = 0.f, t1 = 0.f;
    #pragma unroll 8
    for (int d=0; d<64; ++d){
      float wv = wo[d*64 + lane];
      t0 += OMf[d]    * wv;
      t1 += OMf[64+d] * wv;
    }
    OMf[128+lane] = t0;
    OMf[192+lane] = t1;
    FENCE();
    float a00 = bproj[lane], a01 = bproj[lane+64];
    float a10 = a00, a11 = a01;
    #pragma unroll 8
    for (int m=0; m<64; ++m){
      float f0 = OMf[128+m], f1 = OMf[192+m];
      float w0 = wproj[m*128 + lane], w1 = wproj[m*128 + lane + 64];
      a00 += f0*w0; a01 += f0*w1;
      a10 += f1*w0; a11 += f1*w1;
    }
    feat[(size_t)gb0*128 + lane]        = f2bf(a00);
    feat[(size_t)gb0*128 + lane + 64]   = f2bf(a01);
    feat[(size_t)(gb0+1)*128 + lane]      = f2bf(a10);
    feat[(size_t)(gb0+1)*128 + lane + 64] = f2bf(a11);
  }
}

// ---------------------------------------------------------------------------
// per-variable fc heads: 1 wave = one kh x TWO 16-row tiles (weight loads
// amortized 2x); 8192 waves total
// ---------------------------------------------------------------------------
__global__ __launch_bounds__(256,4) void k_heads(
  const unsigned short* __restrict__ ws0,
  const float* __restrict__ fc1b, const float* __restrict__ fc2b,
  float* __restrict__ pred)
{
  __shared__ alignas(16) unsigned short hh[4*2304];   // per-wave 2x[16][72]
  const int tid=threadIdx.x, w=tid>>6, lane=tid&63, quad=lane>>4, l15=lane&15;
  const int Wv = blockIdx.x*4 + w;          // 0..8191
  const int kh = Wv & 15, tp = Wv >> 4;     // tile pair 0..511
  const int rb = tp*32;
  unsigned short* hw = hh + w*2304;
  const unsigned short* featg = ws0 + O_FEAT;
  const unsigned short* W1 = ws0 + O_FC1 + kh*8192;
  const unsigned short* W2 = ws0 + O_FC2 + kh*2048;
  f32x4 z = {0.f,0.f,0.f,0.f};
  f32x4 acc[2][4];
  #pragma unroll
  for (int t=0;t<2;++t)
  #pragma unroll
  for (int c=0;c<4;++c) acc[t][c]=z;
  #pragma unroll
  for (int kc=0;kc<4;++kc){
    bf16x8 a0 = ld8(featg + (size_t)(rb+l15)*128    + kc*32+quad*8);
    bf16x8 a1 = ld8(featg + (size_t)(rb+16+l15)*128 + kc*32+quad*8);
    #pragma unroll
    for (int c=0;c<4;++c){
      bf16x8 b = ld8(W1 + (c*16+l15)*128 + kc*32+quad*8);
      acc[0][c] = MFMA16(a0, b, acc[0][c]);
      acc[1][c] = MFMA16(a1, b, acc[1][c]);
    }
  }
  #pragma unroll
  for (int c=0;c<4;++c){
    float bb = fc1b[kh*64 + c*16+l15];
    #pragma unroll
    for (int t=0;t<2;++t)
    #pragma unroll
    for (int r=0;r<4;++r)
      hw[t*1152 + (quad*4+r)*72 + c*16+l15] = f2bf(fmaxf(acc[t][c][r]+bb, 0.f));
  }
  __threadfence_block();
  f32x4 acc2[2][2];
  #pragma unroll
  for (int t=0;t<2;++t)
  #pragma unroll
  for (int c=0;c<2;++c) acc2[t][c]=z;
  #pragma unroll
  for (int kc=0;kc<2;++kc){
    bf16x8 a0 = ld8(hw +        l15*72 + kc*32+quad*8);
    bf16x8 a1 = ld8(hw + 1152 + l15*72 + kc*32+quad*8);
    #pragma unroll
    for (int c=0;c<2;++c){
      bf16x8 b = ld8(W2 + (c*16+l15)*64 + kc*32+quad*8);
      acc2[0][c] = MFMA16(a0, b, acc2[0][c]);
      acc2[1][c] = MFMA16(a1, b, acc2[1][c]);
    }
  }
  #pragma unroll
  for (int c=0;c<2;++c){
    int col = c*16+l15;
    if (col < 24){
      float bb = fc2b[kh*24+col];
      #pragma unroll
      for (int t=0;t<2;++t)
      #pragma unroll
      for (int r=0;r<4;++r)
        pred[(size_t)kh*393216 + (size_t)(rb+t*16+quad*4+r)*24 + col] = acc2[t][c][r] + bb;
    }
  }
}

// yb output = y.reshape -> exact copy
__global__ __launch_bounds__(256) void k_copy(const float4* __restrict__ y,
                                              float4* __restrict__ o)
{
  int i = blockIdx.x*256 + threadIdx.x;   // exactly 1572864 float4s
  o[i] = y[i];
}

// ---------------------------------------------------------------------------
extern "C" void kernel_launch(void* const* d_in, const int* in_sizes, int n_in,
                              void* d_out, int out_size, void* d_ws, size_t ws_size,
                              hipStream_t stream) {
  const float* x    = (const float*)d_in[0];
  const float* y    = (const float*)d_in[1];
  const int*   ei   = (const int*)d_in[2];
  const float* w1l  = (const float*)d_in[4];
  const float* w1r  = (const float*)d_in[5];
  const float* b1   = (const float*)d_in[6];
  const float* w2l  = (const float*)d_in[7];
  const float* w2r  = (const float*)d_in[8];
  const float* b2   = (const float*)d_in[9];
  const float* w3l  = (const float*)d_in[10];
  const float* w3r  = (const float*)d_in[11];
  const float* b3   = (const float*)d_in[12];
  const float* tcnw = (const float*)d_in[13];
  const float* tcnb = (const float*)d_in[14];
  const float* wq   = (const float*)d_in[15];
  const float* wk   = (const float*)d_in[16];
  const float* wv   = (const float*)d_in[17];
  const float* wo   = (const float*)d_in[18];
  const float* wpr  = (const float*)d_in[19];
  const float* bpr  = (const float*)d_in[20];
  const float* fc1w = (const float*)d_in[21];
  const float* fc1b = (const float*)d_in[22];
  const float* fc2w = (const float*)d_in[23];
  const float* fc2b = (const float*)d_in[24];

  unsigned short* W = (unsigned short*)d_ws;
  float* out = (float*)d_out;

  k_prep<<<1120, 256, 0, stream>>>(w1l,w1r,w2l,w2r,w3l,w3r,tcnw,wq,wk,wv,wo,fc1w,fc2w,W);
  k_fused<<<NGR/8, 256, 0, stream>>>(x, ei + EDGES, b1,b2,b3,tcnb, wo, wpr, bpr, W, W + O_FEAT);
  k_heads<<<2048, 256, 0, stream>>>(W, fc1b, fc2b, out);
  k_copy<<<6144, 256, 0, stream>>>((const float4*)y, (float4*)(out + PRED_ELEMS));
}

// Round 3
// 649.605 us; speedup vs baseline: 1.2507x; 1.0010x over previous
//
#include <hip/hip_runtime.h>
#include <cstdint>
#include <cstddef>

// ---------------------------------------------------------------------------
// SSTAFormer round 5: register-pressure attack (scratch was pressure spill).
//   - Round-4 evidence: WRITE_SIZE 190 MB = 380 B/thread scratch; appeared
//     with 2-graphs/wave. Peak live state was ~128+ (layer1 merged 64-acc,
//     layer2 os+av+uf, attn xres+bK+bV).
//   - Layer 1 + Layer 2 now run in 4 col-groups of 32 (acc arrays halved).
//   - xres registers dropped: residual re-read from X in LDS (bit-identical).
//   - k_heads: 4 row-tiles per wave (weights amortized 4x), 4096 waves.
// ---------------------------------------------------------------------------

typedef __attribute__((ext_vector_type(8))) __bf16 bf16x8;
typedef __attribute__((ext_vector_type(4))) float  f32x4;

#define MFMA16(a,b,c) __builtin_amdgcn_mfma_f32_16x16x32_bf16((a),(b),(c),0,0,0)
#define FENCE() __threadfence_block()

#define NGR    16384
#define EDGES  1048576
#define PRED_ELEMS (16*16384*24)

// workspace layout in ushort units
#define O_W1L 0               // [128][192]
#define O_W1R 24576
#define O_W2L 49152           // [128][128]
#define O_W2R 65536
#define O_W3L 81920           // [64][128]
#define O_W3R 90112
#define O_T0  98304           // [64 co][64 ci]  (tcn_w[...,0])
#define O_T1  102400
#define O_WQ  106496          // [64][64]
#define O_WK  110592
#define O_WV  114688
#define O_WO  118784
#define O_FC1 122880          // 16 x [64][128]
#define O_FC2 253952          // 16 x [32][64]
#define O_FEAT 286720         // [16384][128] bf16
#define PREP_TOT 286720

static __device__ __forceinline__ unsigned short f2bf(float f){
  unsigned int u = __builtin_bit_cast(unsigned int, f);
  u += 0x7FFFu + ((u >> 16) & 1u);            // RNE
  return (unsigned short)(u >> 16);
}
static __device__ __forceinline__ float bf2f(unsigned short h){
  return __builtin_bit_cast(float, (unsigned int)h << 16);
}
static __device__ __forceinline__ bf16x8 ld8(const unsigned short* p){
  return __builtin_bit_cast(bf16x8, *(const uint4*)p);   // 16B aligned by construction
}
static __device__ __forceinline__ bf16x8 zero8(){
  uint4 u = make_uint4(0u,0u,0u,0u);
  return __builtin_bit_cast(bf16x8, u);
}
// pack two f32 -> one dword of 2 bf16 (register-only)
static __device__ __forceinline__ unsigned int pkbf2(float a, float b){
  return (unsigned int)f2bf(a) | ((unsigned int)f2bf(b)<<16);
}
// build bf16x8 from 4 dwords (register-only)
static __device__ __forceinline__ bf16x8 u4bf(unsigned int a, unsigned int b,
                                              unsigned int c, unsigned int d){
  uint4 u = make_uint4(a,b,c,d);
  return __builtin_bit_cast(bf16x8, u);
}
// C-layout (row=4*quad'+r, col=l15) -> B-frag (k=8*quad+e, col=l15):
// frag dwords pulled from lanes 32*quad+l15 and 32*quad+l15+16 (garbage for
// quad>=2 -- always multiplied by a zeroed A operand).
static __device__ __forceinline__ bf16x8 shfrag(unsigned int p0, unsigned int p1,
                                                int laneA, int laneB){
  return u4bf((unsigned int)__shfl((int)p0, laneA, 64),
              (unsigned int)__shfl((int)p1, laneA, 64),
              (unsigned int)__shfl((int)p0, laneB, 64),
              (unsigned int)__shfl((int)p1, laneB, 64));
}
// A-fragment from global fp32 x row (K padded 168->192, W rows >=168 are zero)
static __device__ __forceinline__ bf16x8 xfrag(const float* __restrict__ xrow, int k0){
  int ks = (k0 < 168) ? k0 : 0;          // clamped lanes multiply zero W rows
  float4 f0 = *(const float4*)(xrow + ks);
  float4 f1 = *(const float4*)(xrow + ks + 4);
  return u4bf(pkbf2(f0.x,f0.y), pkbf2(f0.z,f0.w),
              pkbf2(f1.x,f1.y), pkbf2(f1.z,f1.w));
}

// ---------------------------------------------------------------------------
// weight prep (unchanged, verified correct)
// ---------------------------------------------------------------------------
__global__ __launch_bounds__(256) void k_prep(
  const float* __restrict__ w1l, const float* __restrict__ w1r,
  const float* __restrict__ w2l, const float* __restrict__ w2r,
  const float* __restrict__ w3l, const float* __restrict__ w3r,
  const float* __restrict__ tcnw,
  const float* __restrict__ wq, const float* __restrict__ wk,
  const float* __restrict__ wv, const float* __restrict__ wo,
  const float* __restrict__ fc1w, const float* __restrict__ fc2w,
  unsigned short* __restrict__ W)
{
  int idx = blockIdx.x*256 + threadIdx.x;
  if (idx >= PREP_TOT) return;
  float v;
  if      (idx <  24576){ int t=idx;        int n=t/192,k=t%192; v=(k<168)? w1l[k*128+n]:0.f; }
  else if (idx <  49152){ int t=idx- 24576; int n=t/192,k=t%192; v=(k<168)? w1r[k*128+n]:0.f; }
  else if (idx <  65536){ int t=idx- 49152; int n=t/128,k=t%128; v=w2l[k*128+n]; }
  else if (idx <  81920){ int t=idx- 65536; int n=t/128,k=t%128; v=w2r[k*128+n]; }
  else if (idx <  90112){ int t=idx- 81920; int n=t/128,k=t%128; v=w3l[k*64+n]; }
  else if (idx <  98304){ int t=idx- 90112; int n=t/128,k=t%128; v=w3r[k*64+n]; }
  else if (idx < 102400){ int t=idx- 98304; int n=t/64, k=t%64;  v=tcnw[(n*64+k)*2+0]; }
  else if (idx < 106496){ int t=idx-102400; int n=t/64, k=t%64;  v=tcnw[(n*64+k)*2+1]; }
  else if (idx < 110592){ int t=idx-106496; int n=t/64, k=t%64;  v=wq[k*64+n]; }
  else if (idx < 114688){ int t=idx-110592; int n=t/64, k=t%64;  v=wk[k*64+n]; }
  else if (idx < 118784){ int t=idx-114688; int n=t/64, k=t%64;  v=wv[k*64+n]; }
  else if (idx < 122880){ int t=idx-118784; int n=t/64, k=t%64;  v=wo[k*64+n]; }
  else if (idx < 253952){ int t=idx-122880; int kh=t/8192, r=t%8192, n=r/128, k=r%128;
                          v=fc1w[kh*8192 + k*64 + n]; }
  else                  { int t=idx-253952; int kh=t/2048, r=t%2048, n=r/64,  k=r%64;
                          v=(n<24)? fc2w[kh*1536 + k*24 + n] : 0.f; }
  W[idx] = f2bf(v);
}

// ---------------------------------------------------------------------------
// fused GNN + TCN + attention + proj : 1 wg = 8 graphs, 1 wave = 2 graphs
// Per-wave LDS arena 9216 B (ushort offsets), overlays ordered by program
// order + FENCE at phase boundaries (all LDS traffic is wave-private):
//   Hb [2][16][136] 0..4352    (SAGE h; layer-3 writes X only after all reads)
//   X  [2][16][72]  0..2304    over Hb head (dead after TCN residual re-read)
//   T  [2][16][72]  2304..4608 over Hb tail (dead after QKV passes)
//   Qb [2][16][72]  0..2304    over X       (dead after S)
//   Pb [2][4][16][16] 2304..4352 over T     (dead after PV)
//   OM [4][64] f32  0..512u    over Qb      (col-means + om@wo staging)
// ---------------------------------------------------------------------------
__global__ __launch_bounds__(256,4) void k_fused(
  const float* __restrict__ x, const int* __restrict__ edst,
  const float* __restrict__ b1, const float* __restrict__ b2,
  const float* __restrict__ b3, const float* __restrict__ tcnb,
  const float* __restrict__ wo, const float* __restrict__ wproj,
  const float* __restrict__ bproj,
  const unsigned short* __restrict__ ws0, unsigned short* __restrict__ feat)
{
  __shared__ alignas(16) unsigned char pool[4*9216];
  const int tid=threadIdx.x, w=tid>>6, lane=tid&63, quad=lane>>4, l15=lane&15;
  unsigned short* AR = (unsigned short*)(pool + w*9216);
  const int gb0 = (blockIdx.x*4 + w)*2;           // first of this wave's 2 graphs

  unsigned short* Hb = AR;              // [2][16][136]
  unsigned short* X  = AR;              // [2][16][72]
  unsigned short* T  = AR + 2304;       // [2][16][72]
  unsigned short* Qb = AR;              // [2][16][72]
  unsigned short* Pb = AR + 2304;       // [2][4][16][16]
  float* OMf = (float*)AR;              // [4][64] f32

  const bf16x8 Z = zero8();
  const f32x4  z = {0.f,0.f,0.f,0.f};
  const int laneA = 32*quad + l15, laneB = laneA + 16;

  // ---- adjacency: A-frags built fully in registers via shuffles ----
  bf16x8 aA[2];
  #pragma unroll
  for (int g=0; g<2; ++g){
    int dl = edst[(gb0+g)*64 + lane] & 15;
    float c4[4]; float csum = 0.f;
    #pragma unroll
    for (int ss=0; ss<4; ++ss){
      int s = quad*4 + ss; int cc = 0;
      #pragma unroll
      for (int k=0;k<4;++k) cc += (__shfl(dl, s*4+k, 64) == l15) ? 1 : 0;
      c4[ss] = (float)cc; csum += (float)cc;
    }
    csum += __shfl_xor(csum, 16, 64);
    csum += __shfl_xor(csum, 32, 64);
    float ainv = 1.f / fmaxf(csum, 1.f);
    unsigned int p0 = pkbf2(c4[0]*ainv, c4[1]*ainv);
    unsigned int p1 = pkbf2(c4[2]*ainv, c4[3]*ainv);
    bf16x8 t = shfrag(p0, p1, laneA, laneB);
    aA[g] = (quad < 2) ? t : Z;           // exact zeros for k>=16
  }

  // ---- SAGE layer 1 (K=192, merged u+v pass, 4 col-groups of 32) ----
  const float* xr0 = x + (size_t)(gb0*16 + l15)*168;
  const float* xr1 = xr0 + 16*168;
  #pragma unroll
  for (int cg=0; cg<4; ++cg){
    f32x4 au[2][2], av_[2][2];
    #pragma unroll
    for (int g=0;g<2;++g)
    #pragma unroll
    for (int c=0;c<2;++c){ au[g][c]=z; av_[g][c]=z; }
    #pragma unroll
    for (int kc=0;kc<6;++kc){
      bf16x8 a0 = xfrag(xr0, kc*32 + quad*8);
      bf16x8 a1 = xfrag(xr1, kc*32 + quad*8);
      #pragma unroll
      for (int c=0;c<2;++c){
        const unsigned short* pb_ = ws0 + (size_t)(cg*32 + c*16 + l15)*192 + kc*32 + quad*8;
        bf16x8 bl = ld8(pb_ + O_W1L);
        bf16x8 br = ld8(pb_ + O_W1R);
        au[0][c]  = MFMA16(a0, bl, au[0][c]);  au[1][c]  = MFMA16(a1, bl, au[1][c]);
        av_[0][c] = MFMA16(a0, br, av_[0][c]); av_[1][c] = MFMA16(a1, br, av_[1][c]);
      }
    }
    #pragma unroll
    for (int g=0;g<2;++g)
    #pragma unroll
    for (int c=0;c<2;++c){
      unsigned int p0 = pkbf2(au[g][c][0], au[g][c][1]);
      unsigned int p1 = pkbf2(au[g][c][2], au[g][c][3]);
      av_[g][c] = MFMA16(aA[g], shfrag(p0,p1,laneA,laneB), av_[g][c]);
    }
    #pragma unroll
    for (int c=0;c<2;++c){
      float bb = b1[cg*32 + c*16 + l15];
      #pragma unroll
      for (int g=0;g<2;++g)
      #pragma unroll
      for (int r=0;r<4;++r)
        Hb[g*2176 + (quad*4+r)*136 + cg*32 + c*16 + l15] = f2bf(fmaxf(av_[g][c][r]+bb, 0.f));
    }
  }
  FENCE();

  // ---- SAGE layer 2 (K=128, 4 col-groups of 32, two-pass, staged writeback) ----
  {
    ushort4 os[4][2][2];                        // [cg][g][c]
    #pragma unroll
    for (int cg=0; cg<4; ++cg){
      bf16x8 uf[2][2];
      { // pass u
        f32x4 au[2][2];
        #pragma unroll
        for (int g=0;g<2;++g)
        #pragma unroll
        for (int c=0;c<2;++c) au[g][c]=z;
        #pragma unroll
        for (int kc=0;kc<4;++kc){
          bf16x8 a0 = ld8(Hb +        l15*136 + kc*32 + quad*8);
          bf16x8 a1 = ld8(Hb + 2176 + l15*136 + kc*32 + quad*8);
          #pragma unroll
          for (int c=0;c<2;++c){
            bf16x8 bl = ld8(ws0 + O_W2L + (cg*32 + c*16 + l15)*128 + kc*32 + quad*8);
            au[0][c] = MFMA16(a0, bl, au[0][c]);
            au[1][c] = MFMA16(a1, bl, au[1][c]);
          }
        }
        #pragma unroll
        for (int g=0;g<2;++g)
        #pragma unroll
        for (int c=0;c<2;++c){
          unsigned int p0 = pkbf2(au[g][c][0], au[g][c][1]);
          unsigned int p1 = pkbf2(au[g][c][2], au[g][c][3]);
          uf[g][c] = shfrag(p0,p1,laneA,laneB);
        }
      }
      { // pass v + A@u
        f32x4 av_[2][2];
        #pragma unroll
        for (int g=0;g<2;++g)
        #pragma unroll
        for (int c=0;c<2;++c) av_[g][c]=z;
        #pragma unroll
        for (int kc=0;kc<4;++kc){
          bf16x8 a0 = ld8(Hb +        l15*136 + kc*32 + quad*8);
          bf16x8 a1 = ld8(Hb + 2176 + l15*136 + kc*32 + quad*8);
          #pragma unroll
          for (int c=0;c<2;++c){
            bf16x8 br = ld8(ws0 + O_W2R + (cg*32 + c*16 + l15)*128 + kc*32 + quad*8);
            av_[0][c] = MFMA16(a0, br, av_[0][c]);
            av_[1][c] = MFMA16(a1, br, av_[1][c]);
          }
        }
        #pragma unroll
        for (int g=0;g<2;++g)
        #pragma unroll
        for (int c=0;c<2;++c)
          av_[g][c] = MFMA16(aA[g], uf[g][c], av_[g][c]);
        #pragma unroll
        for (int c=0;c<2;++c){
          float bb = b2[cg*32 + c*16 + l15];
          #pragma unroll
          for (int g=0;g<2;++g){
            ushort4 p;
            p.x = f2bf(fmaxf(av_[g][c][0]+bb, 0.f));
            p.y = f2bf(fmaxf(av_[g][c][1]+bb, 0.f));
            p.z = f2bf(fmaxf(av_[g][c][2]+bb, 0.f));
            p.w = f2bf(fmaxf(av_[g][c][3]+bb, 0.f));
            os[cg][g][c] = p;
          }
        }
      }
    }
    // in-place writeback after ALL reads of all col-groups
    #pragma unroll
    for (int cg=0; cg<4; ++cg)
    #pragma unroll
    for (int g=0; g<2; ++g)
    #pragma unroll
    for (int c=0; c<2; ++c){
      unsigned short* bp = Hb + g*2176 + cg*32 + c*16 + l15;
      ushort4 p = os[cg][g][c];
      bp[(quad*4+0)*136] = p.x;
      bp[(quad*4+1)*136] = p.y;
      bp[(quad*4+2)*136] = p.z;
      bp[(quad*4+3)*136] = p.w;
    }
  }
  FENCE();

  // ---- SAGE layer 3 (64 cols, no relu) -> X ----
  {
    bf16x8 uf[2][4];
    { // pass u
      f32x4 au[2][4];
      #pragma unroll
      for (int g=0;g<2;++g)
      #pragma unroll
      for (int c=0;c<4;++c) au[g][c]=z;
      #pragma unroll
      for (int kc=0;kc<4;++kc){
        bf16x8 a0 = ld8(Hb +        l15*136 + kc*32 + quad*8);
        bf16x8 a1 = ld8(Hb + 2176 + l15*136 + kc*32 + quad*8);
        #pragma unroll
        for (int c=0;c<4;++c){
          bf16x8 bl = ld8(ws0 + O_W3L + (c*16 + l15)*128 + kc*32 + quad*8);
          au[0][c] = MFMA16(a0, bl, au[0][c]);
          au[1][c] = MFMA16(a1, bl, au[1][c]);
        }
      }
      #pragma unroll
      for (int g=0;g<2;++g)
      #pragma unroll
      for (int c=0;c<4;++c){
        unsigned int p0 = pkbf2(au[g][c][0], au[g][c][1]);
        unsigned int p1 = pkbf2(au[g][c][2], au[g][c][3]);
        uf[g][c] = shfrag(p0,p1,laneA,laneB);
      }
    }
    { // pass v + A@u -> X (writes only after all Hb reads)
      f32x4 av_[2][4];
      #pragma unroll
      for (int g=0;g<2;++g)
      #pragma unroll
      for (int c=0;c<4;++c) av_[g][c]=z;
      #pragma unroll
      for (int kc=0;kc<4;++kc){
        bf16x8 a0 = ld8(Hb +        l15*136 + kc*32 + quad*8);
        bf16x8 a1 = ld8(Hb + 2176 + l15*136 + kc*32 + quad*8);
        #pragma unroll
        for (int c=0;c<4;++c){
          bf16x8 br = ld8(ws0 + O_W3R + (c*16 + l15)*128 + kc*32 + quad*8);
          av_[0][c] = MFMA16(a0, br, av_[0][c]);
          av_[1][c] = MFMA16(a1, br, av_[1][c]);
        }
      }
      #pragma unroll
      for (int g=0;g<2;++g)
      #pragma unroll
      for (int c=0;c<4;++c)
        av_[g][c] = MFMA16(aA[g], uf[g][c], av_[g][c]);
      #pragma unroll
      for (int c=0;c<4;++c){
        float bb = b3[c*16 + l15];
        #pragma unroll
        for (int g=0;g<2;++g)
        #pragma unroll
        for (int r=0;r<4;++r)
          X[g*1152 + (quad*4+r)*72 + c*16 + l15] = f2bf(av_[g][c][r] + bb);
      }
    }
  }
  FENCE();

  // ---- TCN: t = relu(Xshift@W0 + X@W1 + b) + X  (residual re-read from X) ----
  {
    f32x4 acct[2][4];
    #pragma unroll
    for (int g=0;g<2;++g)
    #pragma unroll
    for (int c=0;c<4;++c) acct[g][c]=z;
    #pragma unroll
    for (int kc=0;kc<2;++kc){
      bf16x8 ax0 = ld8(X +        l15*72 + kc*32 + quad*8);
      bf16x8 ax1 = ld8(X + 1152 + l15*72 + kc*32 + quad*8);
      bf16x8 as0 = (l15>0) ? ld8(X +        (l15-1)*72 + kc*32 + quad*8) : Z;
      bf16x8 as1 = (l15>0) ? ld8(X + 1152 + (l15-1)*72 + kc*32 + quad*8) : Z;
      #pragma unroll
      for (int c=0;c<4;++c){
        bf16x8 w0 = ld8(ws0 + O_T0 + (c*16 + l15)*64 + kc*32 + quad*8);
        bf16x8 w1 = ld8(ws0 + O_T1 + (c*16 + l15)*64 + kc*32 + quad*8);
        acct[0][c] = MFMA16(as0, w0, acct[0][c]);
        acct[0][c] = MFMA16(ax0, w1, acct[0][c]);
        acct[1][c] = MFMA16(as1, w0, acct[1][c]);
        acct[1][c] = MFMA16(ax1, w1, acct[1][c]);
      }
    }
    #pragma unroll
    for (int c=0;c<4;++c){
      float tb = tcnb[c*16 + l15];
      #pragma unroll
      for (int g=0;g<2;++g)
      #pragma unroll
      for (int r=0;r<4;++r){
        float xr = bf2f(X[g*1152 + (quad*4+r)*72 + c*16 + l15]);
        T[g*1152 + (quad*4+r)*72 + c*16 + l15] =
            f2bf(fmaxf(acct[g][c][r]+tb, 0.f) + xr);
      }
    }
  }
  FENCE();

  // ---- Q pass: Q row-major -> Qb (over dead X) ----
  {
    f32x4 acc[2][4];
    #pragma unroll
    for (int g=0;g<2;++g)
    #pragma unroll
    for (int c=0;c<4;++c) acc[g][c]=z;
    #pragma unroll
    for (int kc=0;kc<2;++kc){
      bf16x8 t0 = ld8(T +        l15*72 + kc*32 + quad*8);
      bf16x8 t1 = ld8(T + 1152 + l15*72 + kc*32 + quad*8);
      #pragma unroll
      for (int c=0;c<4;++c){
        bf16x8 b = ld8(ws0 + O_WQ + (c*16 + l15)*64 + kc*32 + quad*8);
        acc[0][c] = MFMA16(t0, b, acc[0][c]);
        acc[1][c] = MFMA16(t1, b, acc[1][c]);
      }
    }
    #pragma unroll
    for (int c=0;c<4;++c)
    #pragma unroll
    for (int g=0;g<2;++g)
    #pragma unroll
    for (int r=0;r<4;++r)
      Qb[g*1152 + (quad*4+r)*72 + c*16 + l15] = f2bf(acc[g][c][r]);
  }

  // ---- K^T pass: swapped operands (A = O_WK = Wk^T, B = T rows) ->
  //      C = K^T[d][node], col==l15 -> shuffle straight into B-frags ----
  bf16x8 bK[2][4];
  {
    f32x4 kt[2][4];
    #pragma unroll
    for (int g=0;g<2;++g)
    #pragma unroll
    for (int c=0;c<4;++c) kt[g][c]=z;
    #pragma unroll
    for (int kc=0;kc<2;++kc){
      bf16x8 t0 = ld8(T +        l15*72 + kc*32 + quad*8);
      bf16x8 t1 = ld8(T + 1152 + l15*72 + kc*32 + quad*8);
      #pragma unroll
      for (int c=0;c<4;++c){
        bf16x8 aW = ld8(ws0 + O_WK + (c*16 + l15)*64 + kc*32 + quad*8);
        kt[0][c] = MFMA16(aW, t0, kt[0][c]);
        kt[1][c] = MFMA16(aW, t1, kt[1][c]);
      }
    }
    #pragma unroll
    for (int g=0;g<2;++g)
    #pragma unroll
    for (int c=0;c<4;++c){
      unsigned int p0 = pkbf2(kt[g][c][0], kt[g][c][1]);
      unsigned int p1 = pkbf2(kt[g][c][2], kt[g][c][3]);
      bf16x8 f = shfrag(p0,p1,laneA,laneB);
      bK[g][c] = (quad < 2) ? f : Z;       // K padded 16->32: zero upper half
    }
  }

  // ---- V pass: V C-layout (col=d) -> PV B-frags via shfrag (no LDS) ----
  bf16x8 bV[2][4];
  {
    f32x4 acc[2][4];
    #pragma unroll
    for (int g=0;g<2;++g)
    #pragma unroll
    for (int c=0;c<4;++c) acc[g][c]=z;
    #pragma unroll
    for (int kc=0;kc<2;++kc){
      bf16x8 t0 = ld8(T +        l15*72 + kc*32 + quad*8);
      bf16x8 t1 = ld8(T + 1152 + l15*72 + kc*32 + quad*8);
      #pragma unroll
      for (int c=0;c<4;++c){
        bf16x8 b = ld8(ws0 + O_WV + (c*16 + l15)*64 + kc*32 + quad*8);
        acc[0][c] = MFMA16(t0, b, acc[0][c]);
        acc[1][c] = MFMA16(t1, b, acc[1][c]);
      }
    }
    #pragma unroll
    for (int g=0;g<2;++g)
    #pragma unroll
    for (int c=0;c<4;++c){
      unsigned int p0 = pkbf2(acc[g][c][0], acc[g][c][1]);
      unsigned int p1 = pkbf2(acc[g][c][2], acc[g][c][3]);
      bV[g][c] = shfrag(p0,p1,laneA,laneB);  // garbage k>=16 killed by zero aP
    }
  }
  FENCE();

  // ---- S = (Q K^T)/4 per head; softmax across l15 lanes -> Pb (over T) ----
  {
    #pragma unroll
    for (int g=0;g<2;++g)
    #pragma unroll
    for (int h=0;h<4;++h){
      bf16x8 aQ = (quad < 2) ? ld8(Qb + g*1152 + l15*72 + h*16 + quad*8) : Z;
      f32x4 s4 = MFMA16(aQ, bK[g][h], z);
      #pragma unroll
      for (int r=0;r<4;++r){
        float s = s4[r]*0.25f;
        float m = s;
        m = fmaxf(m, __shfl_xor(m,1,64));
        m = fmaxf(m, __shfl_xor(m,2,64));
        m = fmaxf(m, __shfl_xor(m,4,64));
        m = fmaxf(m, __shfl_xor(m,8,64));
        float p = __expf(s-m);
        float su = p;
        su += __shfl_xor(su,1,64);
        su += __shfl_xor(su,2,64);
        su += __shfl_xor(su,4,64);
        su += __shfl_xor(su,8,64);
        Pb[g*1024 + (h*16 + quad*4 + r)*16 + l15] = f2bf(p/su);
      }
    }
  }
  FENCE();

  // ---- O = P@V per head; column mean over 16 nodes in-register -> OM ----
  {
    #pragma unroll
    for (int g=0;g<2;++g)
    #pragma unroll
    for (int h=0;h<4;++h){
      bf16x8 aP = (quad < 2) ? ld8(Pb + g*1024 + (h*16 + l15)*16 + quad*8) : Z;
      f32x4 o = MFMA16(aP, bV[g][h], z);
      float cs = o[0]+o[1]+o[2]+o[3];
      cs += __shfl_xor(cs, 16, 64);
      cs += __shfl_xor(cs, 32, 64);
      if (quad == 0) OMf[g*64 + h*16 + l15] = cs * (1.f/16.f);
    }
  }
  FENCE();

  // ---- feat = ((mean O) @ wo) @ wproj + bproj  (all fp32 scalar) ----
  {
    float t0 = 0.f, t1 = 0.f;
    #pragma unroll 8
    for (int d=0; d<64; ++d){
      float wv = wo[d*64 + lane];
      t0 += OMf[d]    * wv;
      t1 += OMf[64+d] * wv;
    }
    OMf[128+lane] = t0;
    OMf[192+lane] = t1;
    FENCE();
    float a00 = bproj[lane], a01 = bproj[lane+64];
    float a10 = a00, a11 = a01;
    #pragma unroll 8
    for (int m=0; m<64; ++m){
      float f0 = OMf[128+m], f1 = OMf[192+m];
      float w0 = wproj[m*128 + lane], w1 = wproj[m*128 + lane + 64];
      a00 += f0*w0; a01 += f0*w1;
      a10 += f1*w0; a11 += f1*w1;
    }
    feat[(size_t)gb0*128 + lane]        = f2bf(a00);
    feat[(size_t)gb0*128 + lane + 64]   = f2bf(a01);
    feat[(size_t)(gb0+1)*128 + lane]      = f2bf(a10);
    feat[(size_t)(gb0+1)*128 + lane + 64] = f2bf(a11);
  }
}

// ---------------------------------------------------------------------------
// per-variable fc heads: 1 wave = one kh x FOUR 16-row tiles (weight loads
// amortized 4x); 4096 waves total
// ---------------------------------------------------------------------------
__global__ __launch_bounds__(256,4) void k_heads(
  const unsigned short* __restrict__ ws0,
  const float* __restrict__ fc1b, const float* __restrict__ fc2b,
  float* __restrict__ pred)
{
  __shared__ alignas(16) unsigned short hh[4*4608];   // per-wave 4x[16][72]
  const int tid=threadIdx.x, w=tid>>6, lane=tid&63, quad=lane>>4, l15=lane&15;
  const int Wv = blockIdx.x*4 + w;          // 0..4095
  const int kh = Wv & 15, tq = Wv >> 4;     // tile quad 0..255
  const int rb = tq*64;
  unsigned short* hw = hh + w*4608;
  const unsigned short* featg = ws0 + O_FEAT;
  const unsigned short* W1 = ws0 + O_FC1 + kh*8192;
  const unsigned short* W2 = ws0 + O_FC2 + kh*2048;
  f32x4 z = {0.f,0.f,0.f,0.f};
  f32x4 acc[4][4];
  #pragma unroll
  for (int t=0;t<4;++t)
  #pragma unroll
  for (int c=0;c<4;++c) acc[t][c]=z;
  #pragma unroll
  for (int kc=0;kc<4;++kc){
    bf16x8 a[4];
    #pragma unroll
    for (int t=0;t<4;++t)
      a[t] = ld8(featg + (size_t)(rb + t*16 + l15)*128 + kc*32+quad*8);
    #pragma unroll
    for (int c=0;c<4;++c){
      bf16x8 b = ld8(W1 + (c*16+l15)*128 + kc*32+quad*8);
      #pragma unroll
      for (int t=0;t<4;++t)
        acc[t][c] = MFMA16(a[t], b, acc[t][c]);
    }
  }
  #pragma unroll
  for (int c=0;c<4;++c){
    float bb = fc1b[kh*64 + c*16+l15];
    #pragma unroll
    for (int t=0;t<4;++t)
    #pragma unroll
    for (int r=0;r<4;++r)
      hw[t*1152 + (quad*4+r)*72 + c*16+l15] = f2bf(fmaxf(acc[t][c][r]+bb, 0.f));
  }
  __threadfence_block();
  f32x4 acc2[4][2];
  #pragma unroll
  for (int t=0;t<4;++t)
  #pragma unroll
  for (int c=0;c<2;++c) acc2[t][c]=z;
  #pragma unroll
  for (int kc=0;kc<2;++kc){
    bf16x8 a[4];
    #pragma unroll
    for (int t=0;t<4;++t)
      a[t] = ld8(hw + t*1152 + l15*72 + kc*32+quad*8);
    #pragma unroll
    for (int c=0;c<2;++c){
      bf16x8 b = ld8(W2 + (c*16+l15)*64 + kc*32+quad*8);
      #pragma unroll
      for (int t=0;t<4;++t)
        acc2[t][c] = MFMA16(a[t], b, acc2[t][c]);
    }
  }
  #pragma unroll
  for (int c=0;c<2;++c){
    int col = c*16+l15;
    if (col < 24){
      float bb = fc2b[kh*24+col];
      #pragma unroll
      for (int t=0;t<4;++t)
      #pragma unroll
      for (int r=0;r<4;++r)
        pred[(size_t)kh*393216 + (size_t)(rb+t*16+quad*4+r)*24 + col] = acc2[t][c][r] + bb;
    }
  }
}

// yb output = y.reshape -> exact copy
__global__ __launch_bounds__(256) void k_copy(const float4* __restrict__ y,
                                              float4* __restrict__ o)
{
  int i = blockIdx.x*256 + threadIdx.x;   // exactly 1572864 float4s
  o[i] = y[i];
}

// ---------------------------------------------------------------------------
extern "C" void kernel_launch(void* const* d_in, const int* in_sizes, int n_in,
                              void* d_out, int out_size, void* d_ws, size_t ws_size,
                              hipStream_t stream) {
  const float* x    = (const float*)d_in[0];
  const float* y    = (const float*)d_in[1];
  const int*   ei   = (const int*)d_in[2];
  const float* w1l  = (const float*)d_in[4];
  const float* w1r  = (const float*)d_in[5];
  const float* b1   = (const float*)d_in[6];
  const float* w2l  = (const float*)d_in[7];
  const float* w2r  = (const float*)d_in[8];
  const float* b2   = (const float*)d_in[9];
  const float* w3l  = (const float*)d_in[10];
  const float* w3r  = (const float*)d_in[11];
  const float* b3   = (const float*)d_in[12];
  const float* tcnw = (const float*)d_in[13];
  const float* tcnb = (const float*)d_in[14];
  const float* wq   = (const float*)d_in[15];
  const float* wk   = (const float*)d_in[16];
  const float* wv   = (const float*)d_in[17];
  const float* wo   = (const float*)d_in[18];
  const float* wpr  = (const float*)d_in[19];
  const float* bpr  = (const float*)d_in[20];
  const float* fc1w = (const float*)d_in[21];
  const float* fc1b = (const float*)d_in[22];
  const float* fc2w = (const float*)d_in[23];
  const float* fc2b = (const float*)d_in[24];

  unsigned short* W = (unsigned short*)d_ws;
  float* out = (float*)d_out;

  k_prep<<<1120, 256, 0, stream>>>(w1l,w1r,w2l,w2r,w3l,w3r,tcnw,wq,wk,wv,wo,fc1w,fc2w,W);
  k_fused<<<NGR/8, 256, 0, stream>>>(x, ei + EDGES, b1,b2,b3,tcnb, wo, wpr, bpr, W, W + O_FEAT);
  k_heads<<<1024, 256, 0, stream>>>(W, fc1b, fc2b, out);
  k_copy<<<6144, 256, 0, stream>>>((const float4*)y, (float4*)(out + PRED_ELEMS));
}

// Round 4
// 606.191 us; speedup vs baseline: 1.3402x; 1.0716x over previous
//
#include <hip/hip_runtime.h>
#include <cstdint>
#include <cstddef>

// ---------------------------------------------------------------------------
// SSTAFormer round 6: kill BOTH L2-polluting streams (spill + x re-fetch).
//   - Evidence r5: WRITE 194->88 MB (spill halved) but FETCH 383->540 MB
//     (4-cg layer 1 re-read x 4x). Both streams evict the hot weights from
//     L2 -> each weight load in the per-MFMA chain costs HBM-class latency.
//   - x staged ONCE in registers as bf16 frags (xa[2][6], 48 VGPRs, live only
//     in layer 1). Layer-1 keeps 4 col-groups: peak ~88 regs < 128 cap.
//   - Attention restructured per-graph: bK[4]+bV[4] = 32 regs (was 64).
//   - Layer 2/3, TCN, k_heads(4-tile), k_prep, k_copy unchanged from r5.
// ---------------------------------------------------------------------------

typedef __attribute__((ext_vector_type(8))) __bf16 bf16x8;
typedef __attribute__((ext_vector_type(4))) float  f32x4;

#define MFMA16(a,b,c) __builtin_amdgcn_mfma_f32_16x16x32_bf16((a),(b),(c),0,0,0)
#define FENCE() __threadfence_block()

#define NGR    16384
#define EDGES  1048576
#define PRED_ELEMS (16*16384*24)

// workspace layout in ushort units
#define O_W1L 0               // [128][192]
#define O_W1R 24576
#define O_W2L 49152           // [128][128]
#define O_W2R 65536
#define O_W3L 81920           // [64][128]
#define O_W3R 90112
#define O_T0  98304           // [64 co][64 ci]  (tcn_w[...,0])
#define O_T1  102400
#define O_WQ  106496          // [64][64]
#define O_WK  110592
#define O_WV  114688
#define O_WO  118784
#define O_FC1 122880          // 16 x [64][128]
#define O_FC2 253952          // 16 x [32][64]
#define O_FEAT 286720         // [16384][128] bf16
#define PREP_TOT 286720

static __device__ __forceinline__ unsigned short f2bf(float f){
  unsigned int u = __builtin_bit_cast(unsigned int, f);
  u += 0x7FFFu + ((u >> 16) & 1u);            // RNE
  return (unsigned short)(u >> 16);
}
static __device__ __forceinline__ float bf2f(unsigned short h){
  return __builtin_bit_cast(float, (unsigned int)h << 16);
}
static __device__ __forceinline__ bf16x8 ld8(const unsigned short* p){
  return __builtin_bit_cast(bf16x8, *(const uint4*)p);   // 16B aligned by construction
}
static __device__ __forceinline__ bf16x8 zero8(){
  uint4 u = make_uint4(0u,0u,0u,0u);
  return __builtin_bit_cast(bf16x8, u);
}
// pack two f32 -> one dword of 2 bf16 (register-only)
static __device__ __forceinline__ unsigned int pkbf2(float a, float b){
  return (unsigned int)f2bf(a) | ((unsigned int)f2bf(b)<<16);
}
// build bf16x8 from 4 dwords (register-only)
static __device__ __forceinline__ bf16x8 u4bf(unsigned int a, unsigned int b,
                                              unsigned int c, unsigned int d){
  uint4 u = make_uint4(a,b,c,d);
  return __builtin_bit_cast(bf16x8, u);
}
// C-layout (row=4*quad'+r, col=l15) -> B-frag (k=8*quad+e, col=l15):
// frag dwords pulled from lanes 32*quad+l15 and 32*quad+l15+16 (garbage for
// quad>=2 -- always multiplied by a zeroed A operand).
static __device__ __forceinline__ bf16x8 shfrag(unsigned int p0, unsigned int p1,
                                                int laneA, int laneB){
  return u4bf((unsigned int)__shfl((int)p0, laneA, 64),
              (unsigned int)__shfl((int)p1, laneA, 64),
              (unsigned int)__shfl((int)p0, laneB, 64),
              (unsigned int)__shfl((int)p1, laneB, 64));
}
// A-fragment from global fp32 x row (K padded 168->192, W rows >=168 are zero)
static __device__ __forceinline__ bf16x8 xfrag(const float* __restrict__ xrow, int k0){
  int ks = (k0 < 168) ? k0 : 0;          // clamped lanes multiply zero W rows
  float4 f0 = *(const float4*)(xrow + ks);
  float4 f1 = *(const float4*)(xrow + ks + 4);
  return u4bf(pkbf2(f0.x,f0.y), pkbf2(f0.z,f0.w),
              pkbf2(f1.x,f1.y), pkbf2(f1.z,f1.w));
}

// ---------------------------------------------------------------------------
// weight prep (unchanged, verified correct)
// ---------------------------------------------------------------------------
__global__ __launch_bounds__(256) void k_prep(
  const float* __restrict__ w1l, const float* __restrict__ w1r,
  const float* __restrict__ w2l, const float* __restrict__ w2r,
  const float* __restrict__ w3l, const float* __restrict__ w3r,
  const float* __restrict__ tcnw,
  const float* __restrict__ wq, const float* __restrict__ wk,
  const float* __restrict__ wv, const float* __restrict__ wo,
  const float* __restrict__ fc1w, const float* __restrict__ fc2w,
  unsigned short* __restrict__ W)
{
  int idx = blockIdx.x*256 + threadIdx.x;
  if (idx >= PREP_TOT) return;
  float v;
  if      (idx <  24576){ int t=idx;        int n=t/192,k=t%192; v=(k<168)? w1l[k*128+n]:0.f; }
  else if (idx <  49152){ int t=idx- 24576; int n=t/192,k=t%192; v=(k<168)? w1r[k*128+n]:0.f; }
  else if (idx <  65536){ int t=idx- 49152; int n=t/128,k=t%128; v=w2l[k*128+n]; }
  else if (idx <  81920){ int t=idx- 65536; int n=t/128,k=t%128; v=w2r[k*128+n]; }
  else if (idx <  90112){ int t=idx- 81920; int n=t/128,k=t%128; v=w3l[k*64+n]; }
  else if (idx <  98304){ int t=idx- 90112; int n=t/128,k=t%128; v=w3r[k*64+n]; }
  else if (idx < 102400){ int t=idx- 98304; int n=t/64, k=t%64;  v=tcnw[(n*64+k)*2+0]; }
  else if (idx < 106496){ int t=idx-102400; int n=t/64, k=t%64;  v=tcnw[(n*64+k)*2+1]; }
  else if (idx < 110592){ int t=idx-106496; int n=t/64, k=t%64;  v=wq[k*64+n]; }
  else if (idx < 114688){ int t=idx-110592; int n=t/64, k=t%64;  v=wk[k*64+n]; }
  else if (idx < 118784){ int t=idx-114688; int n=t/64, k=t%64;  v=wv[k*64+n]; }
  else if (idx < 122880){ int t=idx-118784; int n=t/64, k=t%64;  v=wo[k*64+n]; }
  else if (idx < 253952){ int t=idx-122880; int kh=t/8192, r=t%8192, n=r/128, k=r%128;
                          v=fc1w[kh*8192 + k*64 + n]; }
  else                  { int t=idx-253952; int kh=t/2048, r=t%2048, n=r/64,  k=r%64;
                          v=(n<24)? fc2w[kh*1536 + k*24 + n] : 0.f; }
  W[idx] = f2bf(v);
}

// ---------------------------------------------------------------------------
// fused GNN + TCN + attention + proj : 1 wg = 8 graphs, 1 wave = 2 graphs
// Per-wave LDS arena 9216 B (ushort offsets), overlays ordered by program
// order + FENCE at phase boundaries (all LDS traffic is wave-private):
//   Hb [2][16][136] 0..4352    (SAGE h; layer-3 writes X only after all reads)
//   X  [2][16][72]  0..2304    over Hb head (dead after TCN residual re-read)
//   T  [2][16][72]  2304..4608 over Hb tail (T[g] dead after g's K/V passes)
//   Qb [2][16][72]  0..2304    over X       (Qb[g] dead after g's S)
//   Pb [2][4][16][16] 2304..4352 over T     (Pb[g] dead after g's PV)
//   OM [4][64] f32  0..512u    over Qb[0]   (col-means + om@wo staging)
// ---------------------------------------------------------------------------
__global__ __launch_bounds__(256,4) void k_fused(
  const float* __restrict__ x, const int* __restrict__ edst,
  const float* __restrict__ b1, const float* __restrict__ b2,
  const float* __restrict__ b3, const float* __restrict__ tcnb,
  const float* __restrict__ wo, const float* __restrict__ wproj,
  const float* __restrict__ bproj,
  const unsigned short* __restrict__ ws0, unsigned short* __restrict__ feat)
{
  __shared__ alignas(16) unsigned char pool[4*9216];
  const int tid=threadIdx.x, w=tid>>6, lane=tid&63, quad=lane>>4, l15=lane&15;
  unsigned short* AR = (unsigned short*)(pool + w*9216);
  const int gb0 = (blockIdx.x*4 + w)*2;           // first of this wave's 2 graphs

  unsigned short* Hb = AR;              // [2][16][136]
  unsigned short* X  = AR;              // [2][16][72]
  unsigned short* T  = AR + 2304;       // [2][16][72]
  unsigned short* Qb = AR;              // [2][16][72]
  unsigned short* Pb = AR + 2304;       // [2][4][16][16]
  float* OMf = (float*)AR;              // [4][64] f32

  const bf16x8 Z = zero8();
  const f32x4  z = {0.f,0.f,0.f,0.f};
  const int laneA = 32*quad + l15, laneB = laneA + 16;

  // ---- adjacency: A-frags built fully in registers via shuffles ----
  bf16x8 aA[2];
  #pragma unroll
  for (int g=0; g<2; ++g){
    int dl = edst[(gb0+g)*64 + lane] & 15;
    float c4[4]; float csum = 0.f;
    #pragma unroll
    for (int ss=0; ss<4; ++ss){
      int s = quad*4 + ss; int cc = 0;
      #pragma unroll
      for (int k=0;k<4;++k) cc += (__shfl(dl, s*4+k, 64) == l15) ? 1 : 0;
      c4[ss] = (float)cc; csum += (float)cc;
    }
    csum += __shfl_xor(csum, 16, 64);
    csum += __shfl_xor(csum, 32, 64);
    float ainv = 1.f / fmaxf(csum, 1.f);
    unsigned int p0 = pkbf2(c4[0]*ainv, c4[1]*ainv);
    unsigned int p1 = pkbf2(c4[2]*ainv, c4[3]*ainv);
    bf16x8 t = shfrag(p0, p1, laneA, laneB);
    aA[g] = (quad < 2) ? t : Z;           // exact zeros for k>=16
  }

  // ---- x staged ONCE: 12 A-frags in registers (dead after layer 1) ----
  const float* xr0 = x + (size_t)(gb0*16 + l15)*168;
  const float* xr1 = xr0 + 16*168;
  bf16x8 xa0[6], xa1[6];
  #pragma unroll
  for (int kc=0;kc<6;++kc){
    xa0[kc] = xfrag(xr0, kc*32 + quad*8);
    xa1[kc] = xfrag(xr1, kc*32 + quad*8);
  }

  // ---- SAGE layer 1 (K=192, merged u+v pass, 4 col-groups of 32) ----
  #pragma unroll
  for (int cg=0; cg<4; ++cg){
    f32x4 au[2][2], av_[2][2];
    #pragma unroll
    for (int g=0;g<2;++g)
    #pragma unroll
    for (int c=0;c<2;++c){ au[g][c]=z; av_[g][c]=z; }
    #pragma unroll
    for (int kc=0;kc<6;++kc){
      #pragma unroll
      for (int c=0;c<2;++c){
        const unsigned short* pb_ = ws0 + (size_t)(cg*32 + c*16 + l15)*192 + kc*32 + quad*8;
        bf16x8 bl = ld8(pb_ + O_W1L);
        bf16x8 br = ld8(pb_ + O_W1R);
        au[0][c]  = MFMA16(xa0[kc], bl, au[0][c]);  au[1][c]  = MFMA16(xa1[kc], bl, au[1][c]);
        av_[0][c] = MFMA16(xa0[kc], br, av_[0][c]); av_[1][c] = MFMA16(xa1[kc], br, av_[1][c]);
      }
    }
    #pragma unroll
    for (int g=0;g<2;++g)
    #pragma unroll
    for (int c=0;c<2;++c){
      unsigned int p0 = pkbf2(au[g][c][0], au[g][c][1]);
      unsigned int p1 = pkbf2(au[g][c][2], au[g][c][3]);
      av_[g][c] = MFMA16(aA[g], shfrag(p0,p1,laneA,laneB), av_[g][c]);
    }
    #pragma unroll
    for (int c=0;c<2;++c){
      float bb = b1[cg*32 + c*16 + l15];
      #pragma unroll
      for (int g=0;g<2;++g)
      #pragma unroll
      for (int r=0;r<4;++r)
        Hb[g*2176 + (quad*4+r)*136 + cg*32 + c*16 + l15] = f2bf(fmaxf(av_[g][c][r]+bb, 0.f));
    }
  }
  FENCE();

  // ---- SAGE layer 2 (K=128, 4 col-groups of 32, two-pass, staged writeback) ----
  {
    ushort4 os[4][2][2];                        // [cg][g][c]
    #pragma unroll
    for (int cg=0; cg<4; ++cg){
      bf16x8 uf[2][2];
      { // pass u
        f32x4 au[2][2];
        #pragma unroll
        for (int g=0;g<2;++g)
        #pragma unroll
        for (int c=0;c<2;++c) au[g][c]=z;
        #pragma unroll
        for (int kc=0;kc<4;++kc){
          bf16x8 a0 = ld8(Hb +        l15*136 + kc*32 + quad*8);
          bf16x8 a1 = ld8(Hb + 2176 + l15*136 + kc*32 + quad*8);
          #pragma unroll
          for (int c=0;c<2;++c){
            bf16x8 bl = ld8(ws0 + O_W2L + (cg*32 + c*16 + l15)*128 + kc*32 + quad*8);
            au[0][c] = MFMA16(a0, bl, au[0][c]);
            au[1][c] = MFMA16(a1, bl, au[1][c]);
          }
        }
        #pragma unroll
        for (int g=0;g<2;++g)
        #pragma unroll
        for (int c=0;c<2;++c){
          unsigned int p0 = pkbf2(au[g][c][0], au[g][c][1]);
          unsigned int p1 = pkbf2(au[g][c][2], au[g][c][3]);
          uf[g][c] = shfrag(p0,p1,laneA,laneB);
        }
      }
      { // pass v + A@u
        f32x4 av_[2][2];
        #pragma unroll
        for (int g=0;g<2;++g)
        #pragma unroll
        for (int c=0;c<2;++c) av_[g][c]=z;
        #pragma unroll
        for (int kc=0;kc<4;++kc){
          bf16x8 a0 = ld8(Hb +        l15*136 + kc*32 + quad*8);
          bf16x8 a1 = ld8(Hb + 2176 + l15*136 + kc*32 + quad*8);
          #pragma unroll
          for (int c=0;c<2;++c){
            bf16x8 br = ld8(ws0 + O_W2R + (cg*32 + c*16 + l15)*128 + kc*32 + quad*8);
            av_[0][c] = MFMA16(a0, br, av_[0][c]);
            av_[1][c] = MFMA16(a1, br, av_[1][c]);
          }
        }
        #pragma unroll
        for (int g=0;g<2;++g)
        #pragma unroll
        for (int c=0;c<2;++c)
          av_[g][c] = MFMA16(aA[g], uf[g][c], av_[g][c]);
        #pragma unroll
        for (int c=0;c<2;++c){
          float bb = b2[cg*32 + c*16 + l15];
          #pragma unroll
          for (int g=0;g<2;++g){
            ushort4 p;
            p.x = f2bf(fmaxf(av_[g][c][0]+bb, 0.f));
            p.y = f2bf(fmaxf(av_[g][c][1]+bb, 0.f));
            p.z = f2bf(fmaxf(av_[g][c][2]+bb, 0.f));
            p.w = f2bf(fmaxf(av_[g][c][3]+bb, 0.f));
            os[cg][g][c] = p;
          }
        }
      }
    }
    // in-place writeback after ALL reads of all col-groups
    #pragma unroll
    for (int cg=0; cg<4; ++cg)
    #pragma unroll
    for (int g=0; g<2; ++g)
    #pragma unroll
    for (int c=0; c<2; ++c){
      unsigned short* bp = Hb + g*2176 + cg*32 + c*16 + l15;
      ushort4 p = os[cg][g][c];
      bp[(quad*4+0)*136] = p.x;
      bp[(quad*4+1)*136] = p.y;
      bp[(quad*4+2)*136] = p.z;
      bp[(quad*4+3)*136] = p.w;
    }
  }
  FENCE();

  // ---- SAGE layer 3 (64 cols, no relu) -> X ----
  {
    bf16x8 uf[2][4];
    { // pass u
      f32x4 au[2][4];
      #pragma unroll
      for (int g=0;g<2;++g)
      #pragma unroll
      for (int c=0;c<4;++c) au[g][c]=z;
      #pragma unroll
      for (int kc=0;kc<4;++kc){
        bf16x8 a0 = ld8(Hb +        l15*136 + kc*32 + quad*8);
        bf16x8 a1 = ld8(Hb + 2176 + l15*136 + kc*32 + quad*8);
        #pragma unroll
        for (int c=0;c<4;++c){
          bf16x8 bl = ld8(ws0 + O_W3L + (c*16 + l15)*128 + kc*32 + quad*8);
          au[0][c] = MFMA16(a0, bl, au[0][c]);
          au[1][c] = MFMA16(a1, bl, au[1][c]);
        }
      }
      #pragma unroll
      for (int g=0;g<2;++g)
      #pragma unroll
      for (int c=0;c<4;++c){
        unsigned int p0 = pkbf2(au[g][c][0], au[g][c][1]);
        unsigned int p1 = pkbf2(au[g][c][2], au[g][c][3]);
        uf[g][c] = shfrag(p0,p1,laneA,laneB);
      }
    }
    { // pass v + A@u -> X (writes only after all Hb reads)
      f32x4 av_[2][4];
      #pragma unroll
      for (int g=0;g<2;++g)
      #pragma unroll
      for (int c=0;c<4;++c) av_[g][c]=z;
      #pragma unroll
      for (int kc=0;kc<4;++kc){
        bf16x8 a0 = ld8(Hb +        l15*136 + kc*32 + quad*8);
        bf16x8 a1 = ld8(Hb + 2176 + l15*136 + kc*32 + quad*8);
        #pragma unroll
        for (int c=0;c<4;++c){
          bf16x8 br = ld8(ws0 + O_W3R + (c*16 + l15)*128 + kc*32 + quad*8);
          av_[0][c] = MFMA16(a0, br, av_[0][c]);
          av_[1][c] = MFMA16(a1, br, av_[1][c]);
        }
      }
      #pragma unroll
      for (int g=0;g<2;++g)
      #pragma unroll
      for (int c=0;c<4;++c)
        av_[g][c] = MFMA16(aA[g], uf[g][c], av_[g][c]);
      #pragma unroll
      for (int c=0;c<4;++c){
        float bb = b3[c*16 + l15];
        #pragma unroll
        for (int g=0;g<2;++g)
        #pragma unroll
        for (int r=0;r<4;++r)
          X[g*1152 + (quad*4+r)*72 + c*16 + l15] = f2bf(av_[g][c][r] + bb);
      }
    }
  }
  FENCE();

  // ---- TCN: t = relu(Xshift@W0 + X@W1 + b) + X  (residual re-read from X) ----
  {
    f32x4 acct[2][4];
    #pragma unroll
    for (int g=0;g<2;++g)
    #pragma unroll
    for (int c=0;c<4;++c) acct[g][c]=z;
    #pragma unroll
    for (int kc=0;kc<2;++kc){
      bf16x8 ax0 = ld8(X +        l15*72 + kc*32 + quad*8);
      bf16x8 ax1 = ld8(X + 1152 + l15*72 + kc*32 + quad*8);
      bf16x8 as0 = (l15>0) ? ld8(X +        (l15-1)*72 + kc*32 + quad*8) : Z;
      bf16x8 as1 = (l15>0) ? ld8(X + 1152 + (l15-1)*72 + kc*32 + quad*8) : Z;
      #pragma unroll
      for (int c=0;c<4;++c){
        bf16x8 w0 = ld8(ws0 + O_T0 + (c*16 + l15)*64 + kc*32 + quad*8);
        bf16x8 w1 = ld8(ws0 + O_T1 + (c*16 + l15)*64 + kc*32 + quad*8);
        acct[0][c] = MFMA16(as0, w0, acct[0][c]);
        acct[0][c] = MFMA16(ax0, w1, acct[0][c]);
        acct[1][c] = MFMA16(as1, w0, acct[1][c]);
        acct[1][c] = MFMA16(ax1, w1, acct[1][c]);
      }
    }
    #pragma unroll
    for (int c=0;c<4;++c){
      float tb = tcnb[c*16 + l15];
      #pragma unroll
      for (int g=0;g<2;++g)
      #pragma unroll
      for (int r=0;r<4;++r){
        float xr = bf2f(X[g*1152 + (quad*4+r)*72 + c*16 + l15]);
        T[g*1152 + (quad*4+r)*72 + c*16 + l15] =
            f2bf(fmaxf(acct[g][c][r]+tb, 0.f) + xr);
      }
    }
  }
  FENCE();

  // ---- Q pass: Q row-major -> Qb (over dead X) ----
  {
    f32x4 acc[2][4];
    #pragma unroll
    for (int g=0;g<2;++g)
    #pragma unroll
    for (int c=0;c<4;++c) acc[g][c]=z;
    #pragma unroll
    for (int kc=0;kc<2;++kc){
      bf16x8 t0 = ld8(T +        l15*72 + kc*32 + quad*8);
      bf16x8 t1 = ld8(T + 1152 + l15*72 + kc*32 + quad*8);
      #pragma unroll
      for (int c=0;c<4;++c){
        bf16x8 b = ld8(ws0 + O_WQ + (c*16 + l15)*64 + kc*32 + quad*8);
        acc[0][c] = MFMA16(t0, b, acc[0][c]);
        acc[1][c] = MFMA16(t1, b, acc[1][c]);
      }
    }
    #pragma unroll
    for (int c=0;c<4;++c)
    #pragma unroll
    for (int g=0;g<2;++g)
    #pragma unroll
    for (int r=0;r<4;++r)
      Qb[g*1152 + (quad*4+r)*72 + c*16 + l15] = f2bf(acc[g][c][r]);
  }
  FENCE();

  // ---- attention per graph: K^T, V, S+softmax, PV (bK+bV = 32 regs) ----
  #pragma unroll
  for (int g=0; g<2; ++g){
    const unsigned short* Tg  = T  + g*1152;
    unsigned short*       Pbg = Pb + g*1024;

    // K^T pass: swapped operands (A = O_WK = Wk^T, B = T rows) ->
    // C = K^T[d][node], col==l15 -> shuffle straight into B-frags
    bf16x8 bK[4];
    {
      f32x4 kt[4] = {z,z,z,z};
      #pragma unroll
      for (int kc=0;kc<2;++kc){
        bf16x8 tg = ld8(Tg + l15*72 + kc*32 + quad*8);
        #pragma unroll
        for (int c=0;c<4;++c){
          bf16x8 aW = ld8(ws0 + O_WK + (c*16 + l15)*64 + kc*32 + quad*8);
          kt[c] = MFMA16(aW, tg, kt[c]);
        }
      }
      #pragma unroll
      for (int c=0;c<4;++c){
        unsigned int p0 = pkbf2(kt[c][0], kt[c][1]);
        unsigned int p1 = pkbf2(kt[c][2], kt[c][3]);
        bf16x8 f = shfrag(p0,p1,laneA,laneB);
        bK[c] = (quad < 2) ? f : Z;       // K padded 16->32: zero upper half
      }
    }

    // V pass: V C-layout (col=d) -> PV B-frags via shfrag (no LDS)
    bf16x8 bV[4];
    {
      f32x4 acc[4] = {z,z,z,z};
      #pragma unroll
      for (int kc=0;kc<2;++kc){
        bf16x8 tg = ld8(Tg + l15*72 + kc*32 + quad*8);
        #pragma unroll
        for (int c=0;c<4;++c){
          bf16x8 b = ld8(ws0 + O_WV + (c*16 + l15)*64 + kc*32 + quad*8);
          acc[c] = MFMA16(tg, b, acc[c]);
        }
      }
      #pragma unroll
      for (int c=0;c<4;++c){
        unsigned int p0 = pkbf2(acc[c][0], acc[c][1]);
        unsigned int p1 = pkbf2(acc[c][2], acc[c][3]);
        bV[c] = shfrag(p0,p1,laneA,laneB);  // garbage k>=16 killed by zero aP
      }
    }
    FENCE();   // T[g] dead; Pb[g] (over T) safe to write

    // S = (Q K^T)/4 per head; softmax across l15 lanes -> Pb[g]
    #pragma unroll
    for (int h=0;h<4;++h){
      bf16x8 aQ = (quad < 2) ? ld8(Qb + g*1152 + l15*72 + h*16 + quad*8) : Z;
      f32x4 s4 = MFMA16(aQ, bK[h], z);
      #pragma unroll
      for (int r=0;r<4;++r){
        float s = s4[r]*0.25f;
        float m = s;
        m = fmaxf(m, __shfl_xor(m,1,64));
        m = fmaxf(m, __shfl_xor(m,2,64));
        m = fmaxf(m, __shfl_xor(m,4,64));
        m = fmaxf(m, __shfl_xor(m,8,64));
        float p = __expf(s-m);
        float su = p;
        su += __shfl_xor(su,1,64);
        su += __shfl_xor(su,2,64);
        su += __shfl_xor(su,4,64);
        su += __shfl_xor(su,8,64);
        Pbg[(h*16 + quad*4 + r)*16 + l15] = f2bf(p/su);
      }
    }
    FENCE();

    // O = P@V per head; column mean over 16 nodes in-register -> OM
    #pragma unroll
    for (int h=0;h<4;++h){
      bf16x8 aP = (quad < 2) ? ld8(Pbg + (h*16 + l15)*16 + quad*8) : Z;
      f32x4 o = MFMA16(aP, bV[h], z);
      float cs = o[0]+o[1]+o[2]+o[3];
      cs += __shfl_xor(cs, 16, 64);
      cs += __shfl_xor(cs, 32, 64);
      if (quad == 0) OMf[g*64 + h*16 + l15] = cs * (1.f/16.f);
    }
    FENCE();
  }

  // ---- feat = ((mean O) @ wo) @ wproj + bproj  (all fp32 scalar) ----
  {
    float t0 = 0.f, t1 = 0.f;
    #pragma unroll 8
    for (int d=0; d<64; ++d){
      float wv = wo[d*64 + lane];
      t0 += OMf[d]    * wv;
      t1 += OMf[64+d] * wv;
    }
    OMf[128+lane] = t0;
    OMf[192+lane] = t1;
    FENCE();
    float a00 = bproj[lane], a01 = bproj[lane+64];
    float a10 = a00, a11 = a01;
    #pragma unroll 8
    for (int m=0; m<64; ++m){
      float f0 = OMf[128+m], f1 = OMf[192+m];
      float w0 = wproj[m*128 + lane], w1 = wproj[m*128 + lane + 64];
      a00 += f0*w0; a01 += f0*w1;
      a10 += f1*w0; a11 += f1*w1;
    }
    feat[(size_t)gb0*128 + lane]        = f2bf(a00);
    feat[(size_t)gb0*128 + lane + 64]   = f2bf(a01);
    feat[(size_t)(gb0+1)*128 + lane]      = f2bf(a10);
    feat[(size_t)(gb0+1)*128 + lane + 64] = f2bf(a11);
  }
}

// ---------------------------------------------------------------------------
// per-variable fc heads: 1 wave = one kh x FOUR 16-row tiles (weight loads
// amortized 4x); 4096 waves total
// ---------------------------------------------------------------------------
__global__ __launch_bounds__(256,4) void k_heads(
  const unsigned short* __restrict__ ws0,
  const float* __restrict__ fc1b, const float* __restrict__ fc2b,
  float* __restrict__ pred)
{
  __shared__ alignas(16) unsigned short hh[4*4608];   // per-wave 4x[16][72]
  const int tid=threadIdx.x, w=tid>>6, lane=tid&63, quad=lane>>4, l15=lane&15;
  const int Wv = blockIdx.x*4 + w;          // 0..4095
  const int kh = Wv & 15, tq = Wv >> 4;     // tile quad 0..255
  const int rb = tq*64;
  unsigned short* hw = hh + w*4608;
  const unsigned short* featg = ws0 + O_FEAT;
  const unsigned short* W1 = ws0 + O_FC1 + kh*8192;
  const unsigned short* W2 = ws0 + O_FC2 + kh*2048;
  f32x4 z = {0.f,0.f,0.f,0.f};
  f32x4 acc[4][4];
  #pragma unroll
  for (int t=0;t<4;++t)
  #pragma unroll
  for (int c=0;c<4;++c) acc[t][c]=z;
  #pragma unroll
  for (int kc=0;kc<4;++kc){
    bf16x8 a[4];
    #pragma unroll
    for (int t=0;t<4;++t)
      a[t] = ld8(featg + (size_t)(rb + t*16 + l15)*128 + kc*32+quad*8);
    #pragma unroll
    for (int c=0;c<4;++c){
      bf16x8 b = ld8(W1 + (c*16+l15)*128 + kc*32+quad*8);
      #pragma unroll
      for (int t=0;t<4;++t)
        acc[t][c] = MFMA16(a[t], b, acc[t][c]);
    }
  }
  #pragma unroll
  for (int c=0;c<4;++c){
    float bb = fc1b[kh*64 + c*16+l15];
    #pragma unroll
    for (int t=0;t<4;++t)
    #pragma unroll
    for (int r=0;r<4;++r)
      hw[t*1152 + (quad*4+r)*72 + c*16+l15] = f2bf(fmaxf(acc[t][c][r]+bb, 0.f));
  }
  __threadfence_block();
  f32x4 acc2[4][2];
  #pragma unroll
  for (int t=0;t<4;++t)
  #pragma unroll
  for (int c=0;c<2;++c) acc2[t][c]=z;
  #pragma unroll
  for (int kc=0;kc<2;++kc){
    bf16x8 a[4];
    #pragma unroll
    for (int t=0;t<4;++t)
      a[t] = ld8(hw + t*1152 + l15*72 + kc*32+quad*8);
    #pragma unroll
    for (int c=0;c<2;++c){
      bf16x8 b = ld8(W2 + (c*16+l15)*64 + kc*32+quad*8);
      #pragma unroll
      for (int t=0;t<4;++t)
        acc2[t][c] = MFMA16(a[t], b, acc2[t][c]);
    }
  }
  #pragma unroll
  for (int c=0;c<2;++c){
    int col = c*16+l15;
    if (col < 24){
      float bb = fc2b[kh*24+col];
      #pragma unroll
      for (int t=0;t<4;++t)
      #pragma unroll
      for (int r=0;r<4;++r)
        pred[(size_t)kh*393216 + (size_t)(rb+t*16+quad*4+r)*24 + col] = acc2[t][c][r] + bb;
    }
  }
}

// yb output = y.reshape -> exact copy
__global__ __launch_bounds__(256) void k_copy(const float4* __restrict__ y,
                                              float4* __restrict__ o)
{
  int i = blockIdx.x*256 + threadIdx.x;   // exactly 1572864 float4s
  o[i] = y[i];
}

// ---------------------------------------------------------------------------
extern "C" void kernel_launch(void* const* d_in, const int* in_sizes, int n_in,
                              void* d_out, int out_size, void* d_ws, size_t ws_size,
                              hipStream_t stream) {
  const float* x    = (const float*)d_in[0];
  const float* y    = (const float*)d_in[1];
  const int*   ei   = (const int*)d_in[2];
  const float* w1l  = (const float*)d_in[4];
  const float* w1r  = (const float*)d_in[5];
  const float* b1   = (const float*)d_in[6];
  const float* w2l  = (const float*)d_in[7];
  const float* w2r  = (const float*)d_in[8];
  const float* b2   = (const float*)d_in[9];
  const float* w3l  = (const float*)d_in[10];
  const float* w3r  = (const float*)d_in[11];
  const float* b3   = (const float*)d_in[12];
  const float* tcnw = (const float*)d_in[13];
  const float* tcnb = (const float*)d_in[14];
  const float* wq   = (const float*)d_in[15];
  const float* wk   = (const float*)d_in[16];
  const float* wv   = (const float*)d_in[17];
  const float* wo   = (const float*)d_in[18];
  const float* wpr  = (const float*)d_in[19];
  const float* bpr  = (const float*)d_in[20];
  const float* fc1w = (const float*)d_in[21];
  const float* fc1b = (const float*)d_in[22];
  const float* fc2w = (const float*)d_in[23];
  const float* fc2b = (const float*)d_in[24];

  unsigned short* W = (unsigned short*)d_ws;
  float* out = (float*)d_out;

  k_prep<<<1120, 256, 0, stream>>>(w1l,w1r,w2l,w2r,w3l,w3r,tcnw,wq,wk,wv,wo,fc1w,fc2w,W);
  k_fused<<<NGR/8, 256, 0, stream>>>(x, ei + EDGES, b1,b2,b3,tcnb, wo, wpr, bpr, W, W + O_FEAT);
  k_heads<<<1024, 256, 0, stream>>>(W, fc1b, fc2b, out);
  k_copy<<<6144, 256, 0, stream>>>((const float4*)y, (float4*)(out + PRED_ELEMS));
}

// Round 5
// 582.492 us; speedup vs baseline: 1.3947x; 1.0407x over previous
//
#include <hip/hip_runtime.h>
#include <cstdint>
#include <cstddef>

// ---------------------------------------------------------------------------
// SSTAFormer round 7: register headroom (k_fused) + LDS weight cache (k_heads).
//   - k_fused: (256,3) -> VGPR cap ~170 (was 128). r6 evidence: 72 MB spill
//     + ~600 cyc/load unpipelined chain at the 128 cap. Occ 16->12 waves/CU,
//     but per-wave chain should shorten >>4/3x. Code otherwise identical.
//   - k_heads: 1 wg = 1 kh; W1/W2 staged once in padded LDS ([64][136],
//     [32][72]) shared by 4 waves x 2 tiles; 2048 blocks = 8192 waves.
//     Weight loads leave the per-wave global-latency chain.
// ---------------------------------------------------------------------------

typedef __attribute__((ext_vector_type(8))) __bf16 bf16x8;
typedef __attribute__((ext_vector_type(4))) float  f32x4;

#define MFMA16(a,b,c) __builtin_amdgcn_mfma_f32_16x16x32_bf16((a),(b),(c),0,0,0)
#define FENCE() __threadfence_block()

#define NGR    16384
#define EDGES  1048576
#define PRED_ELEMS (16*16384*24)

// workspace layout in ushort units
#define O_W1L 0               // [128][192]
#define O_W1R 24576
#define O_W2L 49152           // [128][128]
#define O_W2R 65536
#define O_W3L 81920           // [64][128]
#define O_W3R 90112
#define O_T0  98304           // [64 co][64 ci]  (tcn_w[...,0])
#define O_T1  102400
#define O_WQ  106496          // [64][64]
#define O_WK  110592
#define O_WV  114688
#define O_WO  118784
#define O_FC1 122880          // 16 x [64][128]
#define O_FC2 253952          // 16 x [32][64]
#define O_FEAT 286720         // [16384][128] bf16
#define PREP_TOT 286720

static __device__ __forceinline__ unsigned short f2bf(float f){
  unsigned int u = __builtin_bit_cast(unsigned int, f);
  u += 0x7FFFu + ((u >> 16) & 1u);            // RNE
  return (unsigned short)(u >> 16);
}
static __device__ __forceinline__ float bf2f(unsigned short h){
  return __builtin_bit_cast(float, (unsigned int)h << 16);
}
static __device__ __forceinline__ bf16x8 ld8(const unsigned short* p){
  return __builtin_bit_cast(bf16x8, *(const uint4*)p);   // 16B aligned by construction
}
static __device__ __forceinline__ bf16x8 zero8(){
  uint4 u = make_uint4(0u,0u,0u,0u);
  return __builtin_bit_cast(bf16x8, u);
}
// pack two f32 -> one dword of 2 bf16 (register-only)
static __device__ __forceinline__ unsigned int pkbf2(float a, float b){
  return (unsigned int)f2bf(a) | ((unsigned int)f2bf(b)<<16);
}
// build bf16x8 from 4 dwords (register-only)
static __device__ __forceinline__ bf16x8 u4bf(unsigned int a, unsigned int b,
                                              unsigned int c, unsigned int d){
  uint4 u = make_uint4(a,b,c,d);
  return __builtin_bit_cast(bf16x8, u);
}
// C-layout (row=4*quad'+r, col=l15) -> B-frag (k=8*quad+e, col=l15):
// frag dwords pulled from lanes 32*quad+l15 and 32*quad+l15+16 (garbage for
// quad>=2 -- always multiplied by a zeroed A operand).
static __device__ __forceinline__ bf16x8 shfrag(unsigned int p0, unsigned int p1,
                                                int laneA, int laneB){
  return u4bf((unsigned int)__shfl((int)p0, laneA, 64),
              (unsigned int)__shfl((int)p1, laneA, 64),
              (unsigned int)__shfl((int)p0, laneB, 64),
              (unsigned int)__shfl((int)p1, laneB, 64));
}
// A-fragment from global fp32 x row (K padded 168->192, W rows >=168 are zero)
static __device__ __forceinline__ bf16x8 xfrag(const float* __restrict__ xrow, int k0){
  int ks = (k0 < 168) ? k0 : 0;          // clamped lanes multiply zero W rows
  float4 f0 = *(const float4*)(xrow + ks);
  float4 f1 = *(const float4*)(xrow + ks + 4);
  return u4bf(pkbf2(f0.x,f0.y), pkbf2(f0.z,f0.w),
              pkbf2(f1.x,f1.y), pkbf2(f1.z,f1.w));
}

// ---------------------------------------------------------------------------
// weight prep (unchanged, verified correct)
// ---------------------------------------------------------------------------
__global__ __launch_bounds__(256) void k_prep(
  const float* __restrict__ w1l, const float* __restrict__ w1r,
  const float* __restrict__ w2l, const float* __restrict__ w2r,
  const float* __restrict__ w3l, const float* __restrict__ w3r,
  const float* __restrict__ tcnw,
  const float* __restrict__ wq, const float* __restrict__ wk,
  const float* __restrict__ wv, const float* __restrict__ wo,
  const float* __restrict__ fc1w, const float* __restrict__ fc2w,
  unsigned short* __restrict__ W)
{
  int idx = blockIdx.x*256 + threadIdx.x;
  if (idx >= PREP_TOT) return;
  float v;
  if      (idx <  24576){ int t=idx;        int n=t/192,k=t%192; v=(k<168)? w1l[k*128+n]:0.f; }
  else if (idx <  49152){ int t=idx- 24576; int n=t/192,k=t%192; v=(k<168)? w1r[k*128+n]:0.f; }
  else if (idx <  65536){ int t=idx- 49152; int n=t/128,k=t%128; v=w2l[k*128+n]; }
  else if (idx <  81920){ int t=idx- 65536; int n=t/128,k=t%128; v=w2r[k*128+n]; }
  else if (idx <  90112){ int t=idx- 81920; int n=t/128,k=t%128; v=w3l[k*64+n]; }
  else if (idx <  98304){ int t=idx- 90112; int n=t/128,k=t%128; v=w3r[k*64+n]; }
  else if (idx < 102400){ int t=idx- 98304; int n=t/64, k=t%64;  v=tcnw[(n*64+k)*2+0]; }
  else if (idx < 106496){ int t=idx-102400; int n=t/64, k=t%64;  v=tcnw[(n*64+k)*2+1]; }
  else if (idx < 110592){ int t=idx-106496; int n=t/64, k=t%64;  v=wq[k*64+n]; }
  else if (idx < 114688){ int t=idx-110592; int n=t/64, k=t%64;  v=wk[k*64+n]; }
  else if (idx < 118784){ int t=idx-114688; int n=t/64, k=t%64;  v=wv[k*64+n]; }
  else if (idx < 122880){ int t=idx-118784; int n=t/64, k=t%64;  v=wo[k*64+n]; }
  else if (idx < 253952){ int t=idx-122880; int kh=t/8192, r=t%8192, n=r/128, k=r%128;
                          v=fc1w[kh*8192 + k*64 + n]; }
  else                  { int t=idx-253952; int kh=t/2048, r=t%2048, n=r/64,  k=r%64;
                          v=(n<24)? fc2w[kh*1536 + k*24 + n] : 0.f; }
  W[idx] = f2bf(v);
}

// ---------------------------------------------------------------------------
// fused GNN + TCN + attention + proj : 1 wg = 8 graphs, 1 wave = 2 graphs
// Per-wave LDS arena 9216 B (ushort offsets), overlays ordered by program
// order + FENCE at phase boundaries (all LDS traffic is wave-private):
//   Hb [2][16][136] 0..4352    (SAGE h; layer-3 writes X only after all reads)
//   X  [2][16][72]  0..2304    over Hb head (dead after TCN residual re-read)
//   T  [2][16][72]  2304..4608 over Hb tail (T[g] dead after g's K/V passes)
//   Qb [2][16][72]  0..2304    over X       (Qb[g] dead after g's S)
//   Pb [2][4][16][16] 2304..4352 over T     (Pb[g] dead after g's PV)
//   OM [4][64] f32  0..512u    over Qb[0]   (col-means + om@wo staging)
// ---------------------------------------------------------------------------
__global__ __launch_bounds__(256,3) void k_fused(
  const float* __restrict__ x, const int* __restrict__ edst,
  const float* __restrict__ b1, const float* __restrict__ b2,
  const float* __restrict__ b3, const float* __restrict__ tcnb,
  const float* __restrict__ wo, const float* __restrict__ wproj,
  const float* __restrict__ bproj,
  const unsigned short* __restrict__ ws0, unsigned short* __restrict__ feat)
{
  __shared__ alignas(16) unsigned char pool[4*9216];
  const int tid=threadIdx.x, w=tid>>6, lane=tid&63, quad=lane>>4, l15=lane&15;
  unsigned short* AR = (unsigned short*)(pool + w*9216);
  const int gb0 = (blockIdx.x*4 + w)*2;           // first of this wave's 2 graphs

  unsigned short* Hb = AR;              // [2][16][136]
  unsigned short* X  = AR;              // [2][16][72]
  unsigned short* T  = AR + 2304;       // [2][16][72]
  unsigned short* Qb = AR;              // [2][16][72]
  unsigned short* Pb = AR + 2304;       // [2][4][16][16]
  float* OMf = (float*)AR;              // [4][64] f32

  const bf16x8 Z = zero8();
  const f32x4  z = {0.f,0.f,0.f,0.f};
  const int laneA = 32*quad + l15, laneB = laneA + 16;

  // ---- adjacency: A-frags built fully in registers via shuffles ----
  bf16x8 aA[2];
  #pragma unroll
  for (int g=0; g<2; ++g){
    int dl = edst[(gb0+g)*64 + lane] & 15;
    float c4[4]; float csum = 0.f;
    #pragma unroll
    for (int ss=0; ss<4; ++ss){
      int s = quad*4 + ss; int cc = 0;
      #pragma unroll
      for (int k=0;k<4;++k) cc += (__shfl(dl, s*4+k, 64) == l15) ? 1 : 0;
      c4[ss] = (float)cc; csum += (float)cc;
    }
    csum += __shfl_xor(csum, 16, 64);
    csum += __shfl_xor(csum, 32, 64);
    float ainv = 1.f / fmaxf(csum, 1.f);
    unsigned int p0 = pkbf2(c4[0]*ainv, c4[1]*ainv);
    unsigned int p1 = pkbf2(c4[2]*ainv, c4[3]*ainv);
    bf16x8 t = shfrag(p0, p1, laneA, laneB);
    aA[g] = (quad < 2) ? t : Z;           // exact zeros for k>=16
  }

  // ---- x staged ONCE: 12 A-frags in registers (dead after layer 1) ----
  const float* xr0 = x + (size_t)(gb0*16 + l15)*168;
  const float* xr1 = xr0 + 16*168;
  bf16x8 xa0[6], xa1[6];
  #pragma unroll
  for (int kc=0;kc<6;++kc){
    xa0[kc] = xfrag(xr0, kc*32 + quad*8);
    xa1[kc] = xfrag(xr1, kc*32 + quad*8);
  }

  // ---- SAGE layer 1 (K=192, merged u+v pass, 4 col-groups of 32) ----
  #pragma unroll
  for (int cg=0; cg<4; ++cg){
    f32x4 au[2][2], av_[2][2];
    #pragma unroll
    for (int g=0;g<2;++g)
    #pragma unroll
    for (int c=0;c<2;++c){ au[g][c]=z; av_[g][c]=z; }
    #pragma unroll
    for (int kc=0;kc<6;++kc){
      #pragma unroll
      for (int c=0;c<2;++c){
        const unsigned short* pb_ = ws0 + (size_t)(cg*32 + c*16 + l15)*192 + kc*32 + quad*8;
        bf16x8 bl = ld8(pb_ + O_W1L);
        bf16x8 br = ld8(pb_ + O_W1R);
        au[0][c]  = MFMA16(xa0[kc], bl, au[0][c]);  au[1][c]  = MFMA16(xa1[kc], bl, au[1][c]);
        av_[0][c] = MFMA16(xa0[kc], br, av_[0][c]); av_[1][c] = MFMA16(xa1[kc], br, av_[1][c]);
      }
    }
    #pragma unroll
    for (int g=0;g<2;++g)
    #pragma unroll
    for (int c=0;c<2;++c){
      unsigned int p0 = pkbf2(au[g][c][0], au[g][c][1]);
      unsigned int p1 = pkbf2(au[g][c][2], au[g][c][3]);
      av_[g][c] = MFMA16(aA[g], shfrag(p0,p1,laneA,laneB), av_[g][c]);
    }
    #pragma unroll
    for (int c=0;c<2;++c){
      float bb = b1[cg*32 + c*16 + l15];
      #pragma unroll
      for (int g=0;g<2;++g)
      #pragma unroll
      for (int r=0;r<4;++r)
        Hb[g*2176 + (quad*4+r)*136 + cg*32 + c*16 + l15] = f2bf(fmaxf(av_[g][c][r]+bb, 0.f));
    }
  }
  FENCE();

  // ---- SAGE layer 2 (K=128, 4 col-groups of 32, two-pass, staged writeback) ----
  {
    ushort4 os[4][2][2];                        // [cg][g][c]
    #pragma unroll
    for (int cg=0; cg<4; ++cg){
      bf16x8 uf[2][2];
      { // pass u
        f32x4 au[2][2];
        #pragma unroll
        for (int g=0;g<2;++g)
        #pragma unroll
        for (int c=0;c<2;++c) au[g][c]=z;
        #pragma unroll
        for (int kc=0;kc<4;++kc){
          bf16x8 a0 = ld8(Hb +        l15*136 + kc*32 + quad*8);
          bf16x8 a1 = ld8(Hb + 2176 + l15*136 + kc*32 + quad*8);
          #pragma unroll
          for (int c=0;c<2;++c){
            bf16x8 bl = ld8(ws0 + O_W2L + (cg*32 + c*16 + l15)*128 + kc*32 + quad*8);
            au[0][c] = MFMA16(a0, bl, au[0][c]);
            au[1][c] = MFMA16(a1, bl, au[1][c]);
          }
        }
        #pragma unroll
        for (int g=0;g<2;++g)
        #pragma unroll
        for (int c=0;c<2;++c){
          unsigned int p0 = pkbf2(au[g][c][0], au[g][c][1]);
          unsigned int p1 = pkbf2(au[g][c][2], au[g][c][3]);
          uf[g][c] = shfrag(p0,p1,laneA,laneB);
        }
      }
      { // pass v + A@u
        f32x4 av_[2][2];
        #pragma unroll
        for (int g=0;g<2;++g)
        #pragma unroll
        for (int c=0;c<2;++c) av_[g][c]=z;
        #pragma unroll
        for (int kc=0;kc<4;++kc){
          bf16x8 a0 = ld8(Hb +        l15*136 + kc*32 + quad*8);
          bf16x8 a1 = ld8(Hb + 2176 + l15*136 + kc*32 + quad*8);
          #pragma unroll
          for (int c=0;c<2;++c){
            bf16x8 br = ld8(ws0 + O_W2R + (cg*32 + c*16 + l15)*128 + kc*32 + quad*8);
            av_[0][c] = MFMA16(a0, br, av_[0][c]);
            av_[1][c] = MFMA16(a1, br, av_[1][c]);
          }
        }
        #pragma unroll
        for (int g=0;g<2;++g)
        #pragma unroll
        for (int c=0;c<2;++c)
          av_[g][c] = MFMA16(aA[g], uf[g][c], av_[g][c]);
        #pragma unroll
        for (int c=0;c<2;++c){
          float bb = b2[cg*32 + c*16 + l15];
          #pragma unroll
          for (int g=0;g<2;++g){
            ushort4 p;
            p.x = f2bf(fmaxf(av_[g][c][0]+bb, 0.f));
            p.y = f2bf(fmaxf(av_[g][c][1]+bb, 0.f));
            p.z = f2bf(fmaxf(av_[g][c][2]+bb, 0.f));
            p.w = f2bf(fmaxf(av_[g][c][3]+bb, 0.f));
            os[cg][g][c] = p;
          }
        }
      }
    }
    // in-place writeback after ALL reads of all col-groups
    #pragma unroll
    for (int cg=0; cg<4; ++cg)
    #pragma unroll
    for (int g=0; g<2; ++g)
    #pragma unroll
    for (int c=0; c<2; ++c){
      unsigned short* bp = Hb + g*2176 + cg*32 + c*16 + l15;
      ushort4 p = os[cg][g][c];
      bp[(quad*4+0)*136] = p.x;
      bp[(quad*4+1)*136] = p.y;
      bp[(quad*4+2)*136] = p.z;
      bp[(quad*4+3)*136] = p.w;
    }
  }
  FENCE();

  // ---- SAGE layer 3 (64 cols, no relu) -> X ----
  {
    bf16x8 uf[2][4];
    { // pass u
      f32x4 au[2][4];
      #pragma unroll
      for (int g=0;g<2;++g)
      #pragma unroll
      for (int c=0;c<4;++c) au[g][c]=z;
      #pragma unroll
      for (int kc=0;kc<4;++kc){
        bf16x8 a0 = ld8(Hb +        l15*136 + kc*32 + quad*8);
        bf16x8 a1 = ld8(Hb + 2176 + l15*136 + kc*32 + quad*8);
        #pragma unroll
        for (int c=0;c<4;++c){
          bf16x8 bl = ld8(ws0 + O_W3L + (c*16 + l15)*128 + kc*32 + quad*8);
          au[0][c] = MFMA16(a0, bl, au[0][c]);
          au[1][c] = MFMA16(a1, bl, au[1][c]);
        }
      }
      #pragma unroll
      for (int g=0;g<2;++g)
      #pragma unroll
      for (int c=0;c<4;++c){
        unsigned int p0 = pkbf2(au[g][c][0], au[g][c][1]);
        unsigned int p1 = pkbf2(au[g][c][2], au[g][c][3]);
        uf[g][c] = shfrag(p0,p1,laneA,laneB);
      }
    }
    { // pass v + A@u -> X (writes only after all Hb reads)
      f32x4 av_[2][4];
      #pragma unroll
      for (int g=0;g<2;++g)
      #pragma unroll
      for (int c=0;c<4;++c) av_[g][c]=z;
      #pragma unroll
      for (int kc=0;kc<4;++kc){
        bf16x8 a0 = ld8(Hb +        l15*136 + kc*32 + quad*8);
        bf16x8 a1 = ld8(Hb + 2176 + l15*136 + kc*32 + quad*8);
        #pragma unroll
        for (int c=0;c<4;++c){
          bf16x8 br = ld8(ws0 + O_W3R + (c*16 + l15)*128 + kc*32 + quad*8);
          av_[0][c] = MFMA16(a0, br, av_[0][c]);
          av_[1][c] = MFMA16(a1, br, av_[1][c]);
        }
      }
      #pragma unroll
      for (int g=0;g<2;++g)
      #pragma unroll
      for (int c=0;c<4;++c)
        av_[g][c] = MFMA16(aA[g], uf[g][c], av_[g][c]);
      #pragma unroll
      for (int c=0;c<4;++c){
        float bb = b3[c*16 + l15];
        #pragma unroll
        for (int g=0;g<2;++g)
        #pragma unroll
        for (int r=0;r<4;++r)
          X[g*1152 + (quad*4+r)*72 + c*16 + l15] = f2bf(av_[g][c][r] + bb);
      }
    }
  }
  FENCE();

  // ---- TCN: t = relu(Xshift@W0 + X@W1 + b) + X  (residual re-read from X) ----
  {
    f32x4 acct[2][4];
    #pragma unroll
    for (int g=0;g<2;++g)
    #pragma unroll
    for (int c=0;c<4;++c) acct[g][c]=z;
    #pragma unroll
    for (int kc=0;kc<2;++kc){
      bf16x8 ax0 = ld8(X +        l15*72 + kc*32 + quad*8);
      bf16x8 ax1 = ld8(X + 1152 + l15*72 + kc*32 + quad*8);
      bf16x8 as0 = (l15>0) ? ld8(X +        (l15-1)*72 + kc*32 + quad*8) : Z;
      bf16x8 as1 = (l15>0) ? ld8(X + 1152 + (l15-1)*72 + kc*32 + quad*8) : Z;
      #pragma unroll
      for (int c=0;c<4;++c){
        bf16x8 w0 = ld8(ws0 + O_T0 + (c*16 + l15)*64 + kc*32 + quad*8);
        bf16x8 w1 = ld8(ws0 + O_T1 + (c*16 + l15)*64 + kc*32 + quad*8);
        acct[0][c] = MFMA16(as0, w0, acct[0][c]);
        acct[0][c] = MFMA16(ax0, w1, acct[0][c]);
        acct[1][c] = MFMA16(as1, w0, acct[1][c]);
        acct[1][c] = MFMA16(ax1, w1, acct[1][c]);
      }
    }
    #pragma unroll
    for (int c=0;c<4;++c){
      float tb = tcnb[c*16 + l15];
      #pragma unroll
      for (int g=0;g<2;++g)
      #pragma unroll
      for (int r=0;r<4;++r){
        float xr = bf2f(X[g*1152 + (quad*4+r)*72 + c*16 + l15]);
        T[g*1152 + (quad*4+r)*72 + c*16 + l15] =
            f2bf(fmaxf(acct[g][c][r]+tb, 0.f) + xr);
      }
    }
  }
  FENCE();

  // ---- Q pass: Q row-major -> Qb (over dead X) ----
  {
    f32x4 acc[2][4];
    #pragma unroll
    for (int g=0;g<2;++g)
    #pragma unroll
    for (int c=0;c<4;++c) acc[g][c]=z;
    #pragma unroll
    for (int kc=0;kc<2;++kc){
      bf16x8 t0 = ld8(T +        l15*72 + kc*32 + quad*8);
      bf16x8 t1 = ld8(T + 1152 + l15*72 + kc*32 + quad*8);
      #pragma unroll
      for (int c=0;c<4;++c){
        bf16x8 b = ld8(ws0 + O_WQ + (c*16 + l15)*64 + kc*32 + quad*8);
        acc[0][c] = MFMA16(t0, b, acc[0][c]);
        acc[1][c] = MFMA16(t1, b, acc[1][c]);
      }
    }
    #pragma unroll
    for (int c=0;c<4;++c)
    #pragma unroll
    for (int g=0;g<2;++g)
    #pragma unroll
    for (int r=0;r<4;++r)
      Qb[g*1152 + (quad*4+r)*72 + c*16 + l15] = f2bf(acc[g][c][r]);
  }
  FENCE();

  // ---- attention per graph: K^T, V, S+softmax, PV (bK+bV = 32 regs) ----
  #pragma unroll
  for (int g=0; g<2; ++g){
    const unsigned short* Tg  = T  + g*1152;
    unsigned short*       Pbg = Pb + g*1024;

    // K^T pass: swapped operands (A = O_WK = Wk^T, B = T rows) ->
    // C = K^T[d][node], col==l15 -> shuffle straight into B-frags
    bf16x8 bK[4];
    {
      f32x4 kt[4] = {z,z,z,z};
      #pragma unroll
      for (int kc=0;kc<2;++kc){
        bf16x8 tg = ld8(Tg + l15*72 + kc*32 + quad*8);
        #pragma unroll
        for (int c=0;c<4;++c){
          bf16x8 aW = ld8(ws0 + O_WK + (c*16 + l15)*64 + kc*32 + quad*8);
          kt[c] = MFMA16(aW, tg, kt[c]);
        }
      }
      #pragma unroll
      for (int c=0;c<4;++c){
        unsigned int p0 = pkbf2(kt[c][0], kt[c][1]);
        unsigned int p1 = pkbf2(kt[c][2], kt[c][3]);
        bf16x8 f = shfrag(p0,p1,laneA,laneB);
        bK[c] = (quad < 2) ? f : Z;       // K padded 16->32: zero upper half
      }
    }

    // V pass: V C-layout (col=d) -> PV B-frags via shfrag (no LDS)
    bf16x8 bV[4];
    {
      f32x4 acc[4] = {z,z,z,z};
      #pragma unroll
      for (int kc=0;kc<2;++kc){
        bf16x8 tg = ld8(Tg + l15*72 + kc*32 + quad*8);
        #pragma unroll
        for (int c=0;c<4;++c){
          bf16x8 b = ld8(ws0 + O_WV + (c*16 + l15)*64 + kc*32 + quad*8);
          acc[c] = MFMA16(tg, b, acc[c]);
        }
      }
      #pragma unroll
      for (int c=0;c<4;++c){
        unsigned int p0 = pkbf2(acc[c][0], acc[c][1]);
        unsigned int p1 = pkbf2(acc[c][2], acc[c][3]);
        bV[c] = shfrag(p0,p1,laneA,laneB);  // garbage k>=16 killed by zero aP
      }
    }
    FENCE();   // T[g] dead; Pb[g] (over T) safe to write

    // S = (Q K^T)/4 per head; softmax across l15 lanes -> Pb[g]
    #pragma unroll
    for (int h=0;h<4;++h){
      bf16x8 aQ = (quad < 2) ? ld8(Qb + g*1152 + l15*72 + h*16 + quad*8) : Z;
      f32x4 s4 = MFMA16(aQ, bK[h], z);
      #pragma unroll
      for (int r=0;r<4;++r){
        float s = s4[r]*0.25f;
        float m = s;
        m = fmaxf(m, __shfl_xor(m,1,64));
        m = fmaxf(m, __shfl_xor(m,2,64));
        m = fmaxf(m, __shfl_xor(m,4,64));
        m = fmaxf(m, __shfl_xor(m,8,64));
        float p = __expf(s-m);
        float su = p;
        su += __shfl_xor(su,1,64);
        su += __shfl_xor(su,2,64);
        su += __shfl_xor(su,4,64);
        su += __shfl_xor(su,8,64);
        Pbg[(h*16 + quad*4 + r)*16 + l15] = f2bf(p/su);
      }
    }
    FENCE();

    // O = P@V per head; column mean over 16 nodes in-register -> OM
    #pragma unroll
    for (int h=0;h<4;++h){
      bf16x8 aP = (quad < 2) ? ld8(Pbg + (h*16 + l15)*16 + quad*8) : Z;
      f32x4 o = MFMA16(aP, bV[h], z);
      float cs = o[0]+o[1]+o[2]+o[3];
      cs += __shfl_xor(cs, 16, 64);
      cs += __shfl_xor(cs, 32, 64);
      if (quad == 0) OMf[g*64 + h*16 + l15] = cs * (1.f/16.f);
    }
    FENCE();
  }

  // ---- feat = ((mean O) @ wo) @ wproj + bproj  (all fp32 scalar) ----
  {
    float t0 = 0.f, t1 = 0.f;
    #pragma unroll 8
    for (int d=0; d<64; ++d){
      float wv = wo[d*64 + lane];
      t0 += OMf[d]    * wv;
      t1 += OMf[64+d] * wv;
    }
    OMf[128+lane] = t0;
    OMf[192+lane] = t1;
    FENCE();
    float a00 = bproj[lane], a01 = bproj[lane+64];
    float a10 = a00, a11 = a01;
    #pragma unroll 8
    for (int m=0; m<64; ++m){
      float f0 = OMf[128+m], f1 = OMf[192+m];
      float w0 = wproj[m*128 + lane], w1 = wproj[m*128 + lane + 64];
      a00 += f0*w0; a01 += f0*w1;
      a10 += f1*w0; a11 += f1*w1;
    }
    feat[(size_t)gb0*128 + lane]        = f2bf(a00);
    feat[(size_t)gb0*128 + lane + 64]   = f2bf(a01);
    feat[(size_t)(gb0+1)*128 + lane]      = f2bf(a10);
    feat[(size_t)(gb0+1)*128 + lane + 64] = f2bf(a11);
  }
}

// ---------------------------------------------------------------------------
// per-variable fc heads: 1 wg = 1 kh; W1/W2 staged in padded LDS, shared by
// 4 waves x 2 row-tiles. 2048 blocks (16 kh x 128 rowblocks), 8192 waves.
// LDS: W1s [64][136] 17408 B + W2s [32][72] 4608 B + hw 4x[2][16][72] 18432 B
//    = 40448 B -> 4 wg/CU.
// ---------------------------------------------------------------------------
__global__ __launch_bounds__(256,4) void k_heads(
  const unsigned short* __restrict__ ws0,
  const float* __restrict__ fc1b, const float* __restrict__ fc2b,
  float* __restrict__ pred)
{
  __shared__ alignas(16) unsigned short W1s[64*136];
  __shared__ alignas(16) unsigned short W2s[32*72];
  __shared__ alignas(16) unsigned short hh[4*2304];
  const int tid=threadIdx.x, w=tid>>6, lane=tid&63, quad=lane>>4, l15=lane&15;
  const int kh = blockIdx.x >> 7;
  const int rb = (blockIdx.x & 127)*128 + w*32;   // this wave's 32 rows
  unsigned short* hw = hh + w*2304;
  const unsigned short* featg = ws0 + O_FEAT;
  const unsigned short* W1 = ws0 + O_FC1 + kh*8192;
  const unsigned short* W2 = ws0 + O_FC2 + kh*2048;

  // stage weights into padded LDS (row stride 136 / 72 kills bank conflicts)
  #pragma unroll
  for (int it=0; it<4; ++it){
    int idx = it*2048 + tid*8;
    int row = idx >> 7, col = idx & 127;
    *(uint4*)(W1s + row*136 + col) = *(const uint4*)(W1 + idx);
  }
  {
    int idx = tid*8; int row = idx >> 6, col = idx & 63;
    *(uint4*)(W2s + row*72 + col) = *(const uint4*)(W2 + idx);
  }
  __syncthreads();

  f32x4 z = {0.f,0.f,0.f,0.f};
  f32x4 acc[2][4];
  #pragma unroll
  for (int t=0;t<2;++t)
  #pragma unroll
  for (int c=0;c<4;++c) acc[t][c]=z;
  #pragma unroll
  for (int kc=0;kc<4;++kc){
    bf16x8 a0 = ld8(featg + (size_t)(rb+l15)*128    + kc*32+quad*8);
    bf16x8 a1 = ld8(featg + (size_t)(rb+16+l15)*128 + kc*32+quad*8);
    #pragma unroll
    for (int c=0;c<4;++c){
      bf16x8 b = ld8(W1s + (c*16+l15)*136 + kc*32+quad*8);
      acc[0][c] = MFMA16(a0, b, acc[0][c]);
      acc[1][c] = MFMA16(a1, b, acc[1][c]);
    }
  }
  #pragma unroll
  for (int c=0;c<4;++c){
    float bb = fc1b[kh*64 + c*16+l15];
    #pragma unroll
    for (int t=0;t<2;++t)
    #pragma unroll
    for (int r=0;r<4;++r)
      hw[t*1152 + (quad*4+r)*72 + c*16+l15] = f2bf(fmaxf(acc[t][c][r]+bb, 0.f));
  }
  FENCE();
  f32x4 acc2[2][2];
  #pragma unroll
  for (int t=0;t<2;++t)
  #pragma unroll
  for (int c=0;c<2;++c) acc2[t][c]=z;
  #pragma unroll
  for (int kc=0;kc<2;++kc){
    bf16x8 a0 = ld8(hw +        l15*72 + kc*32+quad*8);
    bf16x8 a1 = ld8(hw + 1152 + l15*72 + kc*32+quad*8);
    #pragma unroll
    for (int c=0;c<2;++c){
      bf16x8 b = ld8(W2s + (c*16+l15)*72 + kc*32+quad*8);
      acc2[0][c] = MFMA16(a0, b, acc2[0][c]);
      acc2[1][c] = MFMA16(a1, b, acc2[1][c]);
    }
  }
  #pragma unroll
  for (int c=0;c<2;++c){
    int col = c*16+l15;
    if (col < 24){
      float bb = fc2b[kh*24+col];
      #pragma unroll
      for (int t=0;t<2;++t)
      #pragma unroll
      for (int r=0;r<4;++r)
        pred[(size_t)kh*393216 + (size_t)(rb+t*16+quad*4+r)*24 + col] = acc2[t][c][r] + bb;
    }
  }
}

// yb output = y.reshape -> exact copy
__global__ __launch_bounds__(256) void k_copy(const float4* __restrict__ y,
                                              float4* __restrict__ o)
{
  int i = blockIdx.x*256 + threadIdx.x;   // exactly 1572864 float4s
  o[i] = y[i];
}

// ---------------------------------------------------------------------------
extern "C" void kernel_launch(void* const* d_in, const int* in_sizes, int n_in,
                              void* d_out, int out_size, void* d_ws, size_t ws_size,
                              hipStream_t stream) {
  const float* x    = (const float*)d_in[0];
  const float* y    = (const float*)d_in[1];
  const int*   ei   = (const int*)d_in[2];
  const float* w1l  = (const float*)d_in[4];
  const float* w1r  = (const float*)d_in[5];
  const float* b1   = (const float*)d_in[6];
  const float* w2l  = (const float*)d_in[7];
  const float* w2r  = (const float*)d_in[8];
  const float* b2   = (const float*)d_in[9];
  const float* w3l  = (const float*)d_in[10];
  const float* w3r  = (const float*)d_in[11];
  const float* b3   = (const float*)d_in[12];
  const float* tcnw = (const float*)d_in[13];
  const float* tcnb = (const float*)d_in[14];
  const float* wq   = (const float*)d_in[15];
  const float* wk   = (const float*)d_in[16];
  const float* wv   = (const float*)d_in[17];
  const float* wo   = (const float*)d_in[18];
  const float* wpr  = (const float*)d_in[19];
  const float* bpr  = (const float*)d_in[20];
  const float* fc1w = (const float*)d_in[21];
  const float* fc1b = (const float*)d_in[22];
  const float* fc2w = (const float*)d_in[23];
  const float* fc2b = (const float*)d_in[24];

  unsigned short* W = (unsigned short*)d_ws;
  float* out = (float*)d_out;

  k_prep<<<1120, 256, 0, stream>>>(w1l,w1r,w2l,w2r,w3l,w3r,tcnw,wq,wk,wv,wo,fc1w,fc2w,W);
  k_fused<<<NGR/8, 256, 0, stream>>>(x, ei + EDGES, b1,b2,b3,tcnb, wo, wpr, bpr, W, W + O_FEAT);
  k_heads<<<2048, 256, 0, stream>>>(W, fc1b, fc2b, out);
  k_copy<<<6144, 256, 0, stream>>>((const float4*)y, (float4*)(out + PRED_ELEMS));
}

// Round 7
// 475.945 us; speedup vs baseline: 1.7070x; 1.2239x over previous
//
#include <hip/hip_runtime.h>
#include <cstdint>
#include <cstddef>

// ---------------------------------------------------------------------------
// SSTAFormer round 9 (= round 8 resubmit after infra failure, + WK/WV hoist).
//   - r7 evidence: spill gone (WRITE=4MB), VGPR 80, yet MfmaUtil 8.8% and
//     ~1000 cyc/weight-load: per-wave serial chain of ~280 L2 loads is THE
//     bottleneck. All waves read identical weights -> stage each phase's
//     chunk into shared LDS (WB, 17408 B) with 256 threads, then B-frags are
//     conflict-free ds_read_b128 (strides 200/136/72 ushorts).
//   - LDS 4*9216 + 17408 = 54272 B -> 3 wg/CU (162816 <= 163840), 12 waves/CU.
//   - Attention: WK/WV staged ONCE (bK[2][4], bV[2][4] in regs) -- 2 fewer
//     barrier convoys than the failed r8 variant.
//   - k_heads: pred written via LDS transpose as coalesced 256-B bursts;
//     y-copy fused into k_heads tail (2048*256*3 float4 exact); k_copy gone.
// ---------------------------------------------------------------------------

typedef __attribute__((ext_vector_type(8))) __bf16 bf16x8;
typedef __attribute__((ext_vector_type(4))) float  f32x4;

#define MFMA16(a,b,c) __builtin_amdgcn_mfma_f32_16x16x32_bf16((a),(b),(c),0,0,0)
#define FENCE() __threadfence_block()

#define NGR    16384
#define EDGES  1048576
#define PRED_ELEMS (16*16384*24)

// workspace layout in ushort units
#define O_W1L 0               // [128][192]
#define O_W1R 24576
#define O_W2L 49152           // [128][128]
#define O_W2R 65536
#define O_W3L 81920           // [64][128]
#define O_W3R 90112
#define O_T0  98304           // [64 co][64 ci]  (tcn_w[...,0])
#define O_T1  102400
#define O_WQ  106496          // [64][64]
#define O_WK  110592
#define O_WV  114688
#define O_WO  118784
#define O_FC1 122880          // 16 x [64][128]
#define O_FC2 253952          // 16 x [32][64]
#define O_FEAT 286720         // [16384][128] bf16
#define PREP_TOT 286720

static __device__ __forceinline__ unsigned short f2bf(float f){
  unsigned int u = __builtin_bit_cast(unsigned int, f);
  u += 0x7FFFu + ((u >> 16) & 1u);            // RNE
  return (unsigned short)(u >> 16);
}
static __device__ __forceinline__ float bf2f(unsigned short h){
  return __builtin_bit_cast(float, (unsigned int)h << 16);
}
static __device__ __forceinline__ bf16x8 ld8(const unsigned short* p){
  return __builtin_bit_cast(bf16x8, *(const uint4*)p);   // 16B aligned by construction
}
static __device__ __forceinline__ bf16x8 zero8(){
  uint4 u = make_uint4(0u,0u,0u,0u);
  return __builtin_bit_cast(bf16x8, u);
}
static __device__ __forceinline__ unsigned int pkbf2(float a, float b){
  return (unsigned int)f2bf(a) | ((unsigned int)f2bf(b)<<16);
}
static __device__ __forceinline__ bf16x8 u4bf(unsigned int a, unsigned int b,
                                              unsigned int c, unsigned int d){
  uint4 u = make_uint4(a,b,c,d);
  return __builtin_bit_cast(bf16x8, u);
}
// C-layout (row=4*quad'+r, col=l15) -> B-frag (k=8*quad+e, col=l15)
static __device__ __forceinline__ bf16x8 shfrag(unsigned int p0, unsigned int p1,
                                                int laneA, int laneB){
  return u4bf((unsigned int)__shfl((int)p0, laneA, 64),
              (unsigned int)__shfl((int)p1, laneA, 64),
              (unsigned int)__shfl((int)p0, laneB, 64),
              (unsigned int)__shfl((int)p1, laneB, 64));
}
// A-fragment from global fp32 x row (K padded 168->192, W rows >=168 are zero)
static __device__ __forceinline__ bf16x8 xfrag(const float* __restrict__ xrow, int k0){
  int ks = (k0 < 168) ? k0 : 0;          // clamped lanes multiply zero W rows
  float4 f0 = *(const float4*)(xrow + ks);
  float4 f1 = *(const float4*)(xrow + ks + 4);
  return u4bf(pkbf2(f0.x,f0.y), pkbf2(f0.z,f0.w),
              pkbf2(f1.x,f1.y), pkbf2(f1.z,f1.w));
}
// cooperative weight staging: TOT ushorts, source rows of K, padded stride P.
// 256 threads x 8 ushorts (uint4); K%8==0 so chunks never straddle rows.
template<int TOT, int K, int P>
static __device__ __forceinline__ void stageW(const unsigned short* __restrict__ src,
                                              unsigned short* __restrict__ dst, int tid){
  #pragma unroll
  for (int it=0; it<TOT/2048; ++it){
    int idx = it*2048 + tid*8;
    int row = idx / K, col = idx - row*K;
    *(uint4*)(dst + row*P + col) = *(const uint4*)(src + idx);
  }
}

// ---------------------------------------------------------------------------
// weight prep (unchanged, verified correct)
// ---------------------------------------------------------------------------
__global__ __launch_bounds__(256) void k_prep(
  const float* __restrict__ w1l, const float* __restrict__ w1r,
  const float* __restrict__ w2l, const float* __restrict__ w2r,
  const float* __restrict__ w3l, const float* __restrict__ w3r,
  const float* __restrict__ tcnw,
  const float* __restrict__ wq, const float* __restrict__ wk,
  const float* __restrict__ wv, const float* __restrict__ wo,
  const float* __restrict__ fc1w, const float* __restrict__ fc2w,
  unsigned short* __restrict__ W)
{
  int idx = blockIdx.x*256 + threadIdx.x;
  if (idx >= PREP_TOT) return;
  float v;
  if      (idx <  24576){ int t=idx;        int n=t/192,k=t%192; v=(k<168)? w1l[k*128+n]:0.f; }
  else if (idx <  49152){ int t=idx- 24576; int n=t/192,k=t%192; v=(k<168)? w1r[k*128+n]:0.f; }
  else if (idx <  65536){ int t=idx- 49152; int n=t/128,k=t%128; v=w2l[k*128+n]; }
  else if (idx <  81920){ int t=idx- 65536; int n=t/128,k=t%128; v=w2r[k*128+n]; }
  else if (idx <  90112){ int t=idx- 81920; int n=t/128,k=t%128; v=w3l[k*64+n]; }
  else if (idx <  98304){ int t=idx- 90112; int n=t/128,k=t%128; v=w3r[k*64+n]; }
  else if (idx < 102400){ int t=idx- 98304; int n=t/64, k=t%64;  v=tcnw[(n*64+k)*2+0]; }
  else if (idx < 106496){ int t=idx-102400; int n=t/64, k=t%64;  v=tcnw[(n*64+k)*2+1]; }
  else if (idx < 110592){ int t=idx-106496; int n=t/64, k=t%64;  v=wq[k*64+n]; }
  else if (idx < 114688){ int t=idx-110592; int n=t/64, k=t%64;  v=wk[k*64+n]; }
  else if (idx < 118784){ int t=idx-114688; int n=t/64, k=t%64;  v=wv[k*64+n]; }
  else if (idx < 122880){ int t=idx-118784; int n=t/64, k=t%64;  v=wo[k*64+n]; }
  else if (idx < 253952){ int t=idx-122880; int kh=t/8192, r=t%8192, n=r/128, k=r%128;
                          v=fc1w[kh*8192 + k*64 + n]; }
  else                  { int t=idx-253952; int kh=t/2048, r=t%2048, n=r/64,  k=r%64;
                          v=(n<24)? fc2w[kh*1536 + k*24 + n] : 0.f; }
  W[idx] = f2bf(v);
}

// ---------------------------------------------------------------------------
// fused GNN + TCN + attention + proj : 1 wg = 8 graphs, 1 wave = 2 graphs.
// Weights cooperatively staged per phase into shared WB (padded, conflict-
// free); per-wave arenas unchanged. All barriers are workgroup-uniform.
// ---------------------------------------------------------------------------
__global__ __launch_bounds__(256,3) void k_fused(
  const float* __restrict__ x, const int* __restrict__ edst,
  const float* __restrict__ b1, const float* __restrict__ b2,
  const float* __restrict__ b3, const float* __restrict__ tcnb,
  const float* __restrict__ wo, const float* __restrict__ wproj,
  const float* __restrict__ bproj,
  const unsigned short* __restrict__ ws0, unsigned short* __restrict__ feat)
{
  __shared__ alignas(16) unsigned char pool[4*9216];
  __shared__ alignas(16) unsigned short WB[8704];     // 17408 B shared stage
  const int tid=threadIdx.x, w=tid>>6, lane=tid&63, quad=lane>>4, l15=lane&15;
  unsigned short* AR = (unsigned short*)(pool + w*9216);
  const int gb0 = (blockIdx.x*4 + w)*2;

  unsigned short* Hb = AR;              // [2][16][136]
  unsigned short* X  = AR;              // [2][16][72]
  unsigned short* T  = AR + 2304;       // [2][16][72]
  unsigned short* Qb = AR;              // [2][16][72]
  unsigned short* Pb = AR + 2304;       // [2][4][16][16]
  float* OMf = (float*)AR;              // [4][64] f32

  const bf16x8 Z = zero8();
  const f32x4  z = {0.f,0.f,0.f,0.f};
  const int laneA = 32*quad + l15, laneB = laneA + 16;

  // ---- adjacency: A-frags built fully in registers via shuffles ----
  bf16x8 aA[2];
  #pragma unroll
  for (int g=0; g<2; ++g){
    int dl = edst[(gb0+g)*64 + lane] & 15;
    float c4[4]; float csum = 0.f;
    #pragma unroll
    for (int ss=0; ss<4; ++ss){
      int s = quad*4 + ss; int cc = 0;
      #pragma unroll
      for (int k=0;k<4;++k) cc += (__shfl(dl, s*4+k, 64) == l15) ? 1 : 0;
      c4[ss] = (float)cc; csum += (float)cc;
    }
    csum += __shfl_xor(csum, 16, 64);
    csum += __shfl_xor(csum, 32, 64);
    float ainv = 1.f / fmaxf(csum, 1.f);
    unsigned int p0 = pkbf2(c4[0]*ainv, c4[1]*ainv);
    unsigned int p1 = pkbf2(c4[2]*ainv, c4[3]*ainv);
    bf16x8 t = shfrag(p0, p1, laneA, laneB);
    aA[g] = (quad < 2) ? t : Z;           // exact zeros for k>=16
  }

  // ---- x staged ONCE: 12 A-frags in registers (dead after layer 1) ----
  const float* xr0 = x + (size_t)(gb0*16 + l15)*168;
  const float* xr1 = xr0 + 16*168;
  bf16x8 xa0[6], xa1[6];
  #pragma unroll
  for (int kc=0;kc<6;++kc){
    xa0[kc] = xfrag(xr0, kc*32 + quad*8);
    xa1[kc] = xfrag(xr1, kc*32 + quad*8);
  }

  // ---- SAGE layer 1 (K=192 pad200, 4 col-groups of 32, staged weights) ----
  #pragma unroll
  for (int cg=0; cg<4; ++cg){
    __syncthreads();
    stageW<6144,192,200>(ws0 + O_W1L + cg*6144, WB, tid);
    __syncthreads();
    f32x4 au[2][2];
    #pragma unroll
    for (int g=0;g<2;++g)
    #pragma unroll
    for (int c=0;c<2;++c) au[g][c]=z;
    #pragma unroll
    for (int kc=0;kc<6;++kc){
      #pragma unroll
      for (int c=0;c<2;++c){
        bf16x8 bl = ld8(WB + (c*16+l15)*200 + kc*32 + quad*8);
        au[0][c] = MFMA16(xa0[kc], bl, au[0][c]);
        au[1][c] = MFMA16(xa1[kc], bl, au[1][c]);
      }
    }
    bf16x8 uf[2][2];
    #pragma unroll
    for (int g=0;g<2;++g)
    #pragma unroll
    for (int c=0;c<2;++c){
      unsigned int p0 = pkbf2(au[g][c][0], au[g][c][1]);
      unsigned int p1 = pkbf2(au[g][c][2], au[g][c][3]);
      uf[g][c] = shfrag(p0,p1,laneA,laneB);
    }
    __syncthreads();
    stageW<6144,192,200>(ws0 + O_W1R + cg*6144, WB, tid);
    __syncthreads();
    f32x4 av_[2][2];
    #pragma unroll
    for (int g=0;g<2;++g)
    #pragma unroll
    for (int c=0;c<2;++c) av_[g][c]=z;
    #pragma unroll
    for (int kc=0;kc<6;++kc){
      #pragma unroll
      for (int c=0;c<2;++c){
        bf16x8 br = ld8(WB + (c*16+l15)*200 + kc*32 + quad*8);
        av_[0][c] = MFMA16(xa0[kc], br, av_[0][c]);
        av_[1][c] = MFMA16(xa1[kc], br, av_[1][c]);
      }
    }
    #pragma unroll
    for (int g=0;g<2;++g)
    #pragma unroll
    for (int c=0;c<2;++c)
      av_[g][c] = MFMA16(aA[g], uf[g][c], av_[g][c]);
    #pragma unroll
    for (int c=0;c<2;++c){
      float bb = b1[cg*32 + c*16 + l15];
      #pragma unroll
      for (int g=0;g<2;++g)
      #pragma unroll
      for (int r=0;r<4;++r)
        Hb[g*2176 + (quad*4+r)*136 + cg*32 + c*16 + l15] = f2bf(fmaxf(av_[g][c][r]+bb, 0.f));
    }
  }
  FENCE();

  // ---- SAGE layer 2 (K=128 pad136, 4 col-groups, staged weights) ----
  {
    ushort4 os[4][2][2];
    #pragma unroll
    for (int cg=0; cg<4; ++cg){
      __syncthreads();
      stageW<4096,128,136>(ws0 + O_W2L + cg*4096, WB, tid);
      __syncthreads();
      bf16x8 uf[2][2];
      {
        f32x4 au[2][2];
        #pragma unroll
        for (int g=0;g<2;++g)
        #pragma unroll
        for (int c=0;c<2;++c) au[g][c]=z;
        #pragma unroll
        for (int kc=0;kc<4;++kc){
          bf16x8 a0 = ld8(Hb +        l15*136 + kc*32 + quad*8);
          bf16x8 a1 = ld8(Hb + 2176 + l15*136 + kc*32 + quad*8);
          #pragma unroll
          for (int c=0;c<2;++c){
            bf16x8 bl = ld8(WB + (c*16+l15)*136 + kc*32 + quad*8);
            au[0][c] = MFMA16(a0, bl, au[0][c]);
            au[1][c] = MFMA16(a1, bl, au[1][c]);
          }
        }
        #pragma unroll
        for (int g=0;g<2;++g)
        #pragma unroll
        for (int c=0;c<2;++c){
          unsigned int p0 = pkbf2(au[g][c][0], au[g][c][1]);
          unsigned int p1 = pkbf2(au[g][c][2], au[g][c][3]);
          uf[g][c] = shfrag(p0,p1,laneA,laneB);
        }
      }
      __syncthreads();
      stageW<4096,128,136>(ws0 + O_W2R + cg*4096, WB, tid);
      __syncthreads();
      {
        f32x4 av_[2][2];
        #pragma unroll
        for (int g=0;g<2;++g)
        #pragma unroll
        for (int c=0;c<2;++c) av_[g][c]=z;
        #pragma unroll
        for (int kc=0;kc<4;++kc){
          bf16x8 a0 = ld8(Hb +        l15*136 + kc*32 + quad*8);
          bf16x8 a1 = ld8(Hb + 2176 + l15*136 + kc*32 + quad*8);
          #pragma unroll
          for (int c=0;c<2;++c){
            bf16x8 br = ld8(WB + (c*16+l15)*136 + kc*32 + quad*8);
            av_[0][c] = MFMA16(a0, br, av_[0][c]);
            av_[1][c] = MFMA16(a1, br, av_[1][c]);
          }
        }
        #pragma unroll
        for (int g=0;g<2;++g)
        #pragma unroll
        for (int c=0;c<2;++c)
          av_[g][c] = MFMA16(aA[g], uf[g][c], av_[g][c]);
        #pragma unroll
        for (int c=0;c<2;++c){
          float bb = b2[cg*32 + c*16 + l15];
          #pragma unroll
          for (int g=0;g<2;++g){
            ushort4 p;
            p.x = f2bf(fmaxf(av_[g][c][0]+bb, 0.f));
            p.y = f2bf(fmaxf(av_[g][c][1]+bb, 0.f));
            p.z = f2bf(fmaxf(av_[g][c][2]+bb, 0.f));
            p.w = f2bf(fmaxf(av_[g][c][3]+bb, 0.f));
            os[cg][g][c] = p;
          }
        }
      }
    }
    // in-place writeback after ALL reads of all col-groups (wave-private Hb)
    #pragma unroll
    for (int cg=0; cg<4; ++cg)
    #pragma unroll
    for (int g=0; g<2; ++g)
    #pragma unroll
    for (int c=0; c<2; ++c){
      unsigned short* bp = Hb + g*2176 + cg*32 + c*16 + l15;
      ushort4 p = os[cg][g][c];
      bp[(quad*4+0)*136] = p.x;
      bp[(quad*4+1)*136] = p.y;
      bp[(quad*4+2)*136] = p.z;
      bp[(quad*4+3)*136] = p.w;
    }
  }
  FENCE();

  // ---- SAGE layer 3 (64 cols, staged weights) -> X ----
  {
    bf16x8 uf[2][4];
    __syncthreads();
    stageW<8192,128,136>(ws0 + O_W3L, WB, tid);
    __syncthreads();
    {
      f32x4 au[2][4];
      #pragma unroll
      for (int g=0;g<2;++g)
      #pragma unroll
      for (int c=0;c<4;++c) au[g][c]=z;
      #pragma unroll
      for (int kc=0;kc<4;++kc){
        bf16x8 a0 = ld8(Hb +        l15*136 + kc*32 + quad*8);
        bf16x8 a1 = ld8(Hb + 2176 + l15*136 + kc*32 + quad*8);
        #pragma unroll
        for (int c=0;c<4;++c){
          bf16x8 bl = ld8(WB + (c*16+l15)*136 + kc*32 + quad*8);
          au[0][c] = MFMA16(a0, bl, au[0][c]);
          au[1][c] = MFMA16(a1, bl, au[1][c]);
        }
      }
      #pragma unroll
      for (int g=0;g<2;++g)
      #pragma unroll
      for (int c=0;c<4;++c){
        unsigned int p0 = pkbf2(au[g][c][0], au[g][c][1]);
        unsigned int p1 = pkbf2(au[g][c][2], au[g][c][3]);
        uf[g][c] = shfrag(p0,p1,laneA,laneB);
      }
    }
    __syncthreads();
    stageW<8192,128,136>(ws0 + O_W3R, WB, tid);
    __syncthreads();
    {
      f32x4 av_[2][4];
      #pragma unroll
      for (int g=0;g<2;++g)
      #pragma unroll
      for (int c=0;c<4;++c) av_[g][c]=z;
      #pragma unroll
      for (int kc=0;kc<4;++kc){
        bf16x8 a0 = ld8(Hb +        l15*136 + kc*32 + quad*8);
        bf16x8 a1 = ld8(Hb + 2176 + l15*136 + kc*32 + quad*8);
        #pragma unroll
        for (int c=0;c<4;++c){
          bf16x8 br = ld8(WB + (c*16+l15)*136 + kc*32 + quad*8);
          av_[0][c] = MFMA16(a0, br, av_[0][c]);
          av_[1][c] = MFMA16(a1, br, av_[1][c]);
        }
      }
      #pragma unroll
      for (int g=0;g<2;++g)
      #pragma unroll
      for (int c=0;c<4;++c)
        av_[g][c] = MFMA16(aA[g], uf[g][c], av_[g][c]);
      #pragma unroll
      for (int c=0;c<4;++c){
        float bb = b3[c*16 + l15];
        #pragma unroll
        for (int g=0;g<2;++g)
        #pragma unroll
        for (int r=0;r<4;++r)
          X[g*1152 + (quad*4+r)*72 + c*16 + l15] = f2bf(av_[g][c][r] + bb);
      }
    }
  }
  FENCE();

  // ---- TCN: t = relu(Xshift@W0 + X@W1 + b) + X  (two staged passes) ----
  {
    f32x4 acct[2][4];
    #pragma unroll
    for (int g=0;g<2;++g)
    #pragma unroll
    for (int c=0;c<4;++c) acct[g][c]=z;
    __syncthreads();
    stageW<4096,64,72>(ws0 + O_T0, WB, tid);
    __syncthreads();
    #pragma unroll
    for (int kc=0;kc<2;++kc){
      bf16x8 as0 = (l15>0) ? ld8(X +        (l15-1)*72 + kc*32 + quad*8) : Z;
      bf16x8 as1 = (l15>0) ? ld8(X + 1152 + (l15-1)*72 + kc*32 + quad*8) : Z;
      #pragma unroll
      for (int c=0;c<4;++c){
        bf16x8 w0 = ld8(WB + (c*16+l15)*72 + kc*32 + quad*8);
        acct[0][c] = MFMA16(as0, w0, acct[0][c]);
        acct[1][c] = MFMA16(as1, w0, acct[1][c]);
      }
    }
    __syncthreads();
    stageW<4096,64,72>(ws0 + O_T1, WB, tid);
    __syncthreads();
    #pragma unroll
    for (int kc=0;kc<2;++kc){
      bf16x8 ax0 = ld8(X +        l15*72 + kc*32 + quad*8);
      bf16x8 ax1 = ld8(X + 1152 + l15*72 + kc*32 + quad*8);
      #pragma unroll
      for (int c=0;c<4;++c){
        bf16x8 w1 = ld8(WB + (c*16+l15)*72 + kc*32 + quad*8);
        acct[0][c] = MFMA16(ax0, w1, acct[0][c]);
        acct[1][c] = MFMA16(ax1, w1, acct[1][c]);
      }
    }
    #pragma unroll
    for (int c=0;c<4;++c){
      float tb = tcnb[c*16 + l15];
      #pragma unroll
      for (int g=0;g<2;++g)
      #pragma unroll
      for (int r=0;r<4;++r){
        float xr = bf2f(X[g*1152 + (quad*4+r)*72 + c*16 + l15]);
        T[g*1152 + (quad*4+r)*72 + c*16 + l15] =
            f2bf(fmaxf(acct[g][c][r]+tb, 0.f) + xr);
      }
    }
  }
  FENCE();

  // ---- Q pass (staged WQ): Q row-major -> Qb (over dead X) ----
  {
    __syncthreads();
    stageW<4096,64,72>(ws0 + O_WQ, WB, tid);
    __syncthreads();
    f32x4 acc[2][4];
    #pragma unroll
    for (int g=0;g<2;++g)
    #pragma unroll
    for (int c=0;c<4;++c) acc[g][c]=z;
    #pragma unroll
    for (int kc=0;kc<2;++kc){
      bf16x8 t0 = ld8(T +        l15*72 + kc*32 + quad*8);
      bf16x8 t1 = ld8(T + 1152 + l15*72 + kc*32 + quad*8);
      #pragma unroll
      for (int c=0;c<4;++c){
        bf16x8 b = ld8(WB + (c*16+l15)*72 + kc*32 + quad*8);
        acc[0][c] = MFMA16(t0, b, acc[0][c]);
        acc[1][c] = MFMA16(t1, b, acc[1][c]);
      }
    }
    #pragma unroll
    for (int c=0;c<4;++c)
    #pragma unroll
    for (int g=0;g<2;++g)
    #pragma unroll
    for (int r=0;r<4;++r)
      Qb[g*1152 + (quad*4+r)*72 + c*16 + l15] = f2bf(acc[g][c][r]);
  }
  FENCE();

  // ---- K^T pass (staged WK, both graphs): swapped operands ->
  //      C = K^T[d][node], col==l15 -> shuffle straight into B-frags ----
  bf16x8 bK[2][4];
  {
    __syncthreads();
    stageW<4096,64,72>(ws0 + O_WK, WB, tid);
    __syncthreads();
    f32x4 kt[2][4];
    #pragma unroll
    for (int g=0;g<2;++g)
    #pragma unroll
    for (int c=0;c<4;++c) kt[g][c]=z;
    #pragma unroll
    for (int kc=0;kc<2;++kc){
      bf16x8 t0 = ld8(T +        l15*72 + kc*32 + quad*8);
      bf16x8 t1 = ld8(T + 1152 + l15*72 + kc*32 + quad*8);
      #pragma unroll
      for (int c=0;c<4;++c){
        bf16x8 aW = ld8(WB + (c*16+l15)*72 + kc*32 + quad*8);
        kt[0][c] = MFMA16(aW, t0, kt[0][c]);
        kt[1][c] = MFMA16(aW, t1, kt[1][c]);
      }
    }
    #pragma unroll
    for (int g=0;g<2;++g)
    #pragma unroll
    for (int c=0;c<4;++c){
      unsigned int p0 = pkbf2(kt[g][c][0], kt[g][c][1]);
      unsigned int p1 = pkbf2(kt[g][c][2], kt[g][c][3]);
      bf16x8 f = shfrag(p0,p1,laneA,laneB);
      bK[g][c] = (quad < 2) ? f : Z;       // K padded 16->32: zero upper half
    }
  }

  // ---- V pass (staged WV, both graphs): C-layout -> PV B-frags ----
  bf16x8 bV[2][4];
  {
    __syncthreads();
    stageW<4096,64,72>(ws0 + O_WV, WB, tid);
    __syncthreads();
    f32x4 acc[2][4];
    #pragma unroll
    for (int g=0;g<2;++g)
    #pragma unroll
    for (int c=0;c<4;++c) acc[g][c]=z;
    #pragma unroll
    for (int kc=0;kc<2;++kc){
      bf16x8 t0 = ld8(T +        l15*72 + kc*32 + quad*8);
      bf16x8 t1 = ld8(T + 1152 + l15*72 + kc*32 + quad*8);
      #pragma unroll
      for (int c=0;c<4;++c){
        bf16x8 b = ld8(WB + (c*16+l15)*72 + kc*32 + quad*8);
        acc[0][c] = MFMA16(t0, b, acc[0][c]);
        acc[1][c] = MFMA16(t1, b, acc[1][c]);
      }
    }
    #pragma unroll
    for (int g=0;g<2;++g)
    #pragma unroll
    for (int c=0;c<4;++c){
      unsigned int p0 = pkbf2(acc[g][c][0], acc[g][c][1]);
      unsigned int p1 = pkbf2(acc[g][c][2], acc[g][c][3]);
      bV[g][c] = shfrag(p0,p1,laneA,laneB);  // garbage k>=16 killed by zero aP
    }
  }
  FENCE();   // all T reads done; Pb (over T) safe to write

  // ---- S = (Q K^T)/4 per head; softmax across l15 lanes -> Pb ----
  #pragma unroll
  for (int g=0; g<2; ++g){
    unsigned short* Pbg = Pb + g*1024;
    #pragma unroll
    for (int h=0;h<4;++h){
      bf16x8 aQ = (quad < 2) ? ld8(Qb + g*1152 + l15*72 + h*16 + quad*8) : Z;
      f32x4 s4 = MFMA16(aQ, bK[g][h], z);
      #pragma unroll
      for (int r=0;r<4;++r){
        float s = s4[r]*0.25f;
        float m = s;
        m = fmaxf(m, __shfl_xor(m,1,64));
        m = fmaxf(m, __shfl_xor(m,2,64));
        m = fmaxf(m, __shfl_xor(m,4,64));
        m = fmaxf(m, __shfl_xor(m,8,64));
        float p = __expf(s-m);
        float su = p;
        su += __shfl_xor(su,1,64);
        su += __shfl_xor(su,2,64);
        su += __shfl_xor(su,4,64);
        su += __shfl_xor(su,8,64);
        Pbg[(h*16 + quad*4 + r)*16 + l15] = f2bf(p/su);
      }
    }
  }
  FENCE();

  // ---- O = P@V per head; column mean over 16 nodes in-register -> OM ----
  #pragma unroll
  for (int g=0; g<2; ++g){
    unsigned short* Pbg = Pb + g*1024;
    #pragma unroll
    for (int h=0;h<4;++h){
      bf16x8 aP = (quad < 2) ? ld8(Pbg + (h*16 + l15)*16 + quad*8) : Z;
      f32x4 o = MFMA16(aP, bV[g][h], z);
      float cs = o[0]+o[1]+o[2]+o[3];
      cs += __shfl_xor(cs, 16, 64);
      cs += __shfl_xor(cs, 32, 64);
      if (quad == 0) OMf[g*64 + h*16 + l15] = cs * (1.f/16.f);
    }
  }
  FENCE();

  // ---- feat = ((mean O) @ wo) @ wproj + bproj  (all fp32 scalar) ----
  {
    float t0 = 0.f, t1 = 0.f;
    #pragma unroll 8
    for (int d=0; d<64; ++d){
      float wv = wo[d*64 + lane];
      t0 += OMf[d]    * wv;
      t1 += OMf[64+d] * wv;
    }
    OMf[128+lane] = t0;
    OMf[192+lane] = t1;
    FENCE();
    float a00 = bproj[lane], a01 = bproj[lane+64];
    float a10 = a00, a11 = a01;
    #pragma unroll 8
    for (int m=0; m<64; ++m){
      float f0 = OMf[128+m], f1 = OMf[192+m];
      float w0 = wproj[m*128 + lane], w1 = wproj[m*128 + lane + 64];
      a00 += f0*w0; a01 += f0*w1;
      a10 += f1*w0; a11 += f1*w1;
    }
    feat[(size_t)gb0*128 + lane]        = f2bf(a00);
    feat[(size_t)gb0*128 + lane + 64]   = f2bf(a01);
    feat[(size_t)(gb0+1)*128 + lane]      = f2bf(a10);
    feat[(size_t)(gb0+1)*128 + lane + 64] = f2bf(a11);
  }
}

// ---------------------------------------------------------------------------
// per-variable fc heads: 1 wg = 1 kh; W1/W2 in padded LDS; pred written via
// LDS transpose as coalesced bursts; y-copy fused at tail (k_copy removed).
// ---------------------------------------------------------------------------
__global__ __launch_bounds__(256,4) void k_heads(
  const unsigned short* __restrict__ ws0,
  const float* __restrict__ fc1b, const float* __restrict__ fc2b,
  float* __restrict__ pred,
  const float4* __restrict__ ysrc, float4* __restrict__ ydst)
{
  __shared__ alignas(16) unsigned short W1s[64*136];
  __shared__ alignas(16) unsigned short W2s[32*72];
  __shared__ alignas(16) unsigned short hh[4*2304];
  const int tid=threadIdx.x, w=tid>>6, lane=tid&63, quad=lane>>4, l15=lane&15;
  const int kh = blockIdx.x >> 7;
  const int rb = (blockIdx.x & 127)*128 + w*32;   // this wave's 32 rows
  unsigned short* hw = hh + w*2304;
  const unsigned short* featg = ws0 + O_FEAT;
  const unsigned short* W1 = ws0 + O_FC1 + kh*8192;
  const unsigned short* W2 = ws0 + O_FC2 + kh*2048;

  #pragma unroll
  for (int it=0; it<4; ++it){
    int idx = it*2048 + tid*8;
    int row = idx >> 7, col = idx & 127;
    *(uint4*)(W1s + row*136 + col) = *(const uint4*)(W1 + idx);
  }
  {
    int idx = tid*8; int row = idx >> 6, col = idx & 63;
    *(uint4*)(W2s + row*72 + col) = *(const uint4*)(W2 + idx);
  }
  __syncthreads();

  f32x4 z = {0.f,0.f,0.f,0.f};
  f32x4 acc[2][4];
  #pragma unroll
  for (int t=0;t<2;++t)
  #pragma unroll
  for (int c=0;c<4;++c) acc[t][c]=z;
  #pragma unroll
  for (int kc=0;kc<4;++kc){
    bf16x8 a0 = ld8(featg + (size_t)(rb+l15)*128    + kc*32+quad*8);
    bf16x8 a1 = ld8(featg + (size_t)(rb+16+l15)*128 + kc*32+quad*8);
    #pragma unroll
    for (int c=0;c<4;++c){
      bf16x8 b = ld8(W1s + (c*16+l15)*136 + kc*32+quad*8);
      acc[0][c] = MFMA16(a0, b, acc[0][c]);
      acc[1][c] = MFMA16(a1, b, acc[1][c]);
    }
  }
  #pragma unroll
  for (int c=0;c<4;++c){
    float bb = fc1b[kh*64 + c*16+l15];
    #pragma unroll
    for (int t=0;t<2;++t)
    #pragma unroll
    for (int r=0;r<4;++r)
      hw[t*1152 + (quad*4+r)*72 + c*16+l15] = f2bf(fmaxf(acc[t][c][r]+bb, 0.f));
  }
  FENCE();
  f32x4 acc2[2][2];
  #pragma unroll
  for (int t=0;t<2;++t)
  #pragma unroll
  for (int c=0;c<2;++c) acc2[t][c]=z;
  #pragma unroll
  for (int kc=0;kc<2;++kc){
    bf16x8 a0 = ld8(hw +        l15*72 + kc*32+quad*8);
    bf16x8 a1 = ld8(hw + 1152 + l15*72 + kc*32+quad*8);
    #pragma unroll
    for (int c=0;c<2;++c){
      bf16x8 b = ld8(W2s + (c*16+l15)*72 + kc*32+quad*8);
      acc2[0][c] = MFMA16(a0, b, acc2[0][c]);
      acc2[1][c] = MFMA16(a1, b, acc2[1][c]);
    }
  }
  FENCE();   // all hw reads done; reuse hw as f32 staging for coalesced writes
  float* hf = (float*)hw;     // 1152 floats; we use 384 per tile
  #pragma unroll
  for (int t=0;t<2;++t){
    #pragma unroll
    for (int c=0;c<2;++c){
      int col = c*16+l15;
      if (col < 24){
        float bb = fc2b[kh*24+col];
        #pragma unroll
        for (int r=0;r<4;++r)
          hf[(quad*4+r)*24 + col] = acc2[t][c][r] + bb;
      }
    }
    FENCE();
    float* pb = pred + (size_t)kh*393216 + (size_t)(rb + t*16)*24;
    #pragma unroll
    for (int k=0;k<6;++k)
      pb[k*64 + lane] = hf[k*64 + lane];
    FENCE();
  }

  // fused yb copy: 2048 blocks x 256 threads x 3 = 1572864 float4 exact
  {
    int gidx = blockIdx.x*256 + tid;
    #pragma unroll
    for (int k=0;k<3;++k)
      ydst[gidx + k*524288] = ysrc[gidx + k*524288];
  }
}

// ---------------------------------------------------------------------------
extern "C" void kernel_launch(void* const* d_in, const int* in_sizes, int n_in,
                              void* d_out, int out_size, void* d_ws, size_t ws_size,
                              hipStream_t stream) {
  const float* x    = (const float*)d_in[0];
  const float* y    = (const float*)d_in[1];
  const int*   ei   = (const int*)d_in[2];
  const float* w1l  = (const float*)d_in[4];
  const float* w1r  = (const float*)d_in[5];
  const float* b1   = (const float*)d_in[6];
  const float* w2l  = (const float*)d_in[7];
  const float* w2r  = (const float*)d_in[8];
  const float* b2   = (const float*)d_in[9];
  const float* w3l  = (const float*)d_in[10];
  const float* w3r  = (const float*)d_in[11];
  const float* b3   = (const float*)d_in[12];
  const float* tcnw = (const float*)d_in[13];
  const float* tcnb = (const float*)d_in[14];
  const float* wq   = (const float*)d_in[15];
  const float* wk   = (const float*)d_in[16];
  const float* wv   = (const float*)d_in[17];
  const float* wo   = (const float*)d_in[18];
  const float* wpr  = (const float*)d_in[19];
  const float* bpr  = (const float*)d_in[20];
  const float* fc1w = (const float*)d_in[21];
  const float* fc1b = (const float*)d_in[22];
  const float* fc2w = (const float*)d_in[23];
  const float* fc2b = (const float*)d_in[24];

  unsigned short* W = (unsigned short*)d_ws;
  float* out = (float*)d_out;

  k_prep<<<1120, 256, 0, stream>>>(w1l,w1r,w2l,w2r,w3l,w3r,tcnw,wq,wk,wv,wo,fc1w,fc2w,W);
  k_fused<<<NGR/8, 256, 0, stream>>>(x, ei + EDGES, b1,b2,b3,tcnb, wo, wpr, bpr, W, W + O_FEAT);
  k_heads<<<2048, 256, 0, stream>>>(W, fc1b, fc2b, out,
                                    (const float4*)y, (float4*)(out + PRED_ELEMS));
}